// Round 7
// baseline (1484.554 us; speedup 1.0000x reference)
//
#include <hip/hip_runtime.h>
#include <math.h>

// ---------------- constants ----------------
#define NN 50000
#define EE 800000
#define ETOT (EE + NN)
#define BB 128
#define DIM 128
#define GHID 32
#define CHUNK 128
#define PCH 16
#define SCB 196  // scan blocks: 196*256 >= 50000

typedef _Float16 f16;
typedef _Float16 f16x2 __attribute__((ext_vector_type(2)));
typedef _Float16 f16x8 __attribute__((ext_vector_type(8)));
typedef float f32x4 __attribute__((ext_vector_type(4)));

struct CurvPack {
  float k[4], sk[4], mx[4];
};

// ---------------- device math helpers ----------------
__device__ __forceinline__ float wsum64(float v) {
#pragma unroll
  for (int m = 32; m; m >>= 1) v += __shfl_xor(v, m, 64);
  return v;
}

__device__ __forceinline__ float tan_k_d(float x, float kv, float sk) {
  if (kv > 0.f) return tanf(x * sk) / sk;
  if (kv < 0.f) return tanhf(x * sk) / sk;
  return x;
}

__device__ __forceinline__ float artan_k_d(float x, float kv, float sk) {
  if (kv > 0.f) return atanf(x * sk) / sk;
  if (kv < 0.f) {
    float t = x * sk;
    t = fminf(fmaxf(t, -1.f + 1e-7f), 1.f - 1e-7f);
    return atanhf(t) / sk;
  }
  return x;
}

__device__ __forceinline__ float proj_scale_d(float n, float kv, float maxn) {
  if (kv < 0.f && n > maxn) return maxn / n;
  return 1.f;
}

// ---------------- graph preprocessing ----------------
__global__ void k_init(float* __restrict__ deg, int n) {
  int i = blockIdx.x * 256 + threadIdx.x;
  if (i < n) deg[i] = 1.0f;  // self loop
}

__global__ void k_counts(const int* __restrict__ batch, int* __restrict__ boff,
                         float* __restrict__ counts, int n) {
  int b = threadIdx.x;  // 0..255
  if (b <= 128) {
    int lo = 0, hi = n;
    while (lo < hi) {
      int mid = (lo + hi) >> 1;
      if (batch[mid] < b) lo = mid + 1; else hi = mid;
    }
    boff[b] = lo;
  }
  __syncthreads();
  if (b < 128) counts[b] = (float)(boff[b + 1] - boff[b]);
}

__global__ void k_deg(const int* __restrict__ ei, float* __restrict__ deg, int e) {
  int i = blockIdx.x * 256 + threadIdx.x;
  if (i < e) atomicAdd(&deg[ei[e + i]], 1.0f);  // col = edge_index[1]
}

__global__ void k_dinv(float* __restrict__ deg, int* __restrict__ ideg, int n) {
  int i = blockIdx.x * 256 + threadIdx.x;
  if (i < n) {
    float d = deg[i];
    ideg[i] = (int)(d + 0.5f);
    deg[i] = 1.0f / sqrtf(d);  // deg buffer becomes dinv
  }
}

// ---------------- parallel scan (3 kernels) ----------------
__global__ void k_scanA(const int* __restrict__ ideg, int* __restrict__ bsum, int n) {
  __shared__ int ls[4];
  int i = blockIdx.x * 256 + threadIdx.x;
  int v = (i < n) ? ideg[i] : 0;
#pragma unroll
  for (int m = 1; m < 64; m <<= 1) v += __shfl_xor(v, m, 64);
  if ((threadIdx.x & 63) == 0) ls[threadIdx.x >> 6] = v;
  __syncthreads();
  if (threadIdx.x == 0) bsum[blockIdx.x] = ls[0] + ls[1] + ls[2] + ls[3];
}

__global__ void k_scanB(int* __restrict__ bsum, int nb) {
  __shared__ int wsh[4];
  int tid = threadIdx.x;
  int lane = tid & 63, w = tid >> 6;
  int v = (tid < nb) ? bsum[tid] : 0;
  int x = v;
#pragma unroll
  for (int o = 1; o < 64; o <<= 1) {
    int t = __shfl_up(x, o, 64);
    if (lane >= o) x += t;
  }
  if (lane == 63) wsh[w] = x;
  __syncthreads();
  int add = 0;
  for (int k2 = 0; k2 < w; k2++) add += wsh[k2];
  if (tid < nb) bsum[tid] = add + x - v;  // exclusive
}

__global__ void k_scanC(const int* __restrict__ ideg, const int* __restrict__ bsum,
                        int* __restrict__ off, int* __restrict__ cursor, int n) {
  __shared__ int wsh[4];
  int i = blockIdx.x * 256 + threadIdx.x;
  int lane = threadIdx.x & 63, w = threadIdx.x >> 6;
  int v = (i < n) ? ideg[i] : 0;
  int x = v;
#pragma unroll
  for (int o = 1; o < 64; o <<= 1) {
    int t = __shfl_up(x, o, 64);
    if (lane >= o) x += t;
  }
  if (lane == 63) wsh[w] = x;
  __syncthreads();
  int add = bsum[blockIdx.x];
  for (int k2 = 0; k2 < w; k2++) add += wsh[k2];
  int excl = add + x - v;
  if (i < n) {
    off[i] = excl;
    cursor[i] = excl;
  }
  if (i == n - 1) off[n] = excl + v;
}

// ---------------- edge placement: perm scatter + sequential-write gather ----------------
__global__ void k_place1(const int* __restrict__ ei, int* __restrict__ cursor,
                         int* __restrict__ perm, int e, int n) {
  int i = blockIdx.x * 256 + threadIdx.x;
  int et = e + n;
  if (i >= et) return;
  int c = (i < e) ? ei[e + i] : i - e;
  int p = atomicAdd(&cursor[c], 1);
  perm[p] = i;
}

__global__ void k_place2(const int* __restrict__ ei, const float* __restrict__ dinv,
                         const int* __restrict__ perm, int2* __restrict__ esw, int e, int n) {
  int q = blockIdx.x * 256 + threadIdx.x;
  int et = e + n;
  if (q >= et) return;
  int i = perm[q];
  int r_ = (i < e) ? ei[i] : i - e;
  int c_ = (i < e) ? ei[e + i] : i - e;
  esw[q] = make_int2(r_, __float_as_int(dinv[r_] * dinv[c_]));
}

// ---------------- per-node prep: raw norm of x + all 4 expert expmap0 scales ----------------
__global__ void k_nodeprep(const float* __restrict__ x, float* __restrict__ scl,
                           float* __restrict__ xnk, int n, CurvPack cp) {
  int wid = blockIdx.x * 4 + (threadIdx.x >> 6);
  int lane = threadIdx.x & 63;
  if (wid >= n) return;
  float2 v = ((const float2*)x)[(size_t)wid * 64 + lane];
  float n2 = wsum64(v.x * v.x + v.y * v.y);
  float nraw = sqrtf(n2);
  if (lane < 4) {
    float kv = cp.k[lane], sk = cp.sk[lane], maxn = cp.mx[lane];
    float nnv = fmaxf(nraw, 1e-15f);
    float tk = tan_k_d(nnv, kv, sk);
    float s = tk / nnv;
    float pn = fmaxf(fabsf(tk) * (nraw / nnv), 1e-15f);
    float ps = proj_scale_d(pn, kv, maxn);
    scl[(size_t)lane * n + wid] = s * ps;
    xnk[(size_t)lane * n + wid] = pn * ps;
  }
}

// ---------------- bias points: expmap0(b) for all 8 (expert,layer) pairs ----------------
__global__ void k_biaspt_all(const float* __restrict__ eb1, const float* __restrict__ eb2,
                             float* __restrict__ biasb, CurvPack cp) {
  __shared__ float l2[2];
  int blk = blockIdx.x;  // ex*2 + layer
  int ex = blk >> 1, layer = blk & 1;
  float kv = cp.k[ex], sk = cp.sk[ex], maxn = cp.mx[ex];
  const float* b = (layer ? eb2 : eb1) + ex * 128;
  float* outb = biasb + blk * 132;
  int j = threadIdx.x;  // 0..127
  float v = b[j];
  float n2 = wsum64(v * v);
  if ((j & 63) == 0) l2[j >> 6] = n2;
  __syncthreads();
  n2 = l2[0] + l2[1];
  float nraw = sqrtf(n2);
  float nnv = fmaxf(nraw, 1e-15f);
  float tk = tan_k_d(nnv, kv, sk);
  float s = tk / nnv;
  float pn = fmaxf(fabsf(tk) * (nraw / nnv), 1e-15f);
  float ps = proj_scale_d(pn, kv, maxn);
  float bp = ps * s * v;
  outb[j] = bp;
  float y2v = wsum64(bp * bp);
  __syncthreads();
  if ((j & 63) == 0) l2[j >> 6] = y2v;
  __syncthreads();
  if (j == 0) outb[128] = l2[0] + l2[1];
}

// ---------------- W -> fp16 hi/lo split (8 slots of 128x128) ----------------
__global__ void k_w2h(const float* __restrict__ ew1, const float* __restrict__ ew2,
                      f16* __restrict__ whi, f16* __restrict__ wlo) {
  int i = blockIdx.x * 256 + threadIdx.x;
  if (i >= 8 * 16384) return;
  int slot = i >> 14;
  int r = i & 16383;
  int ex = slot >> 1, layer = slot & 1;
  float w = (layer ? ew2 : ew1)[ex * 16384 + r];
  f16 h = (f16)w;
  whi[i] = h;
  wlo[i] = (f16)(w - (float)h);
}

// ---------------- MFMA expert GEMM (f16-split, 4 waves/16-node tile) ----------------
// Block = 256 thr = 4 waves; each wave does 16 nodes x 32 cols (2 jt). Cross-wave
// epilogue reductions via 1KB LDS.
__global__ __launch_bounds__(256) void k_matmfma(
    const float* __restrict__ in, const float* __restrict__ scale,
    const float* __restrict__ xnorm, const f16* __restrict__ whi,
    const f16* __restrict__ wlo, const float* __restrict__ biasb,
    f16* __restrict__ tout, int n, float kv, float sk, float maxn) {
  __shared__ float red[4][16][4];  // [s0,s1,s2,t0][node][wave]
  int tid = threadIdx.x;
  int w = tid >> 6;
  int lane = tid & 63;
  int col = lane & 15;
  int quad = lane >> 4;
  int n0w = blockIdx.x * 16;
  if (n0w >= n) return;

  int anodec = min(n0w + col, n - 1);
  float asc = scale ? scale[anodec] : 1.f;
  const float* arow = in + (size_t)anodec * 128;
  int jt0 = w * 2;

  f32x4 acc[2];
  acc[0] = (f32x4){0.f, 0.f, 0.f, 0.f};
  acc[1] = (f32x4){0.f, 0.f, 0.f, 0.f};

#pragma unroll
  for (int kc = 0; kc < 4; kc++) {
    int kb = kc * 32 + quad * 8;
    float4 a0 = *(const float4*)(arow + kb);
    float4 a1 = *(const float4*)(arow + kb + 4);
    float av[8] = {a0.x, a0.y, a0.z, a0.w, a1.x, a1.y, a1.z, a1.w};
    f16x8 ahi, alo;
#pragma unroll
    for (int i = 0; i < 8; i++) {
      float xs = av[i] * asc;
      f16 h = (f16)xs;
      ahi[i] = h;
      alo[i] = (f16)(xs - (float)h);
    }
#pragma unroll
    for (int j2 = 0; j2 < 2; j2++) {
      const f16* bh = whi + (size_t)((jt0 + j2) * 16 + col) * 128 + kb;
      const f16* bl = wlo + (size_t)((jt0 + j2) * 16 + col) * 128 + kb;
      f16x8 bhi = *(const f16x8*)bh;
      f16x8 blo = *(const f16x8*)bl;
      acc[j2] = __builtin_amdgcn_mfma_f32_16x16x32_f16(ahi, bhi, acc[j2], 0, 0, 0);
      acc[j2] = __builtin_amdgcn_mfma_f32_16x16x32_f16(ahi, blo, acc[j2], 0, 0, 0);
      acc[j2] = __builtin_amdgcn_mfma_f32_16x16x32_f16(alo, bhi, acc[j2], 0, 0, 0);
    }
  }

  float bpj[2];
  bpj[0] = biasb[jt0 * 16 + col];
  bpj[1] = biasb[(jt0 + 1) * 16 + col];
  float y2 = biasb[128];

  // phase 1: partial sums over this wave's 32 cols
  float S0[4], S1[4], S2[4];
#pragma unroll
  for (int r = 0; r < 4; r++) {
    float s0 = 0.f, s1 = 0.f, s2 = 0.f;
#pragma unroll
    for (int j2 = 0; j2 < 2; j2++) {
      float v = acc[j2][r];
      s0 = fmaf(v, v, s0);
      s1 += fabsf(v);
      s2 = fmaf(v, bpj[j2], s2);
    }
#pragma unroll
    for (int m = 1; m < 16; m <<= 1) {
      s0 += __shfl_xor(s0, m, 64);
      s1 += __shfl_xor(s1, m, 64);
      s2 += __shfl_xor(s2, m, 64);
    }
    S0[r] = s0;
    S1[r] = s1;
    S2[r] = s2;
  }
  if (col == 0) {
#pragma unroll
    for (int r = 0; r < 4; r++) {
      red[0][quad * 4 + r][w] = S0[r];
      red[1][quad * 4 + r][w] = S1[r];
      red[2][quad * 4 + r][w] = S2[r];
    }
  }
  __syncthreads();

  float As[4], Cs[4];
#pragma unroll
  for (int r = 0; r < 4; r++) {
    int idx = quad * 4 + r;
    float s0f = red[0][idx][0] + red[0][idx][1] + red[0][idx][2] + red[0][idx][3];
    float s1f = red[1][idx][0] + red[1][idx][1] + red[1][idx][2] + red[1][idx][3];
    float s2f = red[2][idx][0] + red[2][idx][1] + red[2][idx][2] + red[2][idx][3];
    float xnr = xnorm[min(n0w + idx, n - 1)];
    float xn = fmaxf(xnr, 1e-15f);
    float mxraw = sqrtf(s0f);
    float mxv = fmaxf(mxraw, 1e-15f);
    float ar = artan_k_d(xn, kv, sk);
    float c1 = tan_k_d(mxv / xn * ar, kv, sk);
    float s = (s1f == 0.f) ? 0.f : c1 / mxv;
    float pn = fmaxf(fabsf(c1) * (mxraw / mxv), 1e-15f);
    float ps = (s1f == 0.f) ? 1.f : proj_scale_d(pn, kv, maxn);
    s *= ps;
    float x2 = (s * s) * s0f;
    float xy = s * s2f;
    float A = 1.f - 2.f * kv * xy - kv * y2;
    float Cc = 1.f + kv * x2;
    float den = fmaxf(1.f - 2.f * kv * xy + (kv * kv) * x2 * y2, 1e-15f);
    As[r] = A * s / den;
    Cs[r] = Cc / den;
  }

  // phase 2: t0 partial
  float T0[4];
#pragma unroll
  for (int r = 0; r < 4; r++) {
    float t0 = 0.f;
#pragma unroll
    for (int j2 = 0; j2 < 2; j2++) {
      float v = fmaf(As[r], acc[j2][r], Cs[r] * bpj[j2]);
      t0 = fmaf(v, v, t0);
    }
#pragma unroll
    for (int m = 1; m < 16; m <<= 1) t0 += __shfl_xor(t0, m, 64);
    T0[r] = t0;
  }
  if (col == 0) {
#pragma unroll
    for (int r = 0; r < 4; r++) red[3][quad * 4 + r][w] = T0[r];
  }
  __syncthreads();

#pragma unroll
  for (int r = 0; r < 4; r++) {
    int idx = quad * 4 + r;
    int gnode = n0w + idx;
    float t0f = red[3][idx][0] + red[3][idx][1] + red[3][idx][2] + red[3][idx][3];
    float nraw = sqrtf(t0f);
    float ps2 = proj_scale_d(fmaxf(nraw, 1e-15f), kv, maxn);
    float nh = fmaxf(ps2 * nraw, 1e-15f);
    float L = artan_k_d(nh, kv, sk) / nh * ps2;
    if (gnode < n) {
      f16* trow = tout + (size_t)gnode * 128;
#pragma unroll
      for (int j2 = 0; j2 < 2; j2++) {
        float v = fmaf(As[r], acc[j2][r], Cs[r] * bpj[j2]);
        trow[(jt0 + j2) * 16 + col] = (f16)(L * v);
      }
    }
  }
}

// ---------------- edge-sweep aggregation: agg[dst] += w * t[src] (fp16 rows) ----------------
__global__ __launch_bounds__(256) void k_aggE(const int2* __restrict__ esw,
                                              const int* __restrict__ off,
                                              const f16x2* __restrict__ t,
                                              float* __restrict__ agg, int etot, int n) {
  int gw = blockIdx.x * 4 + (threadIdx.x >> 6);
  int lane = threadIdx.x & 63;
  int e0 = gw * CHUNK;
  if (e0 >= etot) return;
  int e1 = min(e0 + CHUNK, etot);
  int lo = 0, hi = n;
  while (hi - lo > 1) {
    int mid = (lo + hi) >> 1;
    if (off[mid] <= e0) lo = mid; else hi = mid;
  }
  int cur = lo;
  int runStart = off[cur];
  int eend = off[cur + 1];
  float ax = 0.f, ay = 0.f;
  int j = e0;
  while (j < e1) {
    if (j + 16 <= e1 && eend >= j + 16) {
      int2 m[16];
#pragma unroll
      for (int q = 0; q < 16; q++) m[q] = esw[j + q];
      f16x2 r[16];
#pragma unroll
      for (int q = 0; q < 16; q++) {
        int s = __builtin_amdgcn_readfirstlane(m[q].x);
        r[q] = t[(size_t)s * 64 + lane];
      }
#pragma unroll
      for (int q = 0; q < 16; q++) {
        float w = __int_as_float(m[q].y);
        ax = fmaf(w, (float)r[q][0], ax);
        ay = fmaf(w, (float)r[q][1], ay);
      }
      j += 16;
    } else if (j + 8 <= e1 && eend >= j + 8) {
      int2 m[8];
#pragma unroll
      for (int q = 0; q < 8; q++) m[q] = esw[j + q];
      f16x2 r[8];
#pragma unroll
      for (int q = 0; q < 8; q++) {
        int s = __builtin_amdgcn_readfirstlane(m[q].x);
        r[q] = t[(size_t)s * 64 + lane];
      }
#pragma unroll
      for (int q = 0; q < 8; q++) {
        float w = __int_as_float(m[q].y);
        ax = fmaf(w, (float)r[q][0], ax);
        ay = fmaf(w, (float)r[q][1], ay);
      }
      j += 8;
    } else if (j + 4 <= e1 && eend >= j + 4) {
      int2 m[4];
#pragma unroll
      for (int q = 0; q < 4; q++) m[q] = esw[j + q];
      f16x2 r[4];
#pragma unroll
      for (int q = 0; q < 4; q++) {
        int s = __builtin_amdgcn_readfirstlane(m[q].x);
        r[q] = t[(size_t)s * 64 + lane];
      }
#pragma unroll
      for (int q = 0; q < 4; q++) {
        float w = __int_as_float(m[q].y);
        ax = fmaf(w, (float)r[q][0], ax);
        ay = fmaf(w, (float)r[q][1], ay);
      }
      j += 4;
    } else {
      if (j == eend) {
        float* dp = agg + (size_t)cur * 128 + lane * 2;
        if (runStart >= e0) {
          dp[0] = ax;
          dp[1] = ay;
        } else {
          atomicAdd(dp, ax);
          atomicAdd(dp + 1, ay);
        }
        ax = ay = 0.f;
        runStart = j;
        cur++;
        eend = off[cur + 1];
      }
      int2 m = esw[j];
      int s = __builtin_amdgcn_readfirstlane(m.x);
      f16x2 rv = t[(size_t)s * 64 + lane];
      float w = __int_as_float(m.y);
      ax = fmaf(w, (float)rv[0], ax);
      ay = fmaf(w, (float)rv[1], ay);
      j++;
    }
  }
  float* dp = agg + (size_t)cur * 128 + lane * 2;
  if (runStart >= e0 && eend <= e1) {
    dp[0] = ax;
    dp[1] = ay;
  } else {
    atomicAdd(dp, ax);
    atomicAdd(dp + 1, ay);
  }
}

// ---------------- post-agg: per-node expmap0 scale (for layer-2) ----------------
__global__ void k_postnorm(const float* __restrict__ agg, float* __restrict__ scl,
                           float* __restrict__ xnk, int n, float kv, float sk, float maxn) {
  int wid = blockIdx.x * 4 + (threadIdx.x >> 6);
  int lane = threadIdx.x & 63;
  if (wid >= n) return;
  float2 v = ((const float2*)agg)[(size_t)wid * 64 + lane];
  float n2 = wsum64(fmaf(v.x, v.x, v.y * v.y));
  float nraw = sqrtf(n2);
  float nnv = fmaxf(nraw, 1e-15f);
  float tk = tan_k_d(nnv, kv, sk);
  float s = tk / nnv;
  float pn = fmaxf(fabsf(tk) * (nraw / nnv), 1e-15f);
  float ps = proj_scale_d(pn, kv, maxn);
  if (lane == 0) {
    scl[wid] = s * ps;
    xnk[wid] = pn * ps;
  }
}

// ---------------- post-agg: per-node pooling scale sc = logmap0 o expmap0 ----------------
__global__ void k_postscale(const float* __restrict__ agg, float* __restrict__ scpool, int n,
                            float kv, float sk, float maxn) {
  int wid = blockIdx.x * 4 + (threadIdx.x >> 6);
  int lane = threadIdx.x & 63;
  if (wid >= n) return;
  float2 v = ((const float2*)agg)[(size_t)wid * 64 + lane];
  float n2 = wsum64(fmaf(v.x, v.x, v.y * v.y));
  float nraw = sqrtf(n2);
  float nnv = fmaxf(nraw, 1e-15f);
  float tk = tan_k_d(nnv, kv, sk);
  float s = tk / nnv;
  float pn = fmaxf(fabsf(tk) * (nraw / nnv), 1e-15f);
  float ps = proj_scale_d(pn, kv, maxn);
  s *= ps;
  float nh = fmaxf(pn * ps, 1e-15f);
  float sc = artan_k_d(nh, kv, sk) / nh * s;
  if (lane == 0) scpool[wid] = sc;
}

// ---------------- strip pooling: feats[b] += sc[node]*agg[node] ----------------
__global__ void k_pooladd(const float* __restrict__ agg, const float* __restrict__ scpool,
                          const int* __restrict__ boff, float* __restrict__ feats, int ex,
                          int n) {
  int gw = blockIdx.x * 4 + (threadIdx.x >> 6);
  int lane = threadIdx.x & 63;
  int n0 = gw * PCH;
  if (n0 >= n) return;
  int n1 = min(n0 + PCH, n);
  int lo = 0, hi = 128;
  while (hi - lo > 1) {
    int mid = (lo + hi) >> 1;
    if (boff[mid] <= n0) lo = mid; else hi = mid;
  }
  int cb = lo;
  int bend = boff[cb + 1];
  float ax = 0.f, ay = 0.f;
  for (int node = n0; node < n1; node++) {
    while (node == bend) {
      float* dp = &feats[(size_t)cb * 512 + ex * 128 + lane * 2];
      atomicAdd(dp, ax);
      atomicAdd(dp + 1, ay);
      ax = ay = 0.f;
      cb++;
      bend = boff[cb + 1];
    }
    float sc = scpool[node];
    float2 v = ((const float2*)agg)[(size_t)node * 64 + lane];
    ax = fmaf(sc, v.x, ax);
    ay = fmaf(sc, v.y, ay);
  }
  float* dp = &feats[(size_t)cb * 512 + ex * 128 + lane * 2];
  atomicAdd(dp, ax);
  atomicAdd(dp + 1, ay);
}

// ---------------- strip pooling: hgate[b] += relu(agg[node]+bias) ----------------
__global__ void k_poolgate(const float* __restrict__ agg, const float* __restrict__ bias,
                           const int* __restrict__ boff, float* __restrict__ hgate, int n) {
  int gw = blockIdx.x * 4 + (threadIdx.x >> 6);
  int lane = threadIdx.x & 63;
  int n0 = gw * PCH;
  if (n0 >= n) return;
  int n1 = min(n0 + PCH, n);
  int lo = 0, hi = 128;
  while (hi - lo > 1) {
    int mid = (lo + hi) >> 1;
    if (boff[mid] <= n0) lo = mid; else hi = mid;
  }
  int cb = lo;
  int bend = boff[cb + 1];
  float2 bb = ((const float2*)bias)[lane];
  float ax = 0.f, ay = 0.f;
  for (int node = n0; node < n1; node++) {
    while (node == bend) {
      float* dp = &hgate[(size_t)cb * 128 + lane * 2];
      atomicAdd(dp, ax);
      atomicAdd(dp + 1, ay);
      ax = ay = 0.f;
      cb++;
      bend = boff[cb + 1];
    }
    float2 v = ((const float2*)agg)[(size_t)node * 64 + lane];
    ax += fmaxf(v.x + bb.x, 0.f);
    ay += fmaxf(v.y + bb.y, 0.f);
  }
  float* dp = &hgate[(size_t)cb * 128 + lane * 2];
  atomicAdd(dp, ax);
  atomicAdd(dp + 1, ay);
}

// ---------------- gate GEMM 1: m1 = x @ gw1.T  [N,128] -> [N,32] ----------------
__global__ __launch_bounds__(256) void k_gate1(const float* __restrict__ x,
                                               const float* __restrict__ gw1,
                                               float* __restrict__ m1, int n) {
  __shared__ float xT[64][68];
  __shared__ float Wt[64][36];
  int tid = threadIdx.x;
  int n0 = blockIdx.x * 64;
  int c = tid & 7, r = tid >> 3;
  float acc[2][4];
#pragma unroll
  for (int i = 0; i < 2; i++)
#pragma unroll
    for (int jj = 0; jj < 4; jj++) acc[i][jj] = 0.f;

  for (int kc = 0; kc < 2; kc++) {
    if (kc) __syncthreads();
#pragma unroll
    for (int it = 0; it < 8; it++) {
      int u = tid + it * 256;
      int j = u >> 6, kd = u & 63;
      Wt[kd][j] = gw1[j * 128 + kc * 64 + kd];
    }
#pragma unroll
    for (int it = 0; it < 4; it++) {
      int u = tid + it * 256;
      int node = u >> 4, c4 = u & 15;
      float4 v = make_float4(0.f, 0.f, 0.f, 0.f);
      if (n0 + node < n) v = ((const float4*)x)[(size_t)(n0 + node) * 32 + kc * 16 + c4];
      xT[4 * c4 + 0][node] = v.x;
      xT[4 * c4 + 1][node] = v.y;
      xT[4 * c4 + 2][node] = v.z;
      xT[4 * c4 + 3][node] = v.w;
    }
    __syncthreads();
#pragma unroll 8
    for (int kd = 0; kd < 64; kd++) {
      float2 av = *(const float2*)&xT[kd][r * 2];
      float4 bv = *(const float4*)&Wt[kd][c * 4];
      float a[2] = {av.x, av.y};
      float bbv[4] = {bv.x, bv.y, bv.z, bv.w};
#pragma unroll
      for (int i = 0; i < 2; i++)
#pragma unroll
        for (int jj = 0; jj < 4; jj++) acc[i][jj] = fmaf(a[i], bbv[jj], acc[i][jj]);
    }
  }
#pragma unroll
  for (int i = 0; i < 2; i++) {
    int node = n0 + r * 2 + i;
    if (node >= n) continue;
    ((float4*)m1)[(size_t)node * 8 + c] = make_float4(acc[i][0], acc[i][1], acc[i][2], acc[i][3]);
  }
}

// ---------------- gate GEMM 2: m2 = g1 @ gw2.T  [N,32] -> [N,128] fp16 out ----------------
__global__ __launch_bounds__(256) void k_gate2(const float* __restrict__ g1,
                                               const float* __restrict__ gw2,
                                               f16* __restrict__ m2, int n) {
  __shared__ float xT[32][68];
  __shared__ float Wt[32][132];
  int tid = threadIdx.x;
  int n0 = blockIdx.x * 64;
  int c = tid & 15, r = tid >> 4;
  float acc[4][8];
#pragma unroll
  for (int i = 0; i < 4; i++)
#pragma unroll
    for (int jj = 0; jj < 8; jj++) acc[i][jj] = 0.f;

#pragma unroll
  for (int it = 0; it < 16; it++) {
    int u = tid + it * 256;
    int j = u >> 5, kd = u & 31;
    Wt[kd][j] = gw2[j * 32 + kd];
  }
#pragma unroll
  for (int it = 0; it < 2; it++) {
    int u = tid + it * 256;
    int node = u >> 3, c4 = u & 7;
    float4 v = make_float4(0.f, 0.f, 0.f, 0.f);
    if (n0 + node < n) v = ((const float4*)g1)[(size_t)(n0 + node) * 8 + c4];
    xT[4 * c4 + 0][node] = v.x;
    xT[4 * c4 + 1][node] = v.y;
    xT[4 * c4 + 2][node] = v.z;
    xT[4 * c4 + 3][node] = v.w;
  }
  __syncthreads();
#pragma unroll 8
  for (int kd = 0; kd < 32; kd++) {
    float4 av = *(const float4*)&xT[kd][r * 4];
    float4 b0 = *(const float4*)&Wt[kd][c * 8];
    float4 b1 = *(const float4*)&Wt[kd][c * 8 + 4];
    float a[4] = {av.x, av.y, av.z, av.w};
    float bbv[8] = {b0.x, b0.y, b0.z, b0.w, b1.x, b1.y, b1.z, b1.w};
#pragma unroll
    for (int i = 0; i < 4; i++)
#pragma unroll
      for (int jj = 0; jj < 8; jj++) acc[i][jj] = fmaf(a[i], bbv[jj], acc[i][jj]);
  }
#pragma unroll
  for (int i = 0; i < 4; i++) {
    int node = n0 + r * 4 + i;
    if (node >= n) continue;
    f16x8 hv;
#pragma unroll
    for (int jj = 0; jj < 8; jj++) hv[jj] = (f16)acc[i][jj];
    *((f16x8*)(m2 + (size_t)node * 128) + c) = hv;
  }
}

// ---------------- gate aggregation dim32 + bias + relu (node-parallel) ----------------
__global__ void k_agg_relu32(const float* __restrict__ m1, const int* __restrict__ off,
                             const int2* __restrict__ esw, const float* __restrict__ bias,
                             float* __restrict__ g1, int n) {
  int node = blockIdx.x * 4 + (threadIdx.x >> 6);
  int lane = threadIdx.x & 63;
  if (node >= n) return;
  int grp = lane >> 3, l8 = lane & 7;
  int e0 = off[node], e1 = off[node + 1];
  float4 acc = make_float4(0.f, 0.f, 0.f, 0.f);
  for (int base = e0 + grp; base < e1; base += 8) {
    int2 me = esw[base];
    int ss = me.x;
    float ww = __int_as_float(me.y);
    float4 tv = ((const float4*)m1)[(size_t)ss * 8 + l8];
    acc.x = fmaf(ww, tv.x, acc.x);
    acc.y = fmaf(ww, tv.y, acc.y);
    acc.z = fmaf(ww, tv.z, acc.z);
    acc.w = fmaf(ww, tv.w, acc.w);
  }
#pragma unroll
  for (int m = 8; m <= 32; m <<= 1) {
    acc.x += __shfl_xor(acc.x, m, 64);
    acc.y += __shfl_xor(acc.y, m, 64);
    acc.z += __shfl_xor(acc.z, m, 64);
    acc.w += __shfl_xor(acc.w, m, 64);
  }
  if (grp == 0) {
    float4 bb = ((const float4*)bias)[l8];
    float4 o = make_float4(fmaxf(acc.x + bb.x, 0.f), fmaxf(acc.y + bb.y, 0.f),
                           fmaxf(acc.z + bb.z, 0.f), fmaxf(acc.w + bb.w, 0.f));
    ((float4*)g1)[(size_t)node * 8 + l8] = o;
  }
}

// ---------------- final: distance gate + softmax + outputs ----------------
__global__ __launch_bounds__(128) void k_final(const float* __restrict__ feats,
                                               const float* __restrict__ hgate,
                                               const float* __restrict__ counts,
                                               const float* __restrict__ gate_u,
                                               const float* __restrict__ tau_raw,
                                               float* __restrict__ out, CurvPack cp) {
  __shared__ float l2[2];
  int b = blockIdx.x;
  int j = threadIdx.x;
  float cnt = fmaxf(counts[b], 1.f);
  float hg = hgate[(size_t)b * 128 + j] / cnt;

  auto bsum = [&](float v) -> float {
    v = wsum64(v);
    __syncthreads();
    if ((j & 63) == 0) l2[j >> 6] = v;
    __syncthreads();
    return l2[0] + l2[1];
  };

  float nhg2 = bsum(hg * hg);
  float nhgraw = sqrtf(nhg2);
  float nhg = fmaxf(nhgraw, 1e-15f);

  float d[4], tau[4];
#pragma unroll
  for (int i = 0; i < 4; i++) {
    float kv = cp.k[i], sk = cp.sk[i], mxn = cp.mx[i];
    float tk = tan_k_d(nhg, kv, sk);
    float s = tk / nhg;
    float pn = fmaxf(fabsf(tk) * (nhgraw / nhg), 1e-15f);
    s *= proj_scale_d(pn, kv, mxn);
    float zk = s * hg;

    float u = gate_u[i * 128 + j];
    float nu2 = bsum(u * u);
    float nuraw = sqrtf(nu2);
    float nu = fmaxf(nuraw, 1e-15f);
    float tku = tan_k_d(nu, kv, sk);
    float su = tku / nu;
    float pnu = fmaxf(fabsf(tku) * (nuraw / nu), 1e-15f);
    su *= proj_scale_d(pnu, kv, mxn);
    float yk = su * u;

    float xv = -zk;
    float x2 = bsum(xv * xv);
    float y2 = bsum(yk * yk);
    float xy = bsum(xv * yk);
    float A = 1.f - 2.f * kv * xy - kv * y2;
    float C = 1.f + kv * x2;
    float den = fmaxf(1.f - 2.f * kv * xy + (kv * kv) * x2 * y2, 1e-15f);
    float ma = (A * xv + C * yk) / den;
    float m2 = bsum(ma * ma);
    float mraw = sqrtf(m2);
    float ps2 = proj_scale_d(fmaxf(mraw, 1e-15f), kv, mxn);
    float nm = fmaxf(ps2 * mraw, 1e-15f);
    d[i] = 2.f * artan_k_d(nm, kv, sk);

    float tr = tau_raw[i];
    tau[i] = fminf(fmaxf(log1pf(expf(tr)) + 0.05f, 0.05f), 10.f);
  }

  float xi[4];
  float mxv = -1e30f;
#pragma unroll
  for (int i = 0; i < 4; i++) {
    xi[i] = -d[i] / tau[i];
    mxv = fmaxf(mxv, xi[i]);
  }
  float es = 0.f, e[4];
#pragma unroll
  for (int i = 0; i < 4; i++) {
    e[i] = expf(xi[i] - mxv);
    es += e[i];
  }
  float w[4];
#pragma unroll
  for (int i = 0; i < 4; i++) w[i] = e[i] / es;

#pragma unroll
  for (int i = 0; i < 4; i++)
    out[(size_t)b * 512 + i * 128 + j] = feats[(size_t)b * 512 + i * 128 + j] / cnt * w[i];

  if (j < 4) {
    out[65536 + b * 4 + j] = w[j];
    out[66048 + b * 4 + j] = d[j];
  }
  if (b == 0 && j < 4) out[66560 + j] = tau[j];
}

// ---------------- host launcher ----------------
extern "C" void kernel_launch(void* const* d_in, const int* in_sizes, int n_in,
                              void* d_out, int out_size, void* d_ws, size_t ws_size,
                              hipStream_t stream) {
  const float* x = (const float*)d_in[0];
  const int* ei = (const int*)d_in[1];
  const int* batch = (const int*)d_in[2];
  const float* ew1 = (const float*)d_in[3];
  const float* eb1 = (const float*)d_in[4];
  const float* ew2 = (const float*)d_in[5];
  const float* eb2 = (const float*)d_in[6];
  const float* gw1 = (const float*)d_in[7];
  const float* gb1 = (const float*)d_in[8];
  const float* gw2 = (const float*)d_in[9];
  const float* gb2 = (const float*)d_in[10];
  const float* gu = (const float*)d_in[11];
  const float* traw = (const float*)d_in[12];
  float* out = (float*)d_out;

  const int N = NN, E = EE, ET = ETOT, B = BB;

  float* ws = (float*)d_ws;
  size_t o = 0;
  f16* tbh = (f16*)ws;      o += (size_t)N * 64;  // N*128 halfs
  float* agg = ws + o;      o += (size_t)N * 128;
  float* m1 = ws + o;       o += (size_t)N * 32;
  float* g1 = ws + o;       o += (size_t)N * 32;
  float* deg = ws + o;      o += N;  // becomes dinv
  float* scl1 = ws + o;     o += (size_t)4 * N;
  float* xnk1 = ws + o;     o += (size_t)4 * N;
  float* scl2 = ws + o;     o += N;
  float* xnk2 = ws + o;     o += N;
  float* scpool = ws + o;   o += N;
  float* counts = ws + o;   o += 256;
  float* feats = ws + o;    o += (size_t)B * 512;
  float* hg = ws + o;       o += (size_t)B * 128;
  float* biasb = ws + o;    o += 8 * 132;
  f16* whi = (f16*)(ws + o);    o += 8 * 16384 / 2;
  f16* wlo = (f16*)(ws + o);    o += 8 * 16384 / 2;
  int* ideg = (int*)(ws + o);   o += N;
  int* csroff = (int*)(ws + o); o += N + 8;
  int* cursor = (int*)(ws + o); o += N;
  int* boff = (int*)(ws + o);   o += 136;
  int* bsum = (int*)(ws + o);   o += 256;
  int* perm = (int*)(ws + o);   o += ET;
  int2* esw = (int2*)(ws + o);  o += (size_t)2 * ET;

  // zero: counts + feats + hg (contiguous)
  hipMemsetAsync(counts, 0, (256 + (size_t)B * 512 + (size_t)B * 128) * sizeof(float), stream);

  const double curvs[4] = {-1.0, 0.0, 1.0, -0.5};
  CurvPack cp;
  for (int i = 0; i < 4; i++) {
    double kd = curvs[i];
    double skd = sqrt(fabs(kd));
    cp.k[i] = (float)kd;
    cp.sk[i] = (float)skd;
    cp.mx[i] = (kd < 0) ? (float)((1.0 - 1e-5) / skd) : 3.0e38f;
  }

  k_init<<<(N + 255) / 256, 256, 0, stream>>>(deg, N);
  k_counts<<<1, 256, 0, stream>>>(batch, boff, counts, N);
  k_deg<<<(E + 255) / 256, 256, 0, stream>>>(ei, deg, E);
  k_dinv<<<(N + 255) / 256, 256, 0, stream>>>(deg, ideg, N);
  k_scanA<<<SCB, 256, 0, stream>>>(ideg, bsum, N);
  k_scanB<<<1, 256, 0, stream>>>(bsum, SCB);
  k_scanC<<<SCB, 256, 0, stream>>>(ideg, bsum, csroff, cursor, N);
  k_place1<<<(ET + 255) / 256, 256, 0, stream>>>(ei, cursor, perm, E, N);
  k_place2<<<(ET + 255) / 256, 256, 0, stream>>>(ei, deg, perm, esw, E, N);
  k_nodeprep<<<(N + 3) / 4, 256, 0, stream>>>(x, scl1, xnk1, N, cp);
  k_biaspt_all<<<8, 128, 0, stream>>>(eb1, eb2, biasb, cp);
  k_w2h<<<512, 256, 0, stream>>>(ew1, ew2, whi, wlo);

  const int aggBlocks = ((ET + CHUNK - 1) / CHUNK + 3) / 4;
  const int poolBlocks = ((N + PCH - 1) / PCH + 3) / 4;
  const int mfmaBlocks = (N + 15) / 16;
  const size_t aggBytes = (size_t)N * 128 * sizeof(float);

  for (int ex = 0; ex < 4; ex++) {
    float kv = cp.k[ex], sk = cp.sk[ex], mxn = cp.mx[ex];
    int s1 = ex * 2, s2 = ex * 2 + 1;
    // layer 1 (expmap0 fused via per-node scale)
    k_matmfma<<<mfmaBlocks, 256, 0, stream>>>(x, scl1 + (size_t)ex * N, xnk1 + (size_t)ex * N,
                                              whi + (size_t)s1 * 16384, wlo + (size_t)s1 * 16384,
                                              biasb + s1 * 132, tbh, N, kv, sk, mxn);
    hipMemsetAsync(agg, 0, aggBytes, stream);
    k_aggE<<<aggBlocks, 256, 0, stream>>>(esw, csroff, (const f16x2*)tbh, agg, ET, N);
    k_postnorm<<<(N + 3) / 4, 256, 0, stream>>>(agg, scl2, xnk2, N, kv, sk, mxn);
    // layer 2 (input = raw agg, expmap0 fused via scl2)
    k_matmfma<<<mfmaBlocks, 256, 0, stream>>>(agg, scl2, xnk2, whi + (size_t)s2 * 16384,
                                              wlo + (size_t)s2 * 16384, biasb + s2 * 132, tbh, N,
                                              kv, sk, mxn);
    hipMemsetAsync(agg, 0, aggBytes, stream);
    k_aggE<<<aggBlocks, 256, 0, stream>>>(esw, csroff, (const f16x2*)tbh, agg, ET, N);
    k_postscale<<<(N + 3) / 4, 256, 0, stream>>>(agg, scpool, N, kv, sk, mxn);
    k_pooladd<<<poolBlocks, 256, 0, stream>>>(agg, scpool, boff, feats, ex, N);
  }

  // gate GCN
  k_gate1<<<(N + 63) / 64, 256, 0, stream>>>(x, gw1, m1, N);
  k_agg_relu32<<<(N + 3) / 4, 256, 0, stream>>>(m1, csroff, esw, gb1, g1, N);
  k_gate2<<<(N + 63) / 64, 256, 0, stream>>>(g1, gw2, tbh, N);
  hipMemsetAsync(agg, 0, aggBytes, stream);
  k_aggE<<<aggBlocks, 256, 0, stream>>>(esw, csroff, (const f16x2*)tbh, agg, ET, N);
  k_poolgate<<<poolBlocks, 256, 0, stream>>>(agg, gb2, boff, hg, N);

  k_final<<<B, 128, 0, stream>>>(feats, hg, counts, gu, traw, out, cp);

  (void)in_sizes; (void)n_in; (void)out_size; (void)ws_size;
}

// Round 8
// 1362.902 us; speedup vs baseline: 1.0893x; 1.0893x over previous
//
#include <hip/hip_runtime.h>
#include <math.h>

// ---------------- constants ----------------
#define NN 50000
#define EE 800000
#define ETOT (EE + NN)
#define BB 128
#define DIM 128
#define GHID 32
#define CHUNK 128
#define NCHUNK ((ETOT + CHUNK - 1) / CHUNK)
#define PCH 16
#define SCB 196  // scan blocks: 196*256 >= 50000

typedef _Float16 f16;
typedef _Float16 f16x2 __attribute__((ext_vector_type(2)));
typedef _Float16 f16x8 __attribute__((ext_vector_type(8)));
typedef float f32x4 __attribute__((ext_vector_type(4)));

struct CurvPack {
  float k[4], sk[4], mx[4];
};

// ---------------- device math helpers ----------------
__device__ __forceinline__ float wsum64(float v) {
#pragma unroll
  for (int m = 32; m; m >>= 1) v += __shfl_xor(v, m, 64);
  return v;
}

__device__ __forceinline__ float tan_k_d(float x, float kv, float sk) {
  if (kv > 0.f) return tanf(x * sk) / sk;
  if (kv < 0.f) return tanhf(x * sk) / sk;
  return x;
}

__device__ __forceinline__ float artan_k_d(float x, float kv, float sk) {
  if (kv > 0.f) return atanf(x * sk) / sk;
  if (kv < 0.f) {
    float t = x * sk;
    t = fminf(fmaxf(t, -1.f + 1e-7f), 1.f - 1e-7f);
    return atanhf(t) / sk;
  }
  return x;
}

__device__ __forceinline__ float proj_scale_d(float n, float kv, float maxn) {
  if (kv < 0.f && n > maxn) return maxn / n;
  return 1.f;
}

// ---------------- graph preprocessing ----------------
__global__ void k_init(float* __restrict__ deg, int n) {
  int i = blockIdx.x * 256 + threadIdx.x;
  if (i < n) deg[i] = 1.0f;  // self loop
}

__global__ void k_counts(const int* __restrict__ batch, int* __restrict__ boff,
                         float* __restrict__ counts, int n) {
  int b = threadIdx.x;  // 0..255
  if (b <= 128) {
    int lo = 0, hi = n;
    while (lo < hi) {
      int mid = (lo + hi) >> 1;
      if (batch[mid] < b) lo = mid + 1; else hi = mid;
    }
    boff[b] = lo;
  }
  __syncthreads();
  if (b < 128) counts[b] = (float)(boff[b + 1] - boff[b]);
}

__global__ void k_deg(const int* __restrict__ ei, float* __restrict__ deg, int e) {
  int i = blockIdx.x * 256 + threadIdx.x;
  if (i < e) atomicAdd(&deg[ei[e + i]], 1.0f);  // col = edge_index[1]
}

__global__ void k_dinv(float* __restrict__ deg, int* __restrict__ ideg, int n) {
  int i = blockIdx.x * 256 + threadIdx.x;
  if (i < n) {
    float d = deg[i];
    ideg[i] = (int)(d + 0.5f);
    deg[i] = 1.0f / sqrtf(d);  // deg buffer becomes dinv
  }
}

// ---------------- parallel scan (3 kernels) ----------------
__global__ void k_scanA(const int* __restrict__ ideg, int* __restrict__ bsum, int n) {
  __shared__ int ls[4];
  int i = blockIdx.x * 256 + threadIdx.x;
  int v = (i < n) ? ideg[i] : 0;
#pragma unroll
  for (int m = 1; m < 64; m <<= 1) v += __shfl_xor(v, m, 64);
  if ((threadIdx.x & 63) == 0) ls[threadIdx.x >> 6] = v;
  __syncthreads();
  if (threadIdx.x == 0) bsum[blockIdx.x] = ls[0] + ls[1] + ls[2] + ls[3];
}

__global__ void k_scanB(int* __restrict__ bsum, int nb) {
  __shared__ int wsh[4];
  int tid = threadIdx.x;
  int lane = tid & 63, w = tid >> 6;
  int v = (tid < nb) ? bsum[tid] : 0;
  int x = v;
#pragma unroll
  for (int o = 1; o < 64; o <<= 1) {
    int t = __shfl_up(x, o, 64);
    if (lane >= o) x += t;
  }
  if (lane == 63) wsh[w] = x;
  __syncthreads();
  int add = 0;
  for (int k2 = 0; k2 < w; k2++) add += wsh[k2];
  if (tid < nb) bsum[tid] = add + x - v;  // exclusive
}

__global__ void k_scanC(const int* __restrict__ ideg, const int* __restrict__ bsum,
                        int* __restrict__ off, int* __restrict__ cursor, int n) {
  __shared__ int wsh[4];
  int i = blockIdx.x * 256 + threadIdx.x;
  int lane = threadIdx.x & 63, w = threadIdx.x >> 6;
  int v = (i < n) ? ideg[i] : 0;
  int x = v;
#pragma unroll
  for (int o = 1; o < 64; o <<= 1) {
    int t = __shfl_up(x, o, 64);
    if (lane >= o) x += t;
  }
  if (lane == 63) wsh[w] = x;
  __syncthreads();
  int add = bsum[blockIdx.x];
  for (int k2 = 0; k2 < w; k2++) add += wsh[k2];
  int excl = add + x - v;
  if (i < n) {
    off[i] = excl;
    cursor[i] = excl;
  }
  if (i == n - 1) off[n] = excl + v;
}

// ---------------- chunk head nodes (run containing first edge of each chunk) ----------------
__global__ void k_bnodes(const int* __restrict__ off, int* __restrict__ bnode, int nchunk,
                         int n) {
  int g = blockIdx.x * 256 + threadIdx.x;
  if (g >= nchunk) return;
  int e0 = g * CHUNK;
  int lo = 0, hi = n;
  while (hi - lo > 1) {
    int mid = (lo + hi) >> 1;
    if (off[mid] <= e0) lo = mid; else hi = mid;
  }
  bnode[g] = lo;
}

// zero only boundary rows (atomic targets) of agg
__global__ void k_zerob(const int* __restrict__ bnode, float* __restrict__ agg, int nchunk) {
  int g = blockIdx.x * 4 + (threadIdx.x >> 6);
  int lane = threadIdx.x & 63;
  if (g >= nchunk) return;
  int nd = bnode[g];
  if (g > 0 && bnode[g - 1] == nd) return;
  ((float2*)agg)[(size_t)nd * 64 + lane] = make_float2(0.f, 0.f);
}

// ---------------- edge placement: perm scatter + sequential-write gather ----------------
__global__ void k_place1(const int* __restrict__ ei, int* __restrict__ cursor,
                         int* __restrict__ perm, int e, int n) {
  int i = blockIdx.x * 256 + threadIdx.x;
  int et = e + n;
  if (i >= et) return;
  int c = (i < e) ? ei[e + i] : i - e;
  int p = atomicAdd(&cursor[c], 1);
  perm[p] = i;
}

__global__ void k_place2(const int* __restrict__ ei, const float* __restrict__ dinv,
                         const int* __restrict__ perm, int2* __restrict__ esw, int e, int n) {
  int q = blockIdx.x * 256 + threadIdx.x;
  int et = e + n;
  if (q >= et) return;
  int i = perm[q];
  int r_ = (i < e) ? ei[i] : i - e;
  int c_ = (i < e) ? ei[e + i] : i - e;
  esw[q] = make_int2(r_, __float_as_int(dinv[r_] * dinv[c_]));
}

// ---------------- x -> f16 hi/lo split (unscaled, shared across experts) ----------------
__global__ void k_xsplit(const float* __restrict__ x, f16* __restrict__ xhi,
                         f16* __restrict__ xlo, int n64) {
  int i = blockIdx.x * 256 + threadIdx.x;
  if (i >= n64) return;
  float2 v = ((const float2*)x)[i];
  f16x2 h, l;
  h[0] = (f16)v.x; l[0] = (f16)(v.x - (float)h[0]);
  h[1] = (f16)v.y; l[1] = (f16)(v.y - (float)h[1]);
  ((f16x2*)xhi)[i] = h;
  ((f16x2*)xlo)[i] = l;
}

// ---------------- per-node prep: raw norm of x + all 4 expert expmap0 scales ----------------
__global__ void k_nodeprep(const float* __restrict__ x, float* __restrict__ scl,
                           float* __restrict__ xnk, int n, CurvPack cp) {
  int wid = blockIdx.x * 4 + (threadIdx.x >> 6);
  int lane = threadIdx.x & 63;
  if (wid >= n) return;
  float2 v = ((const float2*)x)[(size_t)wid * 64 + lane];
  float n2 = wsum64(v.x * v.x + v.y * v.y);
  float nraw = sqrtf(n2);
  if (lane < 4) {
    float kv = cp.k[lane], sk = cp.sk[lane], maxn = cp.mx[lane];
    float nnv = fmaxf(nraw, 1e-15f);
    float tk = tan_k_d(nnv, kv, sk);
    float s = tk / nnv;
    float pn = fmaxf(fabsf(tk) * (nraw / nnv), 1e-15f);
    float ps = proj_scale_d(pn, kv, maxn);
    scl[(size_t)lane * n + wid] = s * ps;
    xnk[(size_t)lane * n + wid] = pn * ps;
  }
}

// ---------------- bias points: expmap0(b) for all 8 (expert,layer) pairs ----------------
__global__ void k_biaspt_all(const float* __restrict__ eb1, const float* __restrict__ eb2,
                             float* __restrict__ biasb, CurvPack cp) {
  __shared__ float l2[2];
  int blk = blockIdx.x;  // ex*2 + layer
  int ex = blk >> 1, layer = blk & 1;
  float kv = cp.k[ex], sk = cp.sk[ex], maxn = cp.mx[ex];
  const float* b = (layer ? eb2 : eb1) + ex * 128;
  float* outb = biasb + blk * 132;
  int j = threadIdx.x;  // 0..127
  float v = b[j];
  float n2 = wsum64(v * v);
  if ((j & 63) == 0) l2[j >> 6] = n2;
  __syncthreads();
  n2 = l2[0] + l2[1];
  float nraw = sqrtf(n2);
  float nnv = fmaxf(nraw, 1e-15f);
  float tk = tan_k_d(nnv, kv, sk);
  float s = tk / nnv;
  float pn = fmaxf(fabsf(tk) * (nraw / nnv), 1e-15f);
  float ps = proj_scale_d(pn, kv, maxn);
  float bp = ps * s * v;
  outb[j] = bp;
  float y2v = wsum64(bp * bp);
  __syncthreads();
  if ((j & 63) == 0) l2[j >> 6] = y2v;
  __syncthreads();
  if (j == 0) outb[128] = l2[0] + l2[1];
}

// ---------------- W -> fp16 hi/lo split (8 slots of 128x128) ----------------
__global__ void k_w2h(const float* __restrict__ ew1, const float* __restrict__ ew2,
                      f16* __restrict__ whi, f16* __restrict__ wlo) {
  int i = blockIdx.x * 256 + threadIdx.x;
  if (i >= 8 * 16384) return;
  int slot = i >> 14;
  int r = i & 16383;
  int ex = slot >> 1, layer = slot & 1;
  float w = (layer ? ew2 : ew1)[ex * 16384 + r];
  f16 h = (f16)w;
  whi[i] = h;
  wlo[i] = (f16)(w - (float)h);
}

// ---------------- MFMA expert GEMM (pre-split f16 A, scale in epilogue) ----------------
// Block = 256 thr = 4 waves; each wave does 16 nodes x 32 cols (2 jt). Cross-wave
// epilogue reductions via 1KB LDS. (s*x)@W^T == s*(x@W^T): scale folded into epilogue.
__global__ __launch_bounds__(256) void k_matmfma(
    const f16* __restrict__ ahi, const f16* __restrict__ alo,
    const float* __restrict__ scale, const float* __restrict__ xnorm,
    const f16* __restrict__ whi, const f16* __restrict__ wlo,
    const float* __restrict__ biasb, f16* __restrict__ tout, int n, float kv, float sk,
    float maxn) {
  __shared__ float red[4][16][4];  // [s0,s1,s2,t0][node][wave]
  int tid = threadIdx.x;
  int w = tid >> 6;
  int lane = tid & 63;
  int col = lane & 15;
  int quad = lane >> 4;
  int n0w = blockIdx.x * 16;
  if (n0w >= n) return;

  int anodec = min(n0w + col, n - 1);
  const f16* ahrow = ahi + (size_t)anodec * 128;
  const f16* alrow = alo + (size_t)anodec * 128;
  int jt0 = w * 2;

  f32x4 acc[2];
  acc[0] = (f32x4){0.f, 0.f, 0.f, 0.f};
  acc[1] = (f32x4){0.f, 0.f, 0.f, 0.f};

#pragma unroll
  for (int kc = 0; kc < 4; kc++) {
    int kb = kc * 32 + quad * 8;
    f16x8 Ah = *(const f16x8*)(ahrow + kb);
    f16x8 Al = *(const f16x8*)(alrow + kb);
#pragma unroll
    for (int j2 = 0; j2 < 2; j2++) {
      const f16* bh = whi + (size_t)((jt0 + j2) * 16 + col) * 128 + kb;
      const f16* bl = wlo + (size_t)((jt0 + j2) * 16 + col) * 128 + kb;
      f16x8 Bh = *(const f16x8*)bh;
      f16x8 Bl = *(const f16x8*)bl;
      acc[j2] = __builtin_amdgcn_mfma_f32_16x16x32_f16(Ah, Bh, acc[j2], 0, 0, 0);
      acc[j2] = __builtin_amdgcn_mfma_f32_16x16x32_f16(Ah, Bl, acc[j2], 0, 0, 0);
      acc[j2] = __builtin_amdgcn_mfma_f32_16x16x32_f16(Al, Bh, acc[j2], 0, 0, 0);
    }
  }

  float bpj[2];
  bpj[0] = biasb[jt0 * 16 + col];
  bpj[1] = biasb[(jt0 + 1) * 16 + col];
  float y2 = biasb[128];

  // per-node expmap0 scale (output row = node quad*4+r)
  float sc4[4];
#pragma unroll
  for (int r = 0; r < 4; r++)
    sc4[r] = scale ? scale[min(n0w + quad * 4 + r, n - 1)] : 1.f;

  // phase 1: partial sums over this wave's 32 cols (scaled values)
  float S0[4], S1[4], S2[4];
#pragma unroll
  for (int r = 0; r < 4; r++) {
    float s0 = 0.f, s1 = 0.f, s2 = 0.f;
#pragma unroll
    for (int j2 = 0; j2 < 2; j2++) {
      float v = sc4[r] * acc[j2][r];
      s0 = fmaf(v, v, s0);
      s1 += fabsf(v);
      s2 = fmaf(v, bpj[j2], s2);
    }
#pragma unroll
    for (int m = 1; m < 16; m <<= 1) {
      s0 += __shfl_xor(s0, m, 64);
      s1 += __shfl_xor(s1, m, 64);
      s2 += __shfl_xor(s2, m, 64);
    }
    S0[r] = s0;
    S1[r] = s1;
    S2[r] = s2;
  }
  if (col == 0) {
#pragma unroll
    for (int r = 0; r < 4; r++) {
      red[0][quad * 4 + r][w] = S0[r];
      red[1][quad * 4 + r][w] = S1[r];
      red[2][quad * 4 + r][w] = S2[r];
    }
  }
  __syncthreads();

  float As[4], Cs[4];
#pragma unroll
  for (int r = 0; r < 4; r++) {
    int idx = quad * 4 + r;
    float s0f = red[0][idx][0] + red[0][idx][1] + red[0][idx][2] + red[0][idx][3];
    float s1f = red[1][idx][0] + red[1][idx][1] + red[1][idx][2] + red[1][idx][3];
    float s2f = red[2][idx][0] + red[2][idx][1] + red[2][idx][2] + red[2][idx][3];
    float xnr = xnorm[min(n0w + idx, n - 1)];
    float xn = fmaxf(xnr, 1e-15f);
    float mxraw = sqrtf(s0f);
    float mxv = fmaxf(mxraw, 1e-15f);
    float ar = artan_k_d(xn, kv, sk);
    float c1 = tan_k_d(mxv / xn * ar, kv, sk);
    float s = (s1f == 0.f) ? 0.f : c1 / mxv;
    float pn = fmaxf(fabsf(c1) * (mxraw / mxv), 1e-15f);
    float ps = (s1f == 0.f) ? 1.f : proj_scale_d(pn, kv, maxn);
    s *= ps;
    float x2 = (s * s) * s0f;
    float xy = s * s2f;
    float A = 1.f - 2.f * kv * xy - kv * y2;
    float Cc = 1.f + kv * x2;
    float den = fmaxf(1.f - 2.f * kv * xy + (kv * kv) * x2 * y2, 1e-15f);
    As[r] = A * s / den;
    Cs[r] = Cc / den;
  }

  // phase 2: t0 partial
  float T0[4];
#pragma unroll
  for (int r = 0; r < 4; r++) {
    float t0 = 0.f;
#pragma unroll
    for (int j2 = 0; j2 < 2; j2++) {
      float v = fmaf(As[r], sc4[r] * acc[j2][r], Cs[r] * bpj[j2]);
      t0 = fmaf(v, v, t0);
    }
#pragma unroll
    for (int m = 1; m < 16; m <<= 1) t0 += __shfl_xor(t0, m, 64);
    T0[r] = t0;
  }
  if (col == 0) {
#pragma unroll
    for (int r = 0; r < 4; r++) red[3][quad * 4 + r][w] = T0[r];
  }
  __syncthreads();

#pragma unroll
  for (int r = 0; r < 4; r++) {
    int idx = quad * 4 + r;
    int gnode = n0w + idx;
    float t0f = red[3][idx][0] + red[3][idx][1] + red[3][idx][2] + red[3][idx][3];
    float nraw = sqrtf(t0f);
    float ps2 = proj_scale_d(fmaxf(nraw, 1e-15f), kv, maxn);
    float nh = fmaxf(ps2 * nraw, 1e-15f);
    float L = artan_k_d(nh, kv, sk) / nh * ps2;
    if (gnode < n) {
      f16* trow = tout + (size_t)gnode * 128;
#pragma unroll
      for (int j2 = 0; j2 < 2; j2++) {
        float v = fmaf(As[r], sc4[r] * acc[j2][r], Cs[r] * bpj[j2]);
        trow[(jt0 + j2) * 16 + col] = (f16)(L * v);
      }
    }
  }
}

// ---------------- edge-sweep aggregation: agg[dst] += w * t[src] (fp16 rows) ----------------
__global__ __launch_bounds__(256) void k_aggE(const int2* __restrict__ esw,
                                              const int* __restrict__ off,
                                              const int* __restrict__ bnode,
                                              const f16x2* __restrict__ t,
                                              float* __restrict__ agg, int etot, int n) {
  int gw = blockIdx.x * 4 + (threadIdx.x >> 6);
  int lane = threadIdx.x & 63;
  int e0 = gw * CHUNK;
  if (e0 >= etot) return;
  int e1 = min(e0 + CHUNK, etot);
  int cur = bnode[gw];
  int runStart = off[cur];
  int eend = off[cur + 1];
  float ax = 0.f, ay = 0.f;
  int j = e0;
  while (j < e1) {
    if (j + 16 <= e1 && eend >= j + 16) {
      int2 m[16];
#pragma unroll
      for (int q = 0; q < 16; q++) m[q] = esw[j + q];
      f16x2 r[16];
#pragma unroll
      for (int q = 0; q < 16; q++) {
        int s = __builtin_amdgcn_readfirstlane(m[q].x);
        r[q] = t[(size_t)s * 64 + lane];
      }
#pragma unroll
      for (int q = 0; q < 16; q++) {
        float w = __int_as_float(m[q].y);
        ax = fmaf(w, (float)r[q][0], ax);
        ay = fmaf(w, (float)r[q][1], ay);
      }
      j += 16;
    } else if (j + 8 <= e1 && eend >= j + 8) {
      int2 m[8];
#pragma unroll
      for (int q = 0; q < 8; q++) m[q] = esw[j + q];
      f16x2 r[8];
#pragma unroll
      for (int q = 0; q < 8; q++) {
        int s = __builtin_amdgcn_readfirstlane(m[q].x);
        r[q] = t[(size_t)s * 64 + lane];
      }
#pragma unroll
      for (int q = 0; q < 8; q++) {
        float w = __int_as_float(m[q].y);
        ax = fmaf(w, (float)r[q][0], ax);
        ay = fmaf(w, (float)r[q][1], ay);
      }
      j += 8;
    } else if (j + 4 <= e1 && eend >= j + 4) {
      int2 m[4];
#pragma unroll
      for (int q = 0; q < 4; q++) m[q] = esw[j + q];
      f16x2 r[4];
#pragma unroll
      for (int q = 0; q < 4; q++) {
        int s = __builtin_amdgcn_readfirstlane(m[q].x);
        r[q] = t[(size_t)s * 64 + lane];
      }
#pragma unroll
      for (int q = 0; q < 4; q++) {
        float w = __int_as_float(m[q].y);
        ax = fmaf(w, (float)r[q][0], ax);
        ay = fmaf(w, (float)r[q][1], ay);
      }
      j += 4;
    } else {
      if (j == eend) {
        float* dp = agg + (size_t)cur * 128 + lane * 2;
        if (runStart >= e0) {
          dp[0] = ax;
          dp[1] = ay;
        } else {
          atomicAdd(dp, ax);
          atomicAdd(dp + 1, ay);
        }
        ax = ay = 0.f;
        runStart = j;
        cur++;
        eend = off[cur + 1];
      }
      int2 m = esw[j];
      int s = __builtin_amdgcn_readfirstlane(m.x);
      f16x2 rv = t[(size_t)s * 64 + lane];
      float w = __int_as_float(m.y);
      ax = fmaf(w, (float)rv[0], ax);
      ay = fmaf(w, (float)rv[1], ay);
      j++;
    }
  }
  float* dp = agg + (size_t)cur * 128 + lane * 2;
  if (runStart >= e0 && eend <= e1) {
    dp[0] = ax;
    dp[1] = ay;
  } else {
    atomicAdd(dp, ax);
    atomicAdd(dp + 1, ay);
  }
}

// ---------------- post-agg: expmap0 scale + f16 hi/lo split of agg ----------------
__global__ void k_postnorm(const float* __restrict__ agg, float* __restrict__ scl,
                           float* __restrict__ xnk, f16* __restrict__ aggh,
                           f16* __restrict__ aggl, int n, float kv, float sk, float maxn) {
  int wid = blockIdx.x * 4 + (threadIdx.x >> 6);
  int lane = threadIdx.x & 63;
  if (wid >= n) return;
  float2 v = ((const float2*)agg)[(size_t)wid * 64 + lane];
  f16x2 h, l;
  h[0] = (f16)v.x; l[0] = (f16)(v.x - (float)h[0]);
  h[1] = (f16)v.y; l[1] = (f16)(v.y - (float)h[1]);
  ((f16x2*)aggh)[(size_t)wid * 64 + lane] = h;
  ((f16x2*)aggl)[(size_t)wid * 64 + lane] = l;
  float n2 = wsum64(fmaf(v.x, v.x, v.y * v.y));
  float nraw = sqrtf(n2);
  float nnv = fmaxf(nraw, 1e-15f);
  float tk = tan_k_d(nnv, kv, sk);
  float s = tk / nnv;
  float pn = fmaxf(fabsf(tk) * (nraw / nnv), 1e-15f);
  float ps = proj_scale_d(pn, kv, maxn);
  if (lane == 0) {
    scl[wid] = s * ps;
    xnk[wid] = pn * ps;
  }
}

// ---------------- post-agg: per-node pooling scale sc = logmap0 o expmap0 ----------------
__global__ void k_postscale(const float* __restrict__ agg, float* __restrict__ scpool, int n,
                            float kv, float sk, float maxn) {
  int wid = blockIdx.x * 4 + (threadIdx.x >> 6);
  int lane = threadIdx.x & 63;
  if (wid >= n) return;
  float2 v = ((const float2*)agg)[(size_t)wid * 64 + lane];
  float n2 = wsum64(fmaf(v.x, v.x, v.y * v.y));
  float nraw = sqrtf(n2);
  float nnv = fmaxf(nraw, 1e-15f);
  float tk = tan_k_d(nnv, kv, sk);
  float s = tk / nnv;
  float pn = fmaxf(fabsf(tk) * (nraw / nnv), 1e-15f);
  float ps = proj_scale_d(pn, kv, maxn);
  s *= ps;
  float nh = fmaxf(pn * ps, 1e-15f);
  float sc = artan_k_d(nh, kv, sk) / nh * s;
  if (lane == 0) scpool[wid] = sc;
}

// ---------------- strip pooling: feats[b] += sc[node]*agg[node] ----------------
__global__ void k_pooladd(const float* __restrict__ agg, const float* __restrict__ scpool,
                          const int* __restrict__ boff, float* __restrict__ feats, int ex,
                          int n) {
  int gw = blockIdx.x * 4 + (threadIdx.x >> 6);
  int lane = threadIdx.x & 63;
  int n0 = gw * PCH;
  if (n0 >= n) return;
  int n1 = min(n0 + PCH, n);
  int lo = 0, hi = 128;
  while (hi - lo > 1) {
    int mid = (lo + hi) >> 1;
    if (boff[mid] <= n0) lo = mid; else hi = mid;
  }
  int cb = lo;
  int bend = boff[cb + 1];
  float ax = 0.f, ay = 0.f;
  for (int node = n0; node < n1; node++) {
    while (node == bend) {
      float* dp = &feats[(size_t)cb * 512 + ex * 128 + lane * 2];
      atomicAdd(dp, ax);
      atomicAdd(dp + 1, ay);
      ax = ay = 0.f;
      cb++;
      bend = boff[cb + 1];
    }
    float sc = scpool[node];
    float2 v = ((const float2*)agg)[(size_t)node * 64 + lane];
    ax = fmaf(sc, v.x, ax);
    ay = fmaf(sc, v.y, ay);
  }
  float* dp = &feats[(size_t)cb * 512 + ex * 128 + lane * 2];
  atomicAdd(dp, ax);
  atomicAdd(dp + 1, ay);
}

// ---------------- strip pooling: hgate[b] += relu(agg[node]+bias) ----------------
__global__ void k_poolgate(const float* __restrict__ agg, const float* __restrict__ bias,
                           const int* __restrict__ boff, float* __restrict__ hgate, int n) {
  int gw = blockIdx.x * 4 + (threadIdx.x >> 6);
  int lane = threadIdx.x & 63;
  int n0 = gw * PCH;
  if (n0 >= n) return;
  int n1 = min(n0 + PCH, n);
  int lo = 0, hi = 128;
  while (hi - lo > 1) {
    int mid = (lo + hi) >> 1;
    if (boff[mid] <= n0) lo = mid; else hi = mid;
  }
  int cb = lo;
  int bend = boff[cb + 1];
  float2 bb = ((const float2*)bias)[lane];
  float ax = 0.f, ay = 0.f;
  for (int node = n0; node < n1; node++) {
    while (node == bend) {
      float* dp = &hgate[(size_t)cb * 128 + lane * 2];
      atomicAdd(dp, ax);
      atomicAdd(dp + 1, ay);
      ax = ay = 0.f;
      cb++;
      bend = boff[cb + 1];
    }
    float2 v = ((const float2*)agg)[(size_t)node * 64 + lane];
    ax += fmaxf(v.x + bb.x, 0.f);
    ay += fmaxf(v.y + bb.y, 0.f);
  }
  float* dp = &hgate[(size_t)cb * 128 + lane * 2];
  atomicAdd(dp, ax);
  atomicAdd(dp + 1, ay);
}

// ---------------- gate GEMM 1: m1 = x @ gw1.T  [N,128] -> [N,32] ----------------
__global__ __launch_bounds__(256) void k_gate1(const float* __restrict__ x,
                                               const float* __restrict__ gw1,
                                               float* __restrict__ m1, int n) {
  __shared__ float xT[64][68];
  __shared__ float Wt[64][36];
  int tid = threadIdx.x;
  int n0 = blockIdx.x * 64;
  int c = tid & 7, r = tid >> 3;
  float acc[2][4];
#pragma unroll
  for (int i = 0; i < 2; i++)
#pragma unroll
    for (int jj = 0; jj < 4; jj++) acc[i][jj] = 0.f;

  for (int kc = 0; kc < 2; kc++) {
    if (kc) __syncthreads();
#pragma unroll
    for (int it = 0; it < 8; it++) {
      int u = tid + it * 256;
      int j = u >> 6, kd = u & 63;
      Wt[kd][j] = gw1[j * 128 + kc * 64 + kd];
    }
#pragma unroll
    for (int it = 0; it < 4; it++) {
      int u = tid + it * 256;
      int node = u >> 4, c4 = u & 15;
      float4 v = make_float4(0.f, 0.f, 0.f, 0.f);
      if (n0 + node < n) v = ((const float4*)x)[(size_t)(n0 + node) * 32 + kc * 16 + c4];
      xT[4 * c4 + 0][node] = v.x;
      xT[4 * c4 + 1][node] = v.y;
      xT[4 * c4 + 2][node] = v.z;
      xT[4 * c4 + 3][node] = v.w;
    }
    __syncthreads();
#pragma unroll 8
    for (int kd = 0; kd < 64; kd++) {
      float2 av = *(const float2*)&xT[kd][r * 2];
      float4 bv = *(const float4*)&Wt[kd][c * 4];
      float a[2] = {av.x, av.y};
      float bbv[4] = {bv.x, bv.y, bv.z, bv.w};
#pragma unroll
      for (int i = 0; i < 2; i++)
#pragma unroll
        for (int jj = 0; jj < 4; jj++) acc[i][jj] = fmaf(a[i], bbv[jj], acc[i][jj]);
    }
  }
#pragma unroll
  for (int i = 0; i < 2; i++) {
    int node = n0 + r * 2 + i;
    if (node >= n) continue;
    ((float4*)m1)[(size_t)node * 8 + c] = make_float4(acc[i][0], acc[i][1], acc[i][2], acc[i][3]);
  }
}

// ---------------- gate GEMM 2: m2 = g1 @ gw2.T  [N,32] -> [N,128] fp16 out ----------------
__global__ __launch_bounds__(256) void k_gate2(const float* __restrict__ g1,
                                               const float* __restrict__ gw2,
                                               f16* __restrict__ m2, int n) {
  __shared__ float xT[32][68];
  __shared__ float Wt[32][132];
  int tid = threadIdx.x;
  int n0 = blockIdx.x * 64;
  int c = tid & 15, r = tid >> 4;
  float acc[4][8];
#pragma unroll
  for (int i = 0; i < 4; i++)
#pragma unroll
    for (int jj = 0; jj < 8; jj++) acc[i][jj] = 0.f;

#pragma unroll
  for (int it = 0; it < 16; it++) {
    int u = tid + it * 256;
    int j = u >> 5, kd = u & 31;
    Wt[kd][j] = gw2[j * 32 + kd];
  }
#pragma unroll
  for (int it = 0; it < 2; it++) {
    int u = tid + it * 256;
    int node = u >> 3, c4 = u & 7;
    float4 v = make_float4(0.f, 0.f, 0.f, 0.f);
    if (n0 + node < n) v = ((const float4*)g1)[(size_t)(n0 + node) * 8 + c4];
    xT[4 * c4 + 0][node] = v.x;
    xT[4 * c4 + 1][node] = v.y;
    xT[4 * c4 + 2][node] = v.z;
    xT[4 * c4 + 3][node] = v.w;
  }
  __syncthreads();
#pragma unroll 8
  for (int kd = 0; kd < 32; kd++) {
    float4 av = *(const float4*)&xT[kd][r * 4];
    float4 b0 = *(const float4*)&Wt[kd][c * 8];
    float4 b1 = *(const float4*)&Wt[kd][c * 8 + 4];
    float a[4] = {av.x, av.y, av.z, av.w};
    float bbv[8] = {b0.x, b0.y, b0.z, b0.w, b1.x, b1.y, b1.z, b1.w};
#pragma unroll
    for (int i = 0; i < 4; i++)
#pragma unroll
      for (int jj = 0; jj < 8; jj++) acc[i][jj] = fmaf(a[i], bbv[jj], acc[i][jj]);
  }
#pragma unroll
  for (int i = 0; i < 4; i++) {
    int node = n0 + r * 4 + i;
    if (node >= n) continue;
    f16x8 hv;
#pragma unroll
    for (int jj = 0; jj < 8; jj++) hv[jj] = (f16)acc[i][jj];
    *((f16x8*)(m2 + (size_t)node * 128) + c) = hv;
  }
}

// ---------------- gate aggregation dim32 + bias + relu (node-parallel) ----------------
__global__ void k_agg_relu32(const float* __restrict__ m1, const int* __restrict__ off,
                             const int2* __restrict__ esw, const float* __restrict__ bias,
                             float* __restrict__ g1, int n) {
  int node = blockIdx.x * 4 + (threadIdx.x >> 6);
  int lane = threadIdx.x & 63;
  if (node >= n) return;
  int grp = lane >> 3, l8 = lane & 7;
  int e0 = off[node], e1 = off[node + 1];
  float4 acc = make_float4(0.f, 0.f, 0.f, 0.f);
  for (int base = e0 + grp; base < e1; base += 8) {
    int2 me = esw[base];
    int ss = me.x;
    float ww = __int_as_float(me.y);
    float4 tv = ((const float4*)m1)[(size_t)ss * 8 + l8];
    acc.x = fmaf(ww, tv.x, acc.x);
    acc.y = fmaf(ww, tv.y, acc.y);
    acc.z = fmaf(ww, tv.z, acc.z);
    acc.w = fmaf(ww, tv.w, acc.w);
  }
#pragma unroll
  for (int m = 8; m <= 32; m <<= 1) {
    acc.x += __shfl_xor(acc.x, m, 64);
    acc.y += __shfl_xor(acc.y, m, 64);
    acc.z += __shfl_xor(acc.z, m, 64);
    acc.w += __shfl_xor(acc.w, m, 64);
  }
  if (grp == 0) {
    float4 bb = ((const float4*)bias)[l8];
    float4 o = make_float4(fmaxf(acc.x + bb.x, 0.f), fmaxf(acc.y + bb.y, 0.f),
                           fmaxf(acc.z + bb.z, 0.f), fmaxf(acc.w + bb.w, 0.f));
    ((float4*)g1)[(size_t)node * 8 + l8] = o;
  }
}

// ---------------- final: distance gate + softmax + outputs ----------------
__global__ __launch_bounds__(128) void k_final(const float* __restrict__ feats,
                                               const float* __restrict__ hgate,
                                               const float* __restrict__ counts,
                                               const float* __restrict__ gate_u,
                                               const float* __restrict__ tau_raw,
                                               float* __restrict__ out, CurvPack cp) {
  __shared__ float l2[2];
  int b = blockIdx.x;
  int j = threadIdx.x;
  float cnt = fmaxf(counts[b], 1.f);
  float hg = hgate[(size_t)b * 128 + j] / cnt;

  auto bsum = [&](float v) -> float {
    v = wsum64(v);
    __syncthreads();
    if ((j & 63) == 0) l2[j >> 6] = v;
    __syncthreads();
    return l2[0] + l2[1];
  };

  float nhg2 = bsum(hg * hg);
  float nhgraw = sqrtf(nhg2);
  float nhg = fmaxf(nhgraw, 1e-15f);

  float d[4], tau[4];
#pragma unroll
  for (int i = 0; i < 4; i++) {
    float kv = cp.k[i], sk = cp.sk[i], mxn = cp.mx[i];
    float tk = tan_k_d(nhg, kv, sk);
    float s = tk / nhg;
    float pn = fmaxf(fabsf(tk) * (nhgraw / nhg), 1e-15f);
    s *= proj_scale_d(pn, kv, mxn);
    float zk = s * hg;

    float u = gate_u[i * 128 + j];
    float nu2 = bsum(u * u);
    float nuraw = sqrtf(nu2);
    float nu = fmaxf(nuraw, 1e-15f);
    float tku = tan_k_d(nu, kv, sk);
    float su = tku / nu;
    float pnu = fmaxf(fabsf(tku) * (nuraw / nu), 1e-15f);
    su *= proj_scale_d(pnu, kv, mxn);
    float yk = su * u;

    float xv = -zk;
    float x2 = bsum(xv * xv);
    float y2 = bsum(yk * yk);
    float xy = bsum(xv * yk);
    float A = 1.f - 2.f * kv * xy - kv * y2;
    float C = 1.f + kv * x2;
    float den = fmaxf(1.f - 2.f * kv * xy + (kv * kv) * x2 * y2, 1e-15f);
    float ma = (A * xv + C * yk) / den;
    float m2 = bsum(ma * ma);
    float mraw = sqrtf(m2);
    float ps2 = proj_scale_d(fmaxf(mraw, 1e-15f), kv, mxn);
    float nm = fmaxf(ps2 * mraw, 1e-15f);
    d[i] = 2.f * artan_k_d(nm, kv, sk);

    float tr = tau_raw[i];
    tau[i] = fminf(fmaxf(log1pf(expf(tr)) + 0.05f, 0.05f), 10.f);
  }

  float xi[4];
  float mxv = -1e30f;
#pragma unroll
  for (int i = 0; i < 4; i++) {
    xi[i] = -d[i] / tau[i];
    mxv = fmaxf(mxv, xi[i]);
  }
  float es = 0.f, e[4];
#pragma unroll
  for (int i = 0; i < 4; i++) {
    e[i] = expf(xi[i] - mxv);
    es += e[i];
  }
  float w[4];
#pragma unroll
  for (int i = 0; i < 4; i++) w[i] = e[i] / es;

#pragma unroll
  for (int i = 0; i < 4; i++)
    out[(size_t)b * 512 + i * 128 + j] = feats[(size_t)b * 512 + i * 128 + j] / cnt * w[i];

  if (j < 4) {
    out[65536 + b * 4 + j] = w[j];
    out[66048 + b * 4 + j] = d[j];
  }
  if (b == 0 && j < 4) out[66560 + j] = tau[j];
}

// ---------------- host launcher ----------------
extern "C" void kernel_launch(void* const* d_in, const int* in_sizes, int n_in,
                              void* d_out, int out_size, void* d_ws, size_t ws_size,
                              hipStream_t stream) {
  const float* x = (const float*)d_in[0];
  const int* ei = (const int*)d_in[1];
  const int* batch = (const int*)d_in[2];
  const float* ew1 = (const float*)d_in[3];
  const float* eb1 = (const float*)d_in[4];
  const float* ew2 = (const float*)d_in[5];
  const float* eb2 = (const float*)d_in[6];
  const float* gw1 = (const float*)d_in[7];
  const float* gb1 = (const float*)d_in[8];
  const float* gw2 = (const float*)d_in[9];
  const float* gb2 = (const float*)d_in[10];
  const float* gu = (const float*)d_in[11];
  const float* traw = (const float*)d_in[12];
  float* out = (float*)d_out;

  const int N = NN, E = EE, ET = ETOT, B = BB;

  float* ws = (float*)d_ws;
  size_t o = 0;
  f16* tbh = (f16*)ws;      o += (size_t)N * 64;  // N*128 halfs
  float* agg = ws + o;      o += (size_t)N * 128;
  f16* xhi = (f16*)(ws + o);    o += (size_t)N * 64;
  f16* xlo = (f16*)(ws + o);    o += (size_t)N * 64;
  f16* aggh = (f16*)(ws + o);   o += (size_t)N * 64;
  f16* aggl = (f16*)(ws + o);   o += (size_t)N * 64;
  float* m1 = ws + o;       o += (size_t)N * 32;
  float* g1 = ws + o;       o += (size_t)N * 32;
  float* deg = ws + o;      o += N;  // becomes dinv
  float* scl1 = ws + o;     o += (size_t)4 * N;
  float* xnk1 = ws + o;     o += (size_t)4 * N;
  float* scl2 = ws + o;     o += N;
  float* xnk2 = ws + o;     o += N;
  float* scpool = ws + o;   o += N;
  float* counts = ws + o;   o += 256;
  float* feats = ws + o;    o += (size_t)B * 512;
  float* hg = ws + o;       o += (size_t)B * 128;
  float* biasb = ws + o;    o += 8 * 132;
  f16* whi = (f16*)(ws + o);    o += 8 * 16384 / 2;
  f16* wlo = (f16*)(ws + o);    o += 8 * 16384 / 2;
  int* ideg = (int*)(ws + o);   o += N;
  int* csroff = (int*)(ws + o); o += N + 8;
  int* cursor = (int*)(ws + o); o += N;
  int* boff = (int*)(ws + o);   o += 136;
  int* bsum = (int*)(ws + o);   o += 256;
  int* bnode = (int*)(ws + o);  o += NCHUNK + 8;
  int* perm = (int*)(ws + o);   o += ET;
  int2* esw = (int2*)(ws + o);  o += (size_t)2 * ET;

  // zero: counts + feats + hg (contiguous)
  hipMemsetAsync(counts, 0, (256 + (size_t)B * 512 + (size_t)B * 128) * sizeof(float), stream);

  const double curvs[4] = {-1.0, 0.0, 1.0, -0.5};
  CurvPack cp;
  for (int i = 0; i < 4; i++) {
    double kd = curvs[i];
    double skd = sqrt(fabs(kd));
    cp.k[i] = (float)kd;
    cp.sk[i] = (float)skd;
    cp.mx[i] = (kd < 0) ? (float)((1.0 - 1e-5) / skd) : 3.0e38f;
  }

  k_init<<<(N + 255) / 256, 256, 0, stream>>>(deg, N);
  k_counts<<<1, 256, 0, stream>>>(batch, boff, counts, N);
  k_deg<<<(E + 255) / 256, 256, 0, stream>>>(ei, deg, E);
  k_dinv<<<(N + 255) / 256, 256, 0, stream>>>(deg, ideg, N);
  k_scanA<<<SCB, 256, 0, stream>>>(ideg, bsum, N);
  k_scanB<<<1, 256, 0, stream>>>(bsum, SCB);
  k_scanC<<<SCB, 256, 0, stream>>>(ideg, bsum, csroff, cursor, N);
  k_bnodes<<<(NCHUNK + 255) / 256, 256, 0, stream>>>(csroff, bnode, NCHUNK, N);
  k_place1<<<(ET + 255) / 256, 256, 0, stream>>>(ei, cursor, perm, E, N);
  k_place2<<<(ET + 255) / 256, 256, 0, stream>>>(ei, deg, perm, esw, E, N);
  k_nodeprep<<<(N + 3) / 4, 256, 0, stream>>>(x, scl1, xnk1, N, cp);
  k_xsplit<<<(N * 64 + 255) / 256, 256, 0, stream>>>(x, xhi, xlo, N * 64);
  k_biaspt_all<<<8, 128, 0, stream>>>(eb1, eb2, biasb, cp);
  k_w2h<<<512, 256, 0, stream>>>(ew1, ew2, whi, wlo);

  const int aggBlocks = (NCHUNK + 3) / 4;
  const int zbBlocks = (NCHUNK + 3) / 4;
  const int poolBlocks = ((N + PCH - 1) / PCH + 3) / 4;
  const int mfmaBlocks = (N + 15) / 16;

  for (int ex = 0; ex < 4; ex++) {
    float kv = cp.k[ex], sk = cp.sk[ex], mxn = cp.mx[ex];
    int s1 = ex * 2, s2 = ex * 2 + 1;
    // layer 1 (expmap0 scale folded into epilogue; shared unscaled x split)
    k_matmfma<<<mfmaBlocks, 256, 0, stream>>>(xhi, xlo, scl1 + (size_t)ex * N,
                                              xnk1 + (size_t)ex * N, whi + (size_t)s1 * 16384,
                                              wlo + (size_t)s1 * 16384, biasb + s1 * 132, tbh, N,
                                              kv, sk, mxn);
    k_zerob<<<zbBlocks, 256, 0, stream>>>(bnode, agg, NCHUNK);
    k_aggE<<<aggBlocks, 256, 0, stream>>>(esw, csroff, bnode, (const f16x2*)tbh, agg, ET, N);
    k_postnorm<<<(N + 3) / 4, 256, 0, stream>>>(agg, scl2, xnk2, aggh, aggl, N, kv, sk, mxn);
    // layer 2 (input split produced by postnorm)
    k_matmfma<<<mfmaBlocks, 256, 0, stream>>>(aggh, aggl, scl2, xnk2, whi + (size_t)s2 * 16384,
                                              wlo + (size_t)s2 * 16384, biasb + s2 * 132, tbh, N,
                                              kv, sk, mxn);
    k_zerob<<<zbBlocks, 256, 0, stream>>>(bnode, agg, NCHUNK);
    k_aggE<<<aggBlocks, 256, 0, stream>>>(esw, csroff, bnode, (const f16x2*)tbh, agg, ET, N);
    k_postscale<<<(N + 3) / 4, 256, 0, stream>>>(agg, scpool, N, kv, sk, mxn);
    k_pooladd<<<poolBlocks, 256, 0, stream>>>(agg, scpool, boff, feats, ex, N);
  }

  // gate GCN
  k_gate1<<<(N + 63) / 64, 256, 0, stream>>>(x, gw1, m1, N);
  k_agg_relu32<<<(N + 3) / 4, 256, 0, stream>>>(m1, csroff, esw, gb1, g1, N);
  k_gate2<<<(N + 63) / 64, 256, 0, stream>>>(g1, gw2, tbh, N);
  k_zerob<<<zbBlocks, 256, 0, stream>>>(bnode, agg, NCHUNK);
  k_aggE<<<aggBlocks, 256, 0, stream>>>(esw, csroff, bnode, (const f16x2*)tbh, agg, ET, N);
  k_poolgate<<<poolBlocks, 256, 0, stream>>>(agg, gb2, boff, hg, N);

  k_final<<<B, 128, 0, stream>>>(feats, hg, counts, gu, traw, out, cp);

  (void)in_sizes; (void)n_in; (void)out_size; (void)ws_size;
}

// Round 9
// 1260.657 us; speedup vs baseline: 1.1776x; 1.0811x over previous
//
#include <hip/hip_runtime.h>
#include <math.h>

// ---------------- constants ----------------
#define NN 50000
#define EE 800000
#define ETOT (EE + NN)
#define BB 128
#define DIM 128
#define GHID 32
#define CHUNK 128
#define NCHUNK ((ETOT + CHUNK - 1) / CHUNK)
#define PCH 16
#define SCB 196  // scan blocks: 196*256 >= 50000

typedef _Float16 f16;
typedef _Float16 f16x2 __attribute__((ext_vector_type(2)));
typedef _Float16 f16x8 __attribute__((ext_vector_type(8)));
typedef float f32x4 __attribute__((ext_vector_type(4)));

struct CurvPack {
  float k[4], sk[4], mx[4];
};

// ---------------- device math helpers ----------------
__device__ __forceinline__ float wsum64(float v) {
#pragma unroll
  for (int m = 32; m; m >>= 1) v += __shfl_xor(v, m, 64);
  return v;
}

__device__ __forceinline__ float tan_k_d(float x, float kv, float sk) {
  if (kv > 0.f) return tanf(x * sk) / sk;
  if (kv < 0.f) return tanhf(x * sk) / sk;
  return x;
}

__device__ __forceinline__ float artan_k_d(float x, float kv, float sk) {
  if (kv > 0.f) return atanf(x * sk) / sk;
  if (kv < 0.f) {
    float t = x * sk;
    t = fminf(fmaxf(t, -1.f + 1e-7f), 1.f - 1e-7f);
    return atanhf(t) / sk;
  }
  return x;
}

__device__ __forceinline__ float proj_scale_d(float n, float kv, float maxn) {
  if (kv < 0.f && n > maxn) return maxn / n;
  return 1.f;
}

// ---------------- graph preprocessing ----------------
__global__ void k_init(float* __restrict__ deg, int n) {
  int i = blockIdx.x * 256 + threadIdx.x;
  if (i < n) deg[i] = 1.0f;  // self loop
}

__global__ void k_counts(const int* __restrict__ batch, int* __restrict__ boff,
                         float* __restrict__ counts, int n) {
  int b = threadIdx.x;  // 0..255
  if (b <= 128) {
    int lo = 0, hi = n;
    while (lo < hi) {
      int mid = (lo + hi) >> 1;
      if (batch[mid] < b) lo = mid + 1; else hi = mid;
    }
    boff[b] = lo;
  }
  __syncthreads();
  if (b < 128) counts[b] = (float)(boff[b + 1] - boff[b]);
}

__global__ void k_deg(const int* __restrict__ ei, float* __restrict__ deg, int e) {
  int i = blockIdx.x * 256 + threadIdx.x;
  if (i < e) atomicAdd(&deg[ei[e + i]], 1.0f);  // col = edge_index[1]
}

__global__ void k_dinv(float* __restrict__ deg, int* __restrict__ ideg, int n) {
  int i = blockIdx.x * 256 + threadIdx.x;
  if (i < n) {
    float d = deg[i];
    ideg[i] = (int)(d + 0.5f);
    deg[i] = 1.0f / sqrtf(d);  // deg buffer becomes dinv
  }
}

// ---------------- parallel scan (3 kernels) ----------------
__global__ void k_scanA(const int* __restrict__ ideg, int* __restrict__ bsum, int n) {
  __shared__ int ls[4];
  int i = blockIdx.x * 256 + threadIdx.x;
  int v = (i < n) ? ideg[i] : 0;
#pragma unroll
  for (int m = 1; m < 64; m <<= 1) v += __shfl_xor(v, m, 64);
  if ((threadIdx.x & 63) == 0) ls[threadIdx.x >> 6] = v;
  __syncthreads();
  if (threadIdx.x == 0) bsum[blockIdx.x] = ls[0] + ls[1] + ls[2] + ls[3];
}

__global__ void k_scanB(int* __restrict__ bsum, int nb) {
  __shared__ int wsh[4];
  int tid = threadIdx.x;
  int lane = tid & 63, w = tid >> 6;
  int v = (tid < nb) ? bsum[tid] : 0;
  int x = v;
#pragma unroll
  for (int o = 1; o < 64; o <<= 1) {
    int t = __shfl_up(x, o, 64);
    if (lane >= o) x += t;
  }
  if (lane == 63) wsh[w] = x;
  __syncthreads();
  int add = 0;
  for (int k2 = 0; k2 < w; k2++) add += wsh[k2];
  if (tid < nb) bsum[tid] = add + x - v;  // exclusive
}

__global__ void k_scanC(const int* __restrict__ ideg, const int* __restrict__ bsum,
                        int* __restrict__ off, int* __restrict__ cursor, int n) {
  __shared__ int wsh[4];
  int i = blockIdx.x * 256 + threadIdx.x;
  int lane = threadIdx.x & 63, w = threadIdx.x >> 6;
  int v = (i < n) ? ideg[i] : 0;
  int x = v;
#pragma unroll
  for (int o = 1; o < 64; o <<= 1) {
    int t = __shfl_up(x, o, 64);
    if (lane >= o) x += t;
  }
  if (lane == 63) wsh[w] = x;
  __syncthreads();
  int add = bsum[blockIdx.x];
  for (int k2 = 0; k2 < w; k2++) add += wsh[k2];
  int excl = add + x - v;
  if (i < n) {
    off[i] = excl;
    cursor[i] = excl;
  }
  if (i == n - 1) off[n] = excl + v;
}

// ---------------- chunk head nodes ----------------
__global__ void k_bnodes(const int* __restrict__ off, int* __restrict__ bnode, int nchunk,
                         int n) {
  int g = blockIdx.x * 256 + threadIdx.x;
  if (g >= nchunk) return;
  int e0 = g * CHUNK;
  int lo = 0, hi = n;
  while (hi - lo > 1) {
    int mid = (lo + hi) >> 1;
    if (off[mid] <= e0) lo = mid; else hi = mid;
  }
  bnode[g] = lo;
}

// zero only boundary rows (atomic targets) of agg
__global__ void k_zerob(const int* __restrict__ bnode, float* __restrict__ agg, int nchunk) {
  int g = blockIdx.x * 4 + (threadIdx.x >> 6);
  int lane = threadIdx.x & 63;
  if (g >= nchunk) return;
  int nd = bnode[g];
  if (g > 0 && bnode[g - 1] == nd) return;
  ((float2*)agg)[(size_t)nd * 64 + lane] = make_float2(0.f, 0.f);
}

// ---------------- edge placement ----------------
__global__ void k_place1(const int* __restrict__ ei, int* __restrict__ cursor,
                         int* __restrict__ perm, int e, int n) {
  int i = blockIdx.x * 256 + threadIdx.x;
  int et = e + n;
  if (i >= et) return;
  int c = (i < e) ? ei[e + i] : i - e;
  int p = atomicAdd(&cursor[c], 1);
  perm[p] = i;
}

__global__ void k_place2(const int* __restrict__ ei, const float* __restrict__ dinv,
                         const int* __restrict__ perm, int2* __restrict__ esw, int e, int n) {
  int q = blockIdx.x * 256 + threadIdx.x;
  int et = e + n;
  if (q >= et) return;
  int i = perm[q];
  int r_ = (i < e) ? ei[i] : i - e;
  int c_ = (i < e) ? ei[e + i] : i - e;
  esw[q] = make_int2(r_, __float_as_int(dinv[r_] * dinv[c_]));
}

// ---------------- x -> f16 hi/lo split ----------------
__global__ void k_xsplit(const float* __restrict__ x, f16* __restrict__ xhi,
                         f16* __restrict__ xlo, int n64) {
  int i = blockIdx.x * 256 + threadIdx.x;
  if (i >= n64) return;
  float2 v = ((const float2*)x)[i];
  f16x2 h, l;
  h[0] = (f16)v.x; l[0] = (f16)(v.x - (float)h[0]);
  h[1] = (f16)v.y; l[1] = (f16)(v.y - (float)h[1]);
  ((f16x2*)xhi)[i] = h;
  ((f16x2*)xlo)[i] = l;
}

// ---------------- per-node prep ----------------
__global__ void k_nodeprep(const float* __restrict__ x, float* __restrict__ scl,
                           float* __restrict__ xnk, int n, CurvPack cp) {
  int wid = blockIdx.x * 4 + (threadIdx.x >> 6);
  int lane = threadIdx.x & 63;
  if (wid >= n) return;
  float2 v = ((const float2*)x)[(size_t)wid * 64 + lane];
  float n2 = wsum64(v.x * v.x + v.y * v.y);
  float nraw = sqrtf(n2);
  if (lane < 4) {
    float kv = cp.k[lane], sk = cp.sk[lane], maxn = cp.mx[lane];
    float nnv = fmaxf(nraw, 1e-15f);
    float tk = tan_k_d(nnv, kv, sk);
    float s = tk / nnv;
    float pn = fmaxf(fabsf(tk) * (nraw / nnv), 1e-15f);
    float ps = proj_scale_d(pn, kv, maxn);
    scl[(size_t)lane * n + wid] = s * ps;
    xnk[(size_t)lane * n + wid] = pn * ps;
  }
}

// ---------------- bias points ----------------
__global__ void k_biaspt_all(const float* __restrict__ eb1, const float* __restrict__ eb2,
                             float* __restrict__ biasb, CurvPack cp) {
  __shared__ float l2[2];
  int blk = blockIdx.x;  // ex*2 + layer
  int ex = blk >> 1, layer = blk & 1;
  float kv = cp.k[ex], sk = cp.sk[ex], maxn = cp.mx[ex];
  const float* b = (layer ? eb2 : eb1) + ex * 128;
  float* outb = biasb + blk * 132;
  int j = threadIdx.x;  // 0..127
  float v = b[j];
  float n2 = wsum64(v * v);
  if ((j & 63) == 0) l2[j >> 6] = n2;
  __syncthreads();
  n2 = l2[0] + l2[1];
  float nraw = sqrtf(n2);
  float nnv = fmaxf(nraw, 1e-15f);
  float tk = tan_k_d(nnv, kv, sk);
  float s = tk / nnv;
  float pn = fmaxf(fabsf(tk) * (nraw / nnv), 1e-15f);
  float ps = proj_scale_d(pn, kv, maxn);
  float bp = ps * s * v;
  outb[j] = bp;
  float y2v = wsum64(bp * bp);
  __syncthreads();
  if ((j & 63) == 0) l2[j >> 6] = y2v;
  __syncthreads();
  if (j == 0) outb[128] = l2[0] + l2[1];
}

// ---------------- W -> fp16 hi/lo split ----------------
__global__ void k_w2h(const float* __restrict__ ew1, const float* __restrict__ ew2,
                      f16* __restrict__ whi, f16* __restrict__ wlo) {
  int i = blockIdx.x * 256 + threadIdx.x;
  if (i >= 8 * 16384) return;
  int slot = i >> 14;
  int r = i & 16383;
  int ex = slot >> 1, layer = slot & 1;
  float w = (layer ? ew2 : ew1)[ex * 16384 + r];
  f16 h = (f16)w;
  whi[i] = h;
  wlo[i] = (f16)(w - (float)h);
}

// ---------------- MFMA expert GEMM + deduped epilogue ----------------
// Block = 256 thr = 4 waves; wave w computes 16 nodes x 32 cols. Per-node
// transcendental epilogue computed by 16 threads only (via LDS), then broadcast.
__global__ __launch_bounds__(256) void k_matmfma(
    const f16* __restrict__ ahi, const f16* __restrict__ alo,
    const float* __restrict__ scale, const float* __restrict__ xnorm,
    const f16* __restrict__ whi, const f16* __restrict__ wlo,
    const float* __restrict__ biasb, f16* __restrict__ tout, int n, float kv, float sk,
    float maxn) {
  __shared__ float red[3][16][4];   // unscaled partials [s0,s1,s2][node][wave]
  __shared__ float redT[16][4];     // t0 partials
  __shared__ float nAs[16], nCs[16], nL[16];
  int tid = threadIdx.x;
  int w = tid >> 6;
  int lane = tid & 63;
  int col = lane & 15;
  int quad = lane >> 4;
  int n0w = blockIdx.x * 16;
  if (n0w >= n) return;

  int anodec = min(n0w + col, n - 1);
  const f16* ahrow = ahi + (size_t)anodec * 128;
  const f16* alrow = alo + (size_t)anodec * 128;
  int jt0 = w * 2;

  f32x4 acc[2];
  acc[0] = (f32x4){0.f, 0.f, 0.f, 0.f};
  acc[1] = (f32x4){0.f, 0.f, 0.f, 0.f};

#pragma unroll
  for (int kc = 0; kc < 4; kc++) {
    int kb = kc * 32 + quad * 8;
    f16x8 Ah = *(const f16x8*)(ahrow + kb);
    f16x8 Al = *(const f16x8*)(alrow + kb);
#pragma unroll
    for (int j2 = 0; j2 < 2; j2++) {
      const f16* bh = whi + (size_t)((jt0 + j2) * 16 + col) * 128 + kb;
      const f16* bl = wlo + (size_t)((jt0 + j2) * 16 + col) * 128 + kb;
      f16x8 Bh = *(const f16x8*)bh;
      f16x8 Bl = *(const f16x8*)bl;
      acc[j2] = __builtin_amdgcn_mfma_f32_16x16x32_f16(Ah, Bh, acc[j2], 0, 0, 0);
      acc[j2] = __builtin_amdgcn_mfma_f32_16x16x32_f16(Ah, Bl, acc[j2], 0, 0, 0);
      acc[j2] = __builtin_amdgcn_mfma_f32_16x16x32_f16(Al, Bh, acc[j2], 0, 0, 0);
    }
  }

  float bpj[2];
  bpj[0] = biasb[jt0 * 16 + col];
  bpj[1] = biasb[(jt0 + 1) * 16 + col];
  float y2 = biasb[128];

  // phase 1: UNSCALED partial sums over this wave's 32 cols
#pragma unroll
  for (int r = 0; r < 4; r++) {
    float s0 = 0.f, s1 = 0.f, s2 = 0.f;
#pragma unroll
    for (int j2 = 0; j2 < 2; j2++) {
      float v = acc[j2][r];
      s0 = fmaf(v, v, s0);
      s1 += fabsf(v);
      s2 = fmaf(v, bpj[j2], s2);
    }
#pragma unroll
    for (int m = 1; m < 16; m <<= 1) {
      s0 += __shfl_xor(s0, m, 64);
      s1 += __shfl_xor(s1, m, 64);
      s2 += __shfl_xor(s2, m, 64);
    }
    if (col == 0) {
      red[0][quad * 4 + r][w] = s0;
      red[1][quad * 4 + r][w] = s1;
      red[2][quad * 4 + r][w] = s2;
    }
  }
  __syncthreads();

  // 16-thread section: apply scale, run transcendentals once per node
  if (tid < 16) {
    int gnode = min(n0w + tid, n - 1);
    float sc = scale ? scale[gnode] : 1.f;
    float s0f = (red[0][tid][0] + red[0][tid][1] + red[0][tid][2] + red[0][tid][3]) * sc * sc;
    float s1f = (red[1][tid][0] + red[1][tid][1] + red[1][tid][2] + red[1][tid][3]) * fabsf(sc);
    float s2f = (red[2][tid][0] + red[2][tid][1] + red[2][tid][2] + red[2][tid][3]) * sc;
    float xnr = xnorm[gnode];
    float xn = fmaxf(xnr, 1e-15f);
    float mxraw = sqrtf(s0f);
    float mxv = fmaxf(mxraw, 1e-15f);
    float ar = artan_k_d(xn, kv, sk);
    float c1 = tan_k_d(mxv / xn * ar, kv, sk);
    float s = (s1f == 0.f) ? 0.f : c1 / mxv;
    float pn = fmaxf(fabsf(c1) * (mxraw / mxv), 1e-15f);
    float ps = (s1f == 0.f) ? 1.f : proj_scale_d(pn, kv, maxn);
    s *= ps;
    float x2 = (s * s) * s0f;
    float xy = s * s2f;
    float A = 1.f - 2.f * kv * xy - kv * y2;
    float Cc = 1.f + kv * x2;
    float den = fmaxf(1.f - 2.f * kv * xy + (kv * kv) * x2 * y2, 1e-15f);
    nAs[tid] = A * s / den * sc;  // folded: applies to UNSCALED acc
    nCs[tid] = Cc / den;
  }
  __syncthreads();

  // phase 2: t0 partials with folded As
#pragma unroll
  for (int r = 0; r < 4; r++) {
    int idx = quad * 4 + r;
    float Asc = nAs[idx], Cs = nCs[idx];
    float t0 = 0.f;
#pragma unroll
    for (int j2 = 0; j2 < 2; j2++) {
      float v = fmaf(Asc, acc[j2][r], Cs * bpj[j2]);
      t0 = fmaf(v, v, t0);
    }
#pragma unroll
    for (int m = 1; m < 16; m <<= 1) t0 += __shfl_xor(t0, m, 64);
    if (col == 0) redT[idx][w] = t0;
  }
  __syncthreads();

  if (tid < 16) {
    float t0f = redT[tid][0] + redT[tid][1] + redT[tid][2] + redT[tid][3];
    float nraw = sqrtf(t0f);
    float ps2 = proj_scale_d(fmaxf(nraw, 1e-15f), kv, maxn);
    float nh = fmaxf(ps2 * nraw, 1e-15f);
    nL[tid] = artan_k_d(nh, kv, sk) / nh * ps2;
  }
  __syncthreads();

#pragma unroll
  for (int r = 0; r < 4; r++) {
    int idx = quad * 4 + r;
    int gnode = n0w + idx;
    if (gnode >= n) continue;
    float Asc = nAs[idx], Cs = nCs[idx], L = nL[idx];
    f16* trow = tout + (size_t)gnode * 128;
#pragma unroll
    for (int j2 = 0; j2 < 2; j2++) {
      float v = fmaf(Asc, acc[j2][r], Cs * bpj[j2]);
      trow[(jt0 + j2) * 16 + col] = (f16)(L * v);
    }
  }
}

// ---------------- edge-sweep aggregation ----------------
__global__ __launch_bounds__(256) void k_aggE(const int2* __restrict__ esw,
                                              const int* __restrict__ off,
                                              const int* __restrict__ bnode,
                                              const f16x2* __restrict__ t,
                                              float* __restrict__ agg, int etot, int n) {
  int gw = blockIdx.x * 4 + (threadIdx.x >> 6);
  int lane = threadIdx.x & 63;
  int e0 = gw * CHUNK;
  if (e0 >= etot) return;
  int e1 = min(e0 + CHUNK, etot);
  int cur = bnode[gw];
  int runStart = off[cur];
  int eend = off[cur + 1];
  float ax = 0.f, ay = 0.f;
  int j = e0;
  while (j < e1) {
    if (j + 16 <= e1 && eend >= j + 16) {
      int2 m[16];
#pragma unroll
      for (int q = 0; q < 16; q++) m[q] = esw[j + q];
      f16x2 r[16];
#pragma unroll
      for (int q = 0; q < 16; q++) {
        int s = __builtin_amdgcn_readfirstlane(m[q].x);
        r[q] = t[(size_t)s * 64 + lane];
      }
#pragma unroll
      for (int q = 0; q < 16; q++) {
        float w = __int_as_float(m[q].y);
        ax = fmaf(w, (float)r[q][0], ax);
        ay = fmaf(w, (float)r[q][1], ay);
      }
      j += 16;
    } else if (j + 8 <= e1 && eend >= j + 8) {
      int2 m[8];
#pragma unroll
      for (int q = 0; q < 8; q++) m[q] = esw[j + q];
      f16x2 r[8];
#pragma unroll
      for (int q = 0; q < 8; q++) {
        int s = __builtin_amdgcn_readfirstlane(m[q].x);
        r[q] = t[(size_t)s * 64 + lane];
      }
#pragma unroll
      for (int q = 0; q < 8; q++) {
        float w = __int_as_float(m[q].y);
        ax = fmaf(w, (float)r[q][0], ax);
        ay = fmaf(w, (float)r[q][1], ay);
      }
      j += 8;
    } else if (j + 4 <= e1 && eend >= j + 4) {
      int2 m[4];
#pragma unroll
      for (int q = 0; q < 4; q++) m[q] = esw[j + q];
      f16x2 r[4];
#pragma unroll
      for (int q = 0; q < 4; q++) {
        int s = __builtin_amdgcn_readfirstlane(m[q].x);
        r[q] = t[(size_t)s * 64 + lane];
      }
#pragma unroll
      for (int q = 0; q < 4; q++) {
        float w = __int_as_float(m[q].y);
        ax = fmaf(w, (float)r[q][0], ax);
        ay = fmaf(w, (float)r[q][1], ay);
      }
      j += 4;
    } else {
      if (j == eend) {
        float* dp = agg + (size_t)cur * 128 + lane * 2;
        if (runStart >= e0) {
          dp[0] = ax;
          dp[1] = ay;
        } else {
          atomicAdd(dp, ax);
          atomicAdd(dp + 1, ay);
        }
        ax = ay = 0.f;
        runStart = j;
        cur++;
        eend = off[cur + 1];
      }
      int2 m = esw[j];
      int s = __builtin_amdgcn_readfirstlane(m.x);
      f16x2 rv = t[(size_t)s * 64 + lane];
      float w = __int_as_float(m.y);
      ax = fmaf(w, (float)rv[0], ax);
      ay = fmaf(w, (float)rv[1], ay);
      j++;
    }
  }
  float* dp = agg + (size_t)cur * 128 + lane * 2;
  if (runStart >= e0 && eend <= e1) {
    dp[0] = ax;
    dp[1] = ay;
  } else {
    atomicAdd(dp, ax);
    atomicAdd(dp + 1, ay);
  }
}

// ---------------- post-agg: expmap0 scale + f16 hi/lo split of agg ----------------
__global__ void k_postnorm(const float* __restrict__ agg, float* __restrict__ scl,
                           float* __restrict__ xnk, f16* __restrict__ aggh,
                           f16* __restrict__ aggl, int n, float kv, float sk, float maxn) {
  int wid = blockIdx.x * 4 + (threadIdx.x >> 6);
  int lane = threadIdx.x & 63;
  if (wid >= n) return;
  float2 v = ((const float2*)agg)[(size_t)wid * 64 + lane];
  f16x2 h, l;
  h[0] = (f16)v.x; l[0] = (f16)(v.x - (float)h[0]);
  h[1] = (f16)v.y; l[1] = (f16)(v.y - (float)h[1]);
  ((f16x2*)aggh)[(size_t)wid * 64 + lane] = h;
  ((f16x2*)aggl)[(size_t)wid * 64 + lane] = l;
  float n2 = wsum64(fmaf(v.x, v.x, v.y * v.y));
  float nraw = sqrtf(n2);
  float nnv = fmaxf(nraw, 1e-15f);
  float tk = tan_k_d(nnv, kv, sk);
  float s = tk / nnv;
  float pn = fmaxf(fabsf(tk) * (nraw / nnv), 1e-15f);
  float ps = proj_scale_d(pn, kv, maxn);
  if (lane == 0) {
    scl[wid] = s * ps;
    xnk[wid] = pn * ps;
  }
}

// ---------------- post-agg: per-node pooling scale ----------------
__global__ void k_postscale(const float* __restrict__ agg, float* __restrict__ scpool, int n,
                            float kv, float sk, float maxn) {
  int wid = blockIdx.x * 4 + (threadIdx.x >> 6);
  int lane = threadIdx.x & 63;
  if (wid >= n) return;
  float2 v = ((const float2*)agg)[(size_t)wid * 64 + lane];
  float n2 = wsum64(fmaf(v.x, v.x, v.y * v.y));
  float nraw = sqrtf(n2);
  float nnv = fmaxf(nraw, 1e-15f);
  float tk = tan_k_d(nnv, kv, sk);
  float s = tk / nnv;
  float pn = fmaxf(fabsf(tk) * (nraw / nnv), 1e-15f);
  float ps = proj_scale_d(pn, kv, maxn);
  s *= ps;
  float nh = fmaxf(pn * ps, 1e-15f);
  float sc = artan_k_d(nh, kv, sk) / nh * s;
  if (lane == 0) scpool[wid] = sc;
}

// ---------------- strip pooling: feats ----------------
__global__ void k_pooladd(const float* __restrict__ agg, const float* __restrict__ scpool,
                          const int* __restrict__ boff, float* __restrict__ feats, int ex,
                          int n) {
  int gw = blockIdx.x * 4 + (threadIdx.x >> 6);
  int lane = threadIdx.x & 63;
  int n0 = gw * PCH;
  if (n0 >= n) return;
  int n1 = min(n0 + PCH, n);
  int lo = 0, hi = 128;
  while (hi - lo > 1) {
    int mid = (lo + hi) >> 1;
    if (boff[mid] <= n0) lo = mid; else hi = mid;
  }
  int cb = lo;
  int bend = boff[cb + 1];
  float ax = 0.f, ay = 0.f;
  for (int node = n0; node < n1; node++) {
    while (node == bend) {
      float* dp = &feats[(size_t)cb * 512 + ex * 128 + lane * 2];
      atomicAdd(dp, ax);
      atomicAdd(dp + 1, ay);
      ax = ay = 0.f;
      cb++;
      bend = boff[cb + 1];
    }
    float sc = scpool[node];
    float2 v = ((const float2*)agg)[(size_t)node * 64 + lane];
    ax = fmaf(sc, v.x, ax);
    ay = fmaf(sc, v.y, ay);
  }
  float* dp = &feats[(size_t)cb * 512 + ex * 128 + lane * 2];
  atomicAdd(dp, ax);
  atomicAdd(dp + 1, ay);
}

// ---------------- strip pooling: hgate ----------------
__global__ void k_poolgate(const float* __restrict__ agg, const float* __restrict__ bias,
                           const int* __restrict__ boff, float* __restrict__ hgate, int n) {
  int gw = blockIdx.x * 4 + (threadIdx.x >> 6);
  int lane = threadIdx.x & 63;
  int n0 = gw * PCH;
  if (n0 >= n) return;
  int n1 = min(n0 + PCH, n);
  int lo = 0, hi = 128;
  while (hi - lo > 1) {
    int mid = (lo + hi) >> 1;
    if (boff[mid] <= n0) lo = mid; else hi = mid;
  }
  int cb = lo;
  int bend = boff[cb + 1];
  float2 bb = ((const float2*)bias)[lane];
  float ax = 0.f, ay = 0.f;
  for (int node = n0; node < n1; node++) {
    while (node == bend) {
      float* dp = &hgate[(size_t)cb * 128 + lane * 2];
      atomicAdd(dp, ax);
      atomicAdd(dp + 1, ay);
      ax = ay = 0.f;
      cb++;
      bend = boff[cb + 1];
    }
    float2 v = ((const float2*)agg)[(size_t)node * 64 + lane];
    ax += fmaxf(v.x + bb.x, 0.f);
    ay += fmaxf(v.y + bb.y, 0.f);
  }
  float* dp = &hgate[(size_t)cb * 128 + lane * 2];
  atomicAdd(dp, ax);
  atomicAdd(dp + 1, ay);
}

// ---------------- gate GEMM 1 ----------------
__global__ __launch_bounds__(256) void k_gate1(const float* __restrict__ x,
                                               const float* __restrict__ gw1,
                                               float* __restrict__ m1, int n) {
  __shared__ float xT[64][68];
  __shared__ float Wt[64][36];
  int tid = threadIdx.x;
  int n0 = blockIdx.x * 64;
  int c = tid & 7, r = tid >> 3;
  float acc[2][4];
#pragma unroll
  for (int i = 0; i < 2; i++)
#pragma unroll
    for (int jj = 0; jj < 4; jj++) acc[i][jj] = 0.f;

  for (int kc = 0; kc < 2; kc++) {
    if (kc) __syncthreads();
#pragma unroll
    for (int it = 0; it < 8; it++) {
      int u = tid + it * 256;
      int j = u >> 6, kd = u & 63;
      Wt[kd][j] = gw1[j * 128 + kc * 64 + kd];
    }
#pragma unroll
    for (int it = 0; it < 4; it++) {
      int u = tid + it * 256;
      int node = u >> 4, c4 = u & 15;
      float4 v = make_float4(0.f, 0.f, 0.f, 0.f);
      if (n0 + node < n) v = ((const float4*)x)[(size_t)(n0 + node) * 32 + kc * 16 + c4];
      xT[4 * c4 + 0][node] = v.x;
      xT[4 * c4 + 1][node] = v.y;
      xT[4 * c4 + 2][node] = v.z;
      xT[4 * c4 + 3][node] = v.w;
    }
    __syncthreads();
#pragma unroll 8
    for (int kd = 0; kd < 64; kd++) {
      float2 av = *(const float2*)&xT[kd][r * 2];
      float4 bv = *(const float4*)&Wt[kd][c * 4];
      float a[2] = {av.x, av.y};
      float bbv[4] = {bv.x, bv.y, bv.z, bv.w};
#pragma unroll
      for (int i = 0; i < 2; i++)
#pragma unroll
        for (int jj = 0; jj < 4; jj++) acc[i][jj] = fmaf(a[i], bbv[jj], acc[i][jj]);
    }
  }
#pragma unroll
  for (int i = 0; i < 2; i++) {
    int node = n0 + r * 2 + i;
    if (node >= n) continue;
    ((float4*)m1)[(size_t)node * 8 + c] = make_float4(acc[i][0], acc[i][1], acc[i][2], acc[i][3]);
  }
}

// ---------------- gate GEMM 2 ----------------
__global__ __launch_bounds__(256) void k_gate2(const float* __restrict__ g1,
                                               const float* __restrict__ gw2,
                                               f16* __restrict__ m2, int n) {
  __shared__ float xT[32][68];
  __shared__ float Wt[32][132];
  int tid = threadIdx.x;
  int n0 = blockIdx.x * 64;
  int c = tid & 15, r = tid >> 4;
  float acc[4][8];
#pragma unroll
  for (int i = 0; i < 4; i++)
#pragma unroll
    for (int jj = 0; jj < 8; jj++) acc[i][jj] = 0.f;

#pragma unroll
  for (int it = 0; it < 16; it++) {
    int u = tid + it * 256;
    int j = u >> 5, kd = u & 31;
    Wt[kd][j] = gw2[j * 32 + kd];
  }
#pragma unroll
  for (int it = 0; it < 2; it++) {
    int u = tid + it * 256;
    int node = u >> 3, c4 = u & 7;
    float4 v = make_float4(0.f, 0.f, 0.f, 0.f);
    if (n0 + node < n) v = ((const float4*)g1)[(size_t)(n0 + node) * 8 + c4];
    xT[4 * c4 + 0][node] = v.x;
    xT[4 * c4 + 1][node] = v.y;
    xT[4 * c4 + 2][node] = v.z;
    xT[4 * c4 + 3][node] = v.w;
  }
  __syncthreads();
#pragma unroll 8
  for (int kd = 0; kd < 32; kd++) {
    float4 av = *(const float4*)&xT[kd][r * 4];
    float4 b0 = *(const float4*)&Wt[kd][c * 8];
    float4 b1 = *(const float4*)&Wt[kd][c * 8 + 4];
    float a[4] = {av.x, av.y, av.z, av.w};
    float bbv[8] = {b0.x, b0.y, b0.z, b0.w, b1.x, b1.y, b1.z, b1.w};
#pragma unroll
    for (int i = 0; i < 4; i++)
#pragma unroll
      for (int jj = 0; jj < 8; jj++) acc[i][jj] = fmaf(a[i], bbv[jj], acc[i][jj]);
  }
#pragma unroll
  for (int i = 0; i < 4; i++) {
    int node = n0 + r * 4 + i;
    if (node >= n) continue;
    f16x8 hv;
#pragma unroll
    for (int jj = 0; jj < 8; jj++) hv[jj] = (f16)acc[i][jj];
    *((f16x8*)(m2 + (size_t)node * 128) + c) = hv;
  }
}

// ---------------- gate aggregation dim32 ----------------
__global__ void k_agg_relu32(const float* __restrict__ m1, const int* __restrict__ off,
                             const int2* __restrict__ esw, const float* __restrict__ bias,
                             float* __restrict__ g1, int n) {
  int node = blockIdx.x * 4 + (threadIdx.x >> 6);
  int lane = threadIdx.x & 63;
  if (node >= n) return;
  int grp = lane >> 3, l8 = lane & 7;
  int e0 = off[node], e1 = off[node + 1];
  float4 acc = make_float4(0.f, 0.f, 0.f, 0.f);
  for (int base = e0 + grp; base < e1; base += 8) {
    int2 me = esw[base];
    int ss = me.x;
    float ww = __int_as_float(me.y);
    float4 tv = ((const float4*)m1)[(size_t)ss * 8 + l8];
    acc.x = fmaf(ww, tv.x, acc.x);
    acc.y = fmaf(ww, tv.y, acc.y);
    acc.z = fmaf(ww, tv.z, acc.z);
    acc.w = fmaf(ww, tv.w, acc.w);
  }
#pragma unroll
  for (int m = 8; m <= 32; m <<= 1) {
    acc.x += __shfl_xor(acc.x, m, 64);
    acc.y += __shfl_xor(acc.y, m, 64);
    acc.z += __shfl_xor(acc.z, m, 64);
    acc.w += __shfl_xor(acc.w, m, 64);
  }
  if (grp == 0) {
    float4 bb = ((const float4*)bias)[l8];
    float4 o = make_float4(fmaxf(acc.x + bb.x, 0.f), fmaxf(acc.y + bb.y, 0.f),
                           fmaxf(acc.z + bb.z, 0.f), fmaxf(acc.w + bb.w, 0.f));
    ((float4*)g1)[(size_t)node * 8 + l8] = o;
  }
}

// ---------------- final ----------------
__global__ __launch_bounds__(128) void k_final(const float* __restrict__ feats,
                                               const float* __restrict__ hgate,
                                               const float* __restrict__ counts,
                                               const float* __restrict__ gate_u,
                                               const float* __restrict__ tau_raw,
                                               float* __restrict__ out, CurvPack cp) {
  __shared__ float l2[2];
  int b = blockIdx.x;
  int j = threadIdx.x;
  float cnt = fmaxf(counts[b], 1.f);
  float hg = hgate[(size_t)b * 128 + j] / cnt;

  auto bsum = [&](float v) -> float {
    v = wsum64(v);
    __syncthreads();
    if ((j & 63) == 0) l2[j >> 6] = v;
    __syncthreads();
    return l2[0] + l2[1];
  };

  float nhg2 = bsum(hg * hg);
  float nhgraw = sqrtf(nhg2);
  float nhg = fmaxf(nhgraw, 1e-15f);

  float d[4], tau[4];
#pragma unroll
  for (int i = 0; i < 4; i++) {
    float kv = cp.k[i], sk = cp.sk[i], mxn = cp.mx[i];
    float tk = tan_k_d(nhg, kv, sk);
    float s = tk / nhg;
    float pn = fmaxf(fabsf(tk) * (nhgraw / nhg), 1e-15f);
    s *= proj_scale_d(pn, kv, mxn);
    float zk = s * hg;

    float u = gate_u[i * 128 + j];
    float nu2 = bsum(u * u);
    float nuraw = sqrtf(nu2);
    float nu = fmaxf(nuraw, 1e-15f);
    float tku = tan_k_d(nu, kv, sk);
    float su = tku / nu;
    float pnu = fmaxf(fabsf(tku) * (nuraw / nu), 1e-15f);
    su *= proj_scale_d(pnu, kv, mxn);
    float yk = su * u;

    float xv = -zk;
    float x2 = bsum(xv * xv);
    float y2 = bsum(yk * yk);
    float xy = bsum(xv * yk);
    float A = 1.f - 2.f * kv * xy - kv * y2;
    float C = 1.f + kv * x2;
    float den = fmaxf(1.f - 2.f * kv * xy + (kv * kv) * x2 * y2, 1e-15f);
    float ma = (A * xv + C * yk) / den;
    float m2 = bsum(ma * ma);
    float mraw = sqrtf(m2);
    float ps2 = proj_scale_d(fmaxf(mraw, 1e-15f), kv, mxn);
    float nm = fmaxf(ps2 * mraw, 1e-15f);
    d[i] = 2.f * artan_k_d(nm, kv, sk);

    float tr = tau_raw[i];
    tau[i] = fminf(fmaxf(log1pf(expf(tr)) + 0.05f, 0.05f), 10.f);
  }

  float xi[4];
  float mxv = -1e30f;
#pragma unroll
  for (int i = 0; i < 4; i++) {
    xi[i] = -d[i] / tau[i];
    mxv = fmaxf(mxv, xi[i]);
  }
  float es = 0.f, e[4];
#pragma unroll
  for (int i = 0; i < 4; i++) {
    e[i] = expf(xi[i] - mxv);
    es += e[i];
  }
  float w[4];
#pragma unroll
  for (int i = 0; i < 4; i++) w[i] = e[i] / es;

#pragma unroll
  for (int i = 0; i < 4; i++)
    out[(size_t)b * 512 + i * 128 + j] = feats[(size_t)b * 512 + i * 128 + j] / cnt * w[i];

  if (j < 4) {
    out[65536 + b * 4 + j] = w[j];
    out[66048 + b * 4 + j] = d[j];
  }
  if (b == 0 && j < 4) out[66560 + j] = tau[j];
}

// ---------------- host launcher ----------------
extern "C" void kernel_launch(void* const* d_in, const int* in_sizes, int n_in,
                              void* d_out, int out_size, void* d_ws, size_t ws_size,
                              hipStream_t stream) {
  const float* x = (const float*)d_in[0];
  const int* ei = (const int*)d_in[1];
  const int* batch = (const int*)d_in[2];
  const float* ew1 = (const float*)d_in[3];
  const float* eb1 = (const float*)d_in[4];
  const float* ew2 = (const float*)d_in[5];
  const float* eb2 = (const float*)d_in[6];
  const float* gw1 = (const float*)d_in[7];
  const float* gb1 = (const float*)d_in[8];
  const float* gw2 = (const float*)d_in[9];
  const float* gb2 = (const float*)d_in[10];
  const float* gu = (const float*)d_in[11];
  const float* traw = (const float*)d_in[12];
  float* out = (float*)d_out;

  const int N = NN, E = EE, ET = ETOT, B = BB;

  float* ws = (float*)d_ws;
  size_t o = 0;
  f16* tbh = (f16*)ws;      o += (size_t)N * 64;  // N*128 halfs
  float* agg = ws + o;      o += (size_t)N * 128;
  f16* xhi = (f16*)(ws + o);    o += (size_t)N * 64;
  f16* xlo = (f16*)(ws + o);    o += (size_t)N * 64;
  f16* aggh = (f16*)(ws + o);   o += (size_t)N * 64;
  f16* aggl = (f16*)(ws + o);   o += (size_t)N * 64;
  float* m1 = ws + o;       o += (size_t)N * 32;
  float* g1 = ws + o;       o += (size_t)N * 32;
  float* deg = ws + o;      o += N;  // becomes dinv
  float* scl1 = ws + o;     o += (size_t)4 * N;
  float* xnk1 = ws + o;     o += (size_t)4 * N;
  float* scl2 = ws + o;     o += N;
  float* xnk2 = ws + o;     o += N;
  float* scpool = ws + o;   o += N;
  float* counts = ws + o;   o += 256;
  float* feats = ws + o;    o += (size_t)B * 512;
  float* hg = ws + o;       o += (size_t)B * 128;
  float* biasb = ws + o;    o += 8 * 132;
  f16* whi = (f16*)(ws + o);    o += 8 * 16384 / 2;
  f16* wlo = (f16*)(ws + o);    o += 8 * 16384 / 2;
  int* ideg = (int*)(ws + o);   o += N;
  int* csroff = (int*)(ws + o); o += N + 8;
  int* cursor = (int*)(ws + o); o += N;
  int* boff = (int*)(ws + o);   o += 136;
  int* bsum = (int*)(ws + o);   o += 256;
  int* bnode = (int*)(ws + o);  o += NCHUNK + 8;
  int* perm = (int*)(ws + o);   o += ET;
  int2* esw = (int2*)(ws + o);  o += (size_t)2 * ET;

  // zero: counts + feats + hg (contiguous)
  hipMemsetAsync(counts, 0, (256 + (size_t)B * 512 + (size_t)B * 128) * sizeof(float), stream);

  const double curvs[4] = {-1.0, 0.0, 1.0, -0.5};
  CurvPack cp;
  for (int i = 0; i < 4; i++) {
    double kd = curvs[i];
    double skd = sqrt(fabs(kd));
    cp.k[i] = (float)kd;
    cp.sk[i] = (float)skd;
    cp.mx[i] = (kd < 0) ? (float)((1.0 - 1e-5) / skd) : 3.0e38f;
  }

  k_init<<<(N + 255) / 256, 256, 0, stream>>>(deg, N);
  k_counts<<<1, 256, 0, stream>>>(batch, boff, counts, N);
  k_deg<<<(E + 255) / 256, 256, 0, stream>>>(ei, deg, E);
  k_dinv<<<(N + 255) / 256, 256, 0, stream>>>(deg, ideg, N);
  k_scanA<<<SCB, 256, 0, stream>>>(ideg, bsum, N);
  k_scanB<<<1, 256, 0, stream>>>(bsum, SCB);
  k_scanC<<<SCB, 256, 0, stream>>>(ideg, bsum, csroff, cursor, N);
  k_bnodes<<<(NCHUNK + 255) / 256, 256, 0, stream>>>(csroff, bnode, NCHUNK, N);
  k_place1<<<(ET + 255) / 256, 256, 0, stream>>>(ei, cursor, perm, E, N);
  k_place2<<<(ET + 255) / 256, 256, 0, stream>>>(ei, deg, perm, esw, E, N);
  k_nodeprep<<<(N + 3) / 4, 256, 0, stream>>>(x, scl1, xnk1, N, cp);
  k_xsplit<<<(N * 64 + 255) / 256, 256, 0, stream>>>(x, xhi, xlo, N * 64);
  k_biaspt_all<<<8, 128, 0, stream>>>(eb1, eb2, biasb, cp);
  k_w2h<<<512, 256, 0, stream>>>(ew1, ew2, whi, wlo);

  const int aggBlocks = (NCHUNK + 3) / 4;
  const int zbBlocks = (NCHUNK + 3) / 4;
  const int poolBlocks = ((N + PCH - 1) / PCH + 3) / 4;
  const int mfmaBlocks = (N + 15) / 16;

  for (int ex = 0; ex < 4; ex++) {
    float kv = cp.k[ex], sk = cp.sk[ex], mxn = cp.mx[ex];
    int s1 = ex * 2, s2 = ex * 2 + 1;
    // layer 1
    k_matmfma<<<mfmaBlocks, 256, 0, stream>>>(xhi, xlo, scl1 + (size_t)ex * N,
                                              xnk1 + (size_t)ex * N, whi + (size_t)s1 * 16384,
                                              wlo + (size_t)s1 * 16384, biasb + s1 * 132, tbh, N,
                                              kv, sk, mxn);
    k_zerob<<<zbBlocks, 256, 0, stream>>>(bnode, agg, NCHUNK);
    k_aggE<<<aggBlocks, 256, 0, stream>>>(esw, csroff, bnode, (const f16x2*)tbh, agg, ET, N);
    k_postnorm<<<(N + 3) / 4, 256, 0, stream>>>(agg, scl2, xnk2, aggh, aggl, N, kv, sk, mxn);
    // layer 2
    k_matmfma<<<mfmaBlocks, 256, 0, stream>>>(aggh, aggl, scl2, xnk2, whi + (size_t)s2 * 16384,
                                              wlo + (size_t)s2 * 16384, biasb + s2 * 132, tbh, N,
                                              kv, sk, mxn);
    k_zerob<<<zbBlocks, 256, 0, stream>>>(bnode, agg, NCHUNK);
    k_aggE<<<aggBlocks, 256, 0, stream>>>(esw, csroff, bnode, (const f16x2*)tbh, agg, ET, N);
    k_postscale<<<(N + 3) / 4, 256, 0, stream>>>(agg, scpool, N, kv, sk, mxn);
    k_pooladd<<<poolBlocks, 256, 0, stream>>>(agg, scpool, boff, feats, ex, N);
  }

  // gate GCN
  k_gate1<<<(N + 63) / 64, 256, 0, stream>>>(x, gw1, m1, N);
  k_agg_relu32<<<(N + 3) / 4, 256, 0, stream>>>(m1, csroff, esw, gb1, g1, N);
  k_gate2<<<(N + 63) / 64, 256, 0, stream>>>(g1, gw2, tbh, N);
  k_zerob<<<zbBlocks, 256, 0, stream>>>(bnode, agg, NCHUNK);
  k_aggE<<<aggBlocks, 256, 0, stream>>>(esw, csroff, bnode, (const f16x2*)tbh, agg, ET, N);
  k_poolgate<<<poolBlocks, 256, 0, stream>>>(agg, gb2, boff, hg, N);

  k_final<<<B, 128, 0, stream>>>(feats, hg, counts, gu, traw, out, cp);

  (void)in_sizes; (void)n_in; (void)out_size; (void)ws_size;
}

// Round 10
// 1212.314 us; speedup vs baseline: 1.2246x; 1.0399x over previous
//
#include <hip/hip_runtime.h>
#include <math.h>

// ---------------- constants ----------------
#define NN 50000
#define EE 800000
#define ETOT (EE + NN)
#define BB 128
#define DIM 128
#define GHID 32
#define CHUNK 128
#define NCHUNK ((ETOT + CHUNK - 1) / CHUNK)
#define SCB 196  // scan blocks: 196*256 >= 50000

typedef _Float16 f16;
typedef _Float16 f16x2 __attribute__((ext_vector_type(2)));
typedef _Float16 f16x8 __attribute__((ext_vector_type(8)));
typedef float f32x4 __attribute__((ext_vector_type(4)));

struct CurvPack {
  float k[4], sk[4], mx[4];
};

// ---------------- device math helpers ----------------
__device__ __forceinline__ float wsum64(float v) {
#pragma unroll
  for (int m = 32; m; m >>= 1) v += __shfl_xor(v, m, 64);
  return v;
}

__device__ __forceinline__ float tan_k_d(float x, float kv, float sk) {
  if (kv > 0.f) return tanf(x * sk) / sk;
  if (kv < 0.f) return tanhf(x * sk) / sk;
  return x;
}

__device__ __forceinline__ float artan_k_d(float x, float kv, float sk) {
  if (kv > 0.f) return atanf(x * sk) / sk;
  if (kv < 0.f) {
    float t = x * sk;
    t = fminf(fmaxf(t, -1.f + 1e-7f), 1.f - 1e-7f);
    return atanhf(t) / sk;
  }
  return x;
}

__device__ __forceinline__ float proj_scale_d(float n, float kv, float maxn) {
  if (kv < 0.f && n > maxn) return maxn / n;
  return 1.f;
}

// ---------------- graph preprocessing ----------------
__global__ void k_init(float* __restrict__ deg, int n) {
  int i = blockIdx.x * 256 + threadIdx.x;
  if (i < n) deg[i] = 1.0f;  // self loop
}

__global__ void k_counts(const int* __restrict__ batch, int* __restrict__ boff,
                         float* __restrict__ counts, int n) {
  int b = threadIdx.x;  // 0..255
  if (b <= 128) {
    int lo = 0, hi = n;
    while (lo < hi) {
      int mid = (lo + hi) >> 1;
      if (batch[mid] < b) lo = mid + 1; else hi = mid;
    }
    boff[b] = lo;
  }
  __syncthreads();
  if (b < 128) counts[b] = (float)(boff[b + 1] - boff[b]);
}

__global__ void k_deg(const int* __restrict__ ei, float* __restrict__ deg, int e) {
  int i = blockIdx.x * 256 + threadIdx.x;
  if (i < e) atomicAdd(&deg[ei[e + i]], 1.0f);  // col = edge_index[1]
}

__global__ void k_dinv(float* __restrict__ deg, int* __restrict__ ideg, int n) {
  int i = blockIdx.x * 256 + threadIdx.x;
  if (i < n) {
    float d = deg[i];
    ideg[i] = (int)(d + 0.5f);
    deg[i] = 1.0f / sqrtf(d);  // deg buffer becomes dinv
  }
}

// ---------------- parallel scan (3 kernels) ----------------
__global__ void k_scanA(const int* __restrict__ ideg, int* __restrict__ bsum, int n) {
  __shared__ int ls[4];
  int i = blockIdx.x * 256 + threadIdx.x;
  int v = (i < n) ? ideg[i] : 0;
#pragma unroll
  for (int m = 1; m < 64; m <<= 1) v += __shfl_xor(v, m, 64);
  if ((threadIdx.x & 63) == 0) ls[threadIdx.x >> 6] = v;
  __syncthreads();
  if (threadIdx.x == 0) bsum[blockIdx.x] = ls[0] + ls[1] + ls[2] + ls[3];
}

__global__ void k_scanB(int* __restrict__ bsum, int nb) {
  __shared__ int wsh[4];
  int tid = threadIdx.x;
  int lane = tid & 63, w = tid >> 6;
  int v = (tid < nb) ? bsum[tid] : 0;
  int x = v;
#pragma unroll
  for (int o = 1; o < 64; o <<= 1) {
    int t = __shfl_up(x, o, 64);
    if (lane >= o) x += t;
  }
  if (lane == 63) wsh[w] = x;
  __syncthreads();
  int add = 0;
  for (int k2 = 0; k2 < w; k2++) add += wsh[k2];
  if (tid < nb) bsum[tid] = add + x - v;  // exclusive
}

__global__ void k_scanC(const int* __restrict__ ideg, const int* __restrict__ bsum,
                        int* __restrict__ off, int* __restrict__ cursor, int n) {
  __shared__ int wsh[4];
  int i = blockIdx.x * 256 + threadIdx.x;
  int lane = threadIdx.x & 63, w = threadIdx.x >> 6;
  int v = (i < n) ? ideg[i] : 0;
  int x = v;
#pragma unroll
  for (int o = 1; o < 64; o <<= 1) {
    int t = __shfl_up(x, o, 64);
    if (lane >= o) x += t;
  }
  if (lane == 63) wsh[w] = x;
  __syncthreads();
  int add = bsum[blockIdx.x];
  for (int k2 = 0; k2 < w; k2++) add += wsh[k2];
  int excl = add + x - v;
  if (i < n) {
    off[i] = excl;
    cursor[i] = excl;
  }
  if (i == n - 1) off[n] = excl + v;
}

// ---------------- chunk head nodes ----------------
__global__ void k_bnodes(const int* __restrict__ off, int* __restrict__ bnode, int nchunk,
                         int n) {
  int g = blockIdx.x * 256 + threadIdx.x;
  if (g >= nchunk) return;
  int e0 = g * CHUNK;
  int lo = 0, hi = n;
  while (hi - lo > 1) {
    int mid = (lo + hi) >> 1;
    if (off[mid] <= e0) lo = mid; else hi = mid;
  }
  bnode[g] = lo;
}

// zero only boundary rows (atomic targets) of agg
__global__ void k_zerob(const int* __restrict__ bnode, float* __restrict__ agg, int nchunk) {
  int g = blockIdx.x * 4 + (threadIdx.x >> 6);
  int lane = threadIdx.x & 63;
  if (g >= nchunk) return;
  int nd = bnode[g];
  if (g > 0 && bnode[g - 1] == nd) return;
  ((float2*)agg)[(size_t)nd * 64 + lane] = make_float2(0.f, 0.f);
}

// ---------------- edge placement: single-pass scatter ----------------
__global__ void k_place(const int* __restrict__ ei, const float* __restrict__ dinv,
                        int* __restrict__ cursor, int2* __restrict__ esw, int e, int n) {
  int i = blockIdx.x * 256 + threadIdx.x;
  int et = e + n;
  if (i >= et) return;
  int r_, c_;
  if (i < e) {
    r_ = ei[i];
    c_ = ei[e + i];
  } else {
    r_ = i - e;
    c_ = i - e;
  }
  int p = atomicAdd(&cursor[c_], 1);
  esw[p] = make_int2(r_, __float_as_int(dinv[r_] * dinv[c_]));
}

// ---------------- x -> f16 hi/lo split ----------------
__global__ void k_xsplit(const float* __restrict__ x, f16* __restrict__ xhi,
                         f16* __restrict__ xlo, int n64) {
  int i = blockIdx.x * 256 + threadIdx.x;
  if (i >= n64) return;
  float2 v = ((const float2*)x)[i];
  f16x2 h, l;
  h[0] = (f16)v.x; l[0] = (f16)(v.x - (float)h[0]);
  h[1] = (f16)v.y; l[1] = (f16)(v.y - (float)h[1]);
  ((f16x2*)xhi)[i] = h;
  ((f16x2*)xlo)[i] = l;
}

// ---------------- per-node prep ----------------
__global__ void k_nodeprep(const float* __restrict__ x, float* __restrict__ scl,
                           float* __restrict__ xnk, int n, CurvPack cp) {
  int wid = blockIdx.x * 4 + (threadIdx.x >> 6);
  int lane = threadIdx.x & 63;
  if (wid >= n) return;
  float2 v = ((const float2*)x)[(size_t)wid * 64 + lane];
  float n2 = wsum64(v.x * v.x + v.y * v.y);
  float nraw = sqrtf(n2);
  if (lane < 4) {
    float kv = cp.k[lane], sk = cp.sk[lane], maxn = cp.mx[lane];
    float nnv = fmaxf(nraw, 1e-15f);
    float tk = tan_k_d(nnv, kv, sk);
    float s = tk / nnv;
    float pn = fmaxf(fabsf(tk) * (nraw / nnv), 1e-15f);
    float ps = proj_scale_d(pn, kv, maxn);
    scl[(size_t)lane * n + wid] = s * ps;
    xnk[(size_t)lane * n + wid] = pn * ps;
  }
}

// ---------------- bias points ----------------
__global__ void k_biaspt_all(const float* __restrict__ eb1, const float* __restrict__ eb2,
                             float* __restrict__ biasb, CurvPack cp) {
  __shared__ float l2[2];
  int blk = blockIdx.x;  // ex*2 + layer
  int ex = blk >> 1, layer = blk & 1;
  float kv = cp.k[ex], sk = cp.sk[ex], maxn = cp.mx[ex];
  const float* b = (layer ? eb2 : eb1) + ex * 128;
  float* outb = biasb + blk * 132;
  int j = threadIdx.x;  // 0..127
  float v = b[j];
  float n2 = wsum64(v * v);
  if ((j & 63) == 0) l2[j >> 6] = n2;
  __syncthreads();
  n2 = l2[0] + l2[1];
  float nraw = sqrtf(n2);
  float nnv = fmaxf(nraw, 1e-15f);
  float tk = tan_k_d(nnv, kv, sk);
  float s = tk / nnv;
  float pn = fmaxf(fabsf(tk) * (nraw / nnv), 1e-15f);
  float ps = proj_scale_d(pn, kv, maxn);
  float bp = ps * s * v;
  outb[j] = bp;
  float y2v = wsum64(bp * bp);
  __syncthreads();
  if ((j & 63) == 0) l2[j >> 6] = y2v;
  __syncthreads();
  if (j == 0) outb[128] = l2[0] + l2[1];
}

// ---------------- W -> fp16 hi/lo split ----------------
__global__ void k_w2h(const float* __restrict__ ew1, const float* __restrict__ ew2,
                      f16* __restrict__ whi, f16* __restrict__ wlo) {
  int i = blockIdx.x * 256 + threadIdx.x;
  if (i >= 8 * 16384) return;
  int slot = i >> 14;
  int r = i & 16383;
  int ex = slot >> 1, layer = slot & 1;
  float w = (layer ? ew2 : ew1)[ex * 16384 + r];
  f16 h = (f16)w;
  whi[i] = h;
  wlo[i] = (f16)(w - (float)h);
}

// ---------------- MFMA expert GEMM + deduped epilogue ----------------
__global__ __launch_bounds__(256) void k_matmfma(
    const f16* __restrict__ ahi, const f16* __restrict__ alo,
    const float* __restrict__ scale, const float* __restrict__ xnorm,
    const f16* __restrict__ whi, const f16* __restrict__ wlo,
    const float* __restrict__ biasb, f16* __restrict__ tout, int n, float kv, float sk,
    float maxn) {
  __shared__ float red[3][16][4];
  __shared__ float redT[16][4];
  __shared__ float nAs[16], nCs[16], nL[16];
  int tid = threadIdx.x;
  int w = tid >> 6;
  int lane = tid & 63;
  int col = lane & 15;
  int quad = lane >> 4;
  int n0w = blockIdx.x * 16;
  if (n0w >= n) return;

  int anodec = min(n0w + col, n - 1);
  const f16* ahrow = ahi + (size_t)anodec * 128;
  const f16* alrow = alo + (size_t)anodec * 128;
  int jt0 = w * 2;

  f32x4 acc[2];
  acc[0] = (f32x4){0.f, 0.f, 0.f, 0.f};
  acc[1] = (f32x4){0.f, 0.f, 0.f, 0.f};

#pragma unroll
  for (int kc = 0; kc < 4; kc++) {
    int kb = kc * 32 + quad * 8;
    f16x8 Ah = *(const f16x8*)(ahrow + kb);
    f16x8 Al = *(const f16x8*)(alrow + kb);
#pragma unroll
    for (int j2 = 0; j2 < 2; j2++) {
      const f16* bh = whi + (size_t)((jt0 + j2) * 16 + col) * 128 + kb;
      const f16* bl = wlo + (size_t)((jt0 + j2) * 16 + col) * 128 + kb;
      f16x8 Bh = *(const f16x8*)bh;
      f16x8 Bl = *(const f16x8*)bl;
      acc[j2] = __builtin_amdgcn_mfma_f32_16x16x32_f16(Ah, Bh, acc[j2], 0, 0, 0);
      acc[j2] = __builtin_amdgcn_mfma_f32_16x16x32_f16(Ah, Bl, acc[j2], 0, 0, 0);
      acc[j2] = __builtin_amdgcn_mfma_f32_16x16x32_f16(Al, Bh, acc[j2], 0, 0, 0);
    }
  }

  float bpj[2];
  bpj[0] = biasb[jt0 * 16 + col];
  bpj[1] = biasb[(jt0 + 1) * 16 + col];
  float y2 = biasb[128];

#pragma unroll
  for (int r = 0; r < 4; r++) {
    float s0 = 0.f, s1 = 0.f, s2 = 0.f;
#pragma unroll
    for (int j2 = 0; j2 < 2; j2++) {
      float v = acc[j2][r];
      s0 = fmaf(v, v, s0);
      s1 += fabsf(v);
      s2 = fmaf(v, bpj[j2], s2);
    }
#pragma unroll
    for (int m = 1; m < 16; m <<= 1) {
      s0 += __shfl_xor(s0, m, 64);
      s1 += __shfl_xor(s1, m, 64);
      s2 += __shfl_xor(s2, m, 64);
    }
    if (col == 0) {
      red[0][quad * 4 + r][w] = s0;
      red[1][quad * 4 + r][w] = s1;
      red[2][quad * 4 + r][w] = s2;
    }
  }
  __syncthreads();

  if (tid < 16) {
    int gnode = min(n0w + tid, n - 1);
    float sc = scale ? scale[gnode] : 1.f;
    float s0f = (red[0][tid][0] + red[0][tid][1] + red[0][tid][2] + red[0][tid][3]) * sc * sc;
    float s1f = (red[1][tid][0] + red[1][tid][1] + red[1][tid][2] + red[1][tid][3]) * fabsf(sc);
    float s2f = (red[2][tid][0] + red[2][tid][1] + red[2][tid][2] + red[2][tid][3]) * sc;
    float xnr = xnorm[gnode];
    float xn = fmaxf(xnr, 1e-15f);
    float mxraw = sqrtf(s0f);
    float mxv = fmaxf(mxraw, 1e-15f);
    float ar = artan_k_d(xn, kv, sk);
    float c1 = tan_k_d(mxv / xn * ar, kv, sk);
    float s = (s1f == 0.f) ? 0.f : c1 / mxv;
    float pn = fmaxf(fabsf(c1) * (mxraw / mxv), 1e-15f);
    float ps = (s1f == 0.f) ? 1.f : proj_scale_d(pn, kv, maxn);
    s *= ps;
    float x2 = (s * s) * s0f;
    float xy = s * s2f;
    float A = 1.f - 2.f * kv * xy - kv * y2;
    float Cc = 1.f + kv * x2;
    float den = fmaxf(1.f - 2.f * kv * xy + (kv * kv) * x2 * y2, 1e-15f);
    nAs[tid] = A * s / den * sc;
    nCs[tid] = Cc / den;
  }
  __syncthreads();

#pragma unroll
  for (int r = 0; r < 4; r++) {
    int idx = quad * 4 + r;
    float Asc = nAs[idx], Cs = nCs[idx];
    float t0 = 0.f;
#pragma unroll
    for (int j2 = 0; j2 < 2; j2++) {
      float v = fmaf(Asc, acc[j2][r], Cs * bpj[j2]);
      t0 = fmaf(v, v, t0);
    }
#pragma unroll
    for (int m = 1; m < 16; m <<= 1) t0 += __shfl_xor(t0, m, 64);
    if (col == 0) redT[idx][w] = t0;
  }
  __syncthreads();

  if (tid < 16) {
    float t0f = redT[tid][0] + redT[tid][1] + redT[tid][2] + redT[tid][3];
    float nraw = sqrtf(t0f);
    float ps2 = proj_scale_d(fmaxf(nraw, 1e-15f), kv, maxn);
    float nh = fmaxf(ps2 * nraw, 1e-15f);
    nL[tid] = artan_k_d(nh, kv, sk) / nh * ps2;
  }
  __syncthreads();

#pragma unroll
  for (int r = 0; r < 4; r++) {
    int idx = quad * 4 + r;
    int gnode = n0w + idx;
    if (gnode >= n) continue;
    float Asc = nAs[idx], Cs = nCs[idx], L = nL[idx];
    f16* trow = tout + (size_t)gnode * 128;
#pragma unroll
    for (int j2 = 0; j2 < 2; j2++) {
      float v = fmaf(Asc, acc[j2][r], Cs * bpj[j2]);
      trow[(jt0 + j2) * 16 + col] = (f16)(L * v);
    }
  }
}

// ---------------- fused edge-sweep aggregation ----------------
// MODE 0: layer-1 -> write f16 split (aggh/aggl) + scl2/xnk2 at interior run-ends.
// MODE 1: layer-2 -> logmap0(expmap0) scale + batch pooling into feats.
// MODE 2: gate    -> relu(val+bias) batch pooling into hgate.
// Spanning runs accumulate into agg fp32 (pre-zeroed); fixup kernels finish them.
template <int MODE>
__global__ __launch_bounds__(256) void k_aggF(
    const int2* __restrict__ esw, const int* __restrict__ off,
    const int* __restrict__ bnode, const int* __restrict__ batch,
    const f16x2* __restrict__ t, float* __restrict__ agg,
    f16* __restrict__ aggh, f16* __restrict__ aggl, float* __restrict__ scl2,
    float* __restrict__ xnk2, float* __restrict__ feats, int ex,
    const float* __restrict__ bias, float* __restrict__ hgate,
    int etot, int n, float kv, float sk, float maxn) {
  int gw = blockIdx.x * 4 + (threadIdx.x >> 6);
  int lane = threadIdx.x & 63;
  int e0 = gw * CHUNK;
  if (e0 >= etot) return;
  int e1 = min(e0 + CHUNK, etot);
  int cur = bnode[gw];
  int runStart = off[cur];
  int eend = off[cur + 1];
  float ax = 0.f, ay = 0.f;
  float pax = 0.f, pay = 0.f;
  int bcur = (MODE >= 1) ? batch[cur] : 0;
  float bbx = 0.f, bby = 0.f;
  if (MODE == 2) {
    float2 bb = ((const float2*)bias)[lane];
    bbx = bb.x;
    bby = bb.y;
  }

  auto flushInterior = [&]() {
    if (MODE == 0) {
      f16x2 h, l;
      h[0] = (f16)ax; l[0] = (f16)(ax - (float)h[0]);
      h[1] = (f16)ay; l[1] = (f16)(ay - (float)h[1]);
      ((f16x2*)aggh)[(size_t)cur * 64 + lane] = h;
      ((f16x2*)aggl)[(size_t)cur * 64 + lane] = l;
      float n2 = wsum64(fmaf(ax, ax, ay * ay));
      float nraw = sqrtf(n2);
      float nnv = fmaxf(nraw, 1e-15f);
      float tk = tan_k_d(nnv, kv, sk);
      float s = tk / nnv;
      float pn = fmaxf(fabsf(tk) * (nraw / nnv), 1e-15f);
      float ps = proj_scale_d(pn, kv, maxn);
      if (lane == 0) {
        scl2[cur] = s * ps;
        xnk2[cur] = pn * ps;
      }
    } else if (MODE == 1) {
      float n2 = wsum64(fmaf(ax, ax, ay * ay));
      float nraw = sqrtf(n2);
      float nnv = fmaxf(nraw, 1e-15f);
      float tk = tan_k_d(nnv, kv, sk);
      float s = tk / nnv;
      float pn = fmaxf(fabsf(tk) * (nraw / nnv), 1e-15f);
      float ps = proj_scale_d(pn, kv, maxn);
      s *= ps;
      float nh = fmaxf(pn * ps, 1e-15f);
      float sc = artan_k_d(nh, kv, sk) / nh * s;
      pax = fmaf(sc, ax, pax);
      pay = fmaf(sc, ay, pay);
    } else {
      pax += fmaxf(ax + bbx, 0.f);
      pay += fmaxf(ay + bby, 0.f);
    }
  };
  auto flushBoundary = [&]() {
    float* dp = agg + (size_t)cur * 128 + lane * 2;
    atomicAdd(dp, ax);
    atomicAdd(dp + 1, ay);
  };
  auto flushPool = [&]() {
    if (MODE == 1) {
      float* fp = &feats[(size_t)bcur * 512 + ex * 128 + lane * 2];
      atomicAdd(fp, pax);
      atomicAdd(fp + 1, pay);
    } else if (MODE == 2) {
      float* hp = &hgate[(size_t)bcur * 128 + lane * 2];
      atomicAdd(hp, pax);
      atomicAdd(hp + 1, pay);
    }
  };

  int j = e0;
  while (j < e1) {
    if (j + 16 <= e1 && eend >= j + 16) {
      int2 m[16];
#pragma unroll
      for (int q = 0; q < 16; q++) m[q] = esw[j + q];
      f16x2 r[16];
#pragma unroll
      for (int q = 0; q < 16; q++) {
        int s = __builtin_amdgcn_readfirstlane(m[q].x);
        r[q] = t[(size_t)s * 64 + lane];
      }
#pragma unroll
      for (int q = 0; q < 16; q++) {
        float w = __int_as_float(m[q].y);
        ax = fmaf(w, (float)r[q][0], ax);
        ay = fmaf(w, (float)r[q][1], ay);
      }
      j += 16;
    } else if (j + 8 <= e1 && eend >= j + 8) {
      int2 m[8];
#pragma unroll
      for (int q = 0; q < 8; q++) m[q] = esw[j + q];
      f16x2 r[8];
#pragma unroll
      for (int q = 0; q < 8; q++) {
        int s = __builtin_amdgcn_readfirstlane(m[q].x);
        r[q] = t[(size_t)s * 64 + lane];
      }
#pragma unroll
      for (int q = 0; q < 8; q++) {
        float w = __int_as_float(m[q].y);
        ax = fmaf(w, (float)r[q][0], ax);
        ay = fmaf(w, (float)r[q][1], ay);
      }
      j += 8;
    } else if (j + 4 <= e1 && eend >= j + 4) {
      int2 m[4];
#pragma unroll
      for (int q = 0; q < 4; q++) m[q] = esw[j + q];
      f16x2 r[4];
#pragma unroll
      for (int q = 0; q < 4; q++) {
        int s = __builtin_amdgcn_readfirstlane(m[q].x);
        r[q] = t[(size_t)s * 64 + lane];
      }
#pragma unroll
      for (int q = 0; q < 4; q++) {
        float w = __int_as_float(m[q].y);
        ax = fmaf(w, (float)r[q][0], ax);
        ay = fmaf(w, (float)r[q][1], ay);
      }
      j += 4;
    } else {
      if (j == eend) {
        if (runStart >= e0) flushInterior(); else flushBoundary();
        ax = ay = 0.f;
        runStart = j;
        cur++;
        eend = off[cur + 1];
        if (MODE >= 1) {
          int nb = batch[cur];
          if (nb != bcur) {
            flushPool();
            pax = pay = 0.f;
            bcur = nb;
          }
        }
      }
      int2 m = esw[j];
      int s = __builtin_amdgcn_readfirstlane(m.x);
      f16x2 rv = t[(size_t)s * 64 + lane];
      float w = __int_as_float(m.y);
      ax = fmaf(w, (float)rv[0], ax);
      ay = fmaf(w, (float)rv[1], ay);
      j++;
    }
  }
  if (runStart >= e0 && eend <= e1) flushInterior(); else flushBoundary();
  if (MODE >= 1) flushPool();
}

// ---------------- fixups for chunk-spanning runs ----------------
__device__ __forceinline__ bool span_guard(const int* bnode, const int* off, int g, int nchunk,
                                           int& nd) {
  nd = bnode[g];
  if (g > 0 && bnode[g - 1] == nd) return false;  // dedupe
  int s = off[nd], e = off[nd + 1];
  if (s / CHUNK == (e - 1) / CHUNK) return false;  // fully contained: handled in-wave
  return true;
}

__global__ void k_fix1(const int* __restrict__ bnode, const int* __restrict__ off,
                       const float* __restrict__ agg, f16* __restrict__ aggh,
                       f16* __restrict__ aggl, float* __restrict__ scl2,
                       float* __restrict__ xnk2, int nchunk, float kv, float sk, float maxn) {
  int g = blockIdx.x * 4 + (threadIdx.x >> 6);
  int lane = threadIdx.x & 63;
  if (g >= nchunk) return;
  int nd;
  if (!span_guard(bnode, off, g, nchunk, nd)) return;
  float2 v = ((const float2*)agg)[(size_t)nd * 64 + lane];
  f16x2 h, l;
  h[0] = (f16)v.x; l[0] = (f16)(v.x - (float)h[0]);
  h[1] = (f16)v.y; l[1] = (f16)(v.y - (float)h[1]);
  ((f16x2*)aggh)[(size_t)nd * 64 + lane] = h;
  ((f16x2*)aggl)[(size_t)nd * 64 + lane] = l;
  float n2 = wsum64(fmaf(v.x, v.x, v.y * v.y));
  float nraw = sqrtf(n2);
  float nnv = fmaxf(nraw, 1e-15f);
  float tk = tan_k_d(nnv, kv, sk);
  float s = tk / nnv;
  float pn = fmaxf(fabsf(tk) * (nraw / nnv), 1e-15f);
  float ps = proj_scale_d(pn, kv, maxn);
  if (lane == 0) {
    scl2[nd] = s * ps;
    xnk2[nd] = pn * ps;
  }
}

__global__ void k_fix2(const int* __restrict__ bnode, const int* __restrict__ off,
                       const float* __restrict__ agg, const int* __restrict__ batch,
                       float* __restrict__ feats, int ex, int nchunk, float kv, float sk,
                       float maxn) {
  int g = blockIdx.x * 4 + (threadIdx.x >> 6);
  int lane = threadIdx.x & 63;
  if (g >= nchunk) return;
  int nd;
  if (!span_guard(bnode, off, g, nchunk, nd)) return;
  float2 v = ((const float2*)agg)[(size_t)nd * 64 + lane];
  float n2 = wsum64(fmaf(v.x, v.x, v.y * v.y));
  float nraw = sqrtf(n2);
  float nnv = fmaxf(nraw, 1e-15f);
  float tk = tan_k_d(nnv, kv, sk);
  float s = tk / nnv;
  float pn = fmaxf(fabsf(tk) * (nraw / nnv), 1e-15f);
  float ps = proj_scale_d(pn, kv, maxn);
  s *= ps;
  float nh = fmaxf(pn * ps, 1e-15f);
  float sc = artan_k_d(nh, kv, sk) / nh * s;
  int b = batch[nd];
  float* fp = &feats[(size_t)b * 512 + ex * 128 + lane * 2];
  atomicAdd(fp, sc * v.x);
  atomicAdd(fp + 1, sc * v.y);
}

__global__ void k_fixG(const int* __restrict__ bnode, const int* __restrict__ off,
                       const float* __restrict__ agg, const int* __restrict__ batch,
                       const float* __restrict__ bias, float* __restrict__ hgate, int nchunk) {
  int g = blockIdx.x * 4 + (threadIdx.x >> 6);
  int lane = threadIdx.x & 63;
  if (g >= nchunk) return;
  int nd;
  if (!span_guard(bnode, off, g, nchunk, nd)) return;
  float2 v = ((const float2*)agg)[(size_t)nd * 64 + lane];
  float2 bb = ((const float2*)bias)[lane];
  int b = batch[nd];
  float* hp = &hgate[(size_t)b * 128 + lane * 2];
  atomicAdd(hp, fmaxf(v.x + bb.x, 0.f));
  atomicAdd(hp + 1, fmaxf(v.y + bb.y, 0.f));
}

// ---------------- gate GEMM 1 ----------------
__global__ __launch_bounds__(256) void k_gate1(const float* __restrict__ x,
                                               const float* __restrict__ gw1,
                                               float* __restrict__ m1, int n) {
  __shared__ float xT[64][68];
  __shared__ float Wt[64][36];
  int tid = threadIdx.x;
  int n0 = blockIdx.x * 64;
  int c = tid & 7, r = tid >> 3;
  float acc[2][4];
#pragma unroll
  for (int i = 0; i < 2; i++)
#pragma unroll
    for (int jj = 0; jj < 4; jj++) acc[i][jj] = 0.f;

  for (int kc = 0; kc < 2; kc++) {
    if (kc) __syncthreads();
#pragma unroll
    for (int it = 0; it < 8; it++) {
      int u = tid + it * 256;
      int j = u >> 6, kd = u & 63;
      Wt[kd][j] = gw1[j * 128 + kc * 64 + kd];
    }
#pragma unroll
    for (int it = 0; it < 4; it++) {
      int u = tid + it * 256;
      int node = u >> 4, c4 = u & 15;
      float4 v = make_float4(0.f, 0.f, 0.f, 0.f);
      if (n0 + node < n) v = ((const float4*)x)[(size_t)(n0 + node) * 32 + kc * 16 + c4];
      xT[4 * c4 + 0][node] = v.x;
      xT[4 * c4 + 1][node] = v.y;
      xT[4 * c4 + 2][node] = v.z;
      xT[4 * c4 + 3][node] = v.w;
    }
    __syncthreads();
#pragma unroll 8
    for (int kd = 0; kd < 64; kd++) {
      float2 av = *(const float2*)&xT[kd][r * 2];
      float4 bv = *(const float4*)&Wt[kd][c * 4];
      float a[2] = {av.x, av.y};
      float bbv[4] = {bv.x, bv.y, bv.z, bv.w};
#pragma unroll
      for (int i = 0; i < 2; i++)
#pragma unroll
        for (int jj = 0; jj < 4; jj++) acc[i][jj] = fmaf(a[i], bbv[jj], acc[i][jj]);
    }
  }
#pragma unroll
  for (int i = 0; i < 2; i++) {
    int node = n0 + r * 2 + i;
    if (node >= n) continue;
    ((float4*)m1)[(size_t)node * 8 + c] = make_float4(acc[i][0], acc[i][1], acc[i][2], acc[i][3]);
  }
}

// ---------------- gate GEMM 2 ----------------
__global__ __launch_bounds__(256) void k_gate2(const float* __restrict__ g1,
                                               const float* __restrict__ gw2,
                                               f16* __restrict__ m2, int n) {
  __shared__ float xT[32][68];
  __shared__ float Wt[32][132];
  int tid = threadIdx.x;
  int n0 = blockIdx.x * 64;
  int c = tid & 15, r = tid >> 4;
  float acc[4][8];
#pragma unroll
  for (int i = 0; i < 4; i++)
#pragma unroll
    for (int jj = 0; jj < 8; jj++) acc[i][jj] = 0.f;

#pragma unroll
  for (int it = 0; it < 16; it++) {
    int u = tid + it * 256;
    int j = u >> 5, kd = u & 31;
    Wt[kd][j] = gw2[j * 32 + kd];
  }
#pragma unroll
  for (int it = 0; it < 2; it++) {
    int u = tid + it * 256;
    int node = u >> 3, c4 = u & 7;
    float4 v = make_float4(0.f, 0.f, 0.f, 0.f);
    if (n0 + node < n) v = ((const float4*)g1)[(size_t)(n0 + node) * 8 + c4];
    xT[4 * c4 + 0][node] = v.x;
    xT[4 * c4 + 1][node] = v.y;
    xT[4 * c4 + 2][node] = v.z;
    xT[4 * c4 + 3][node] = v.w;
  }
  __syncthreads();
#pragma unroll 8
  for (int kd = 0; kd < 32; kd++) {
    float4 av = *(const float4*)&xT[kd][r * 4];
    float4 b0 = *(const float4*)&Wt[kd][c * 8];
    float4 b1 = *(const float4*)&Wt[kd][c * 8 + 4];
    float a[4] = {av.x, av.y, av.z, av.w};
    float bbv[8] = {b0.x, b0.y, b0.z, b0.w, b1.x, b1.y, b1.z, b1.w};
#pragma unroll
    for (int i = 0; i < 4; i++)
#pragma unroll
      for (int jj = 0; jj < 8; jj++) acc[i][jj] = fmaf(a[i], bbv[jj], acc[i][jj]);
  }
#pragma unroll
  for (int i = 0; i < 4; i++) {
    int node = n0 + r * 4 + i;
    if (node >= n) continue;
    f16x8 hv;
#pragma unroll
    for (int jj = 0; jj < 8; jj++) hv[jj] = (f16)acc[i][jj];
    *((f16x8*)(m2 + (size_t)node * 128) + c) = hv;
  }
}

// ---------------- gate aggregation dim32 ----------------
__global__ void k_agg_relu32(const float* __restrict__ m1, const int* __restrict__ off,
                             const int2* __restrict__ esw, const float* __restrict__ bias,
                             float* __restrict__ g1, int n) {
  int node = blockIdx.x * 4 + (threadIdx.x >> 6);
  int lane = threadIdx.x & 63;
  if (node >= n) return;
  int grp = lane >> 3, l8 = lane & 7;
  int e0 = off[node], e1 = off[node + 1];
  float4 acc = make_float4(0.f, 0.f, 0.f, 0.f);
  for (int base = e0 + grp; base < e1; base += 8) {
    int2 me = esw[base];
    int ss = me.x;
    float ww = __int_as_float(me.y);
    float4 tv = ((const float4*)m1)[(size_t)ss * 8 + l8];
    acc.x = fmaf(ww, tv.x, acc.x);
    acc.y = fmaf(ww, tv.y, acc.y);
    acc.z = fmaf(ww, tv.z, acc.z);
    acc.w = fmaf(ww, tv.w, acc.w);
  }
#pragma unroll
  for (int m = 8; m <= 32; m <<= 1) {
    acc.x += __shfl_xor(acc.x, m, 64);
    acc.y += __shfl_xor(acc.y, m, 64);
    acc.z += __shfl_xor(acc.z, m, 64);
    acc.w += __shfl_xor(acc.w, m, 64);
  }
  if (grp == 0) {
    float4 bb = ((const float4*)bias)[l8];
    float4 o = make_float4(fmaxf(acc.x + bb.x, 0.f), fmaxf(acc.y + bb.y, 0.f),
                           fmaxf(acc.z + bb.z, 0.f), fmaxf(acc.w + bb.w, 0.f));
    ((float4*)g1)[(size_t)node * 8 + l8] = o;
  }
}

// ---------------- final ----------------
__global__ __launch_bounds__(128) void k_final(const float* __restrict__ feats,
                                               const float* __restrict__ hgate,
                                               const float* __restrict__ counts,
                                               const float* __restrict__ gate_u,
                                               const float* __restrict__ tau_raw,
                                               float* __restrict__ out, CurvPack cp) {
  __shared__ float l2[2];
  int b = blockIdx.x;
  int j = threadIdx.x;
  float cnt = fmaxf(counts[b], 1.f);
  float hg = hgate[(size_t)b * 128 + j] / cnt;

  auto bsum = [&](float v) -> float {
    v = wsum64(v);
    __syncthreads();
    if ((j & 63) == 0) l2[j >> 6] = v;
    __syncthreads();
    return l2[0] + l2[1];
  };

  float nhg2 = bsum(hg * hg);
  float nhgraw = sqrtf(nhg2);
  float nhg = fmaxf(nhgraw, 1e-15f);

  float d[4], tau[4];
#pragma unroll
  for (int i = 0; i < 4; i++) {
    float kv = cp.k[i], sk = cp.sk[i], mxn = cp.mx[i];
    float tk = tan_k_d(nhg, kv, sk);
    float s = tk / nhg;
    float pn = fmaxf(fabsf(tk) * (nhgraw / nhg), 1e-15f);
    s *= proj_scale_d(pn, kv, mxn);
    float zk = s * hg;

    float u = gate_u[i * 128 + j];
    float nu2 = bsum(u * u);
    float nuraw = sqrtf(nu2);
    float nu = fmaxf(nuraw, 1e-15f);
    float tku = tan_k_d(nu, kv, sk);
    float su = tku / nu;
    float pnu = fmaxf(fabsf(tku) * (nuraw / nu), 1e-15f);
    su *= proj_scale_d(pnu, kv, mxn);
    float yk = su * u;

    float xv = -zk;
    float x2 = bsum(xv * xv);
    float y2 = bsum(yk * yk);
    float xy = bsum(xv * yk);
    float A = 1.f - 2.f * kv * xy - kv * y2;
    float C = 1.f + kv * x2;
    float den = fmaxf(1.f - 2.f * kv * xy + (kv * kv) * x2 * y2, 1e-15f);
    float ma = (A * xv + C * yk) / den;
    float m2 = bsum(ma * ma);
    float mraw = sqrtf(m2);
    float ps2 = proj_scale_d(fmaxf(mraw, 1e-15f), kv, mxn);
    float nm = fmaxf(ps2 * mraw, 1e-15f);
    d[i] = 2.f * artan_k_d(nm, kv, sk);

    float tr = tau_raw[i];
    tau[i] = fminf(fmaxf(log1pf(expf(tr)) + 0.05f, 0.05f), 10.f);
  }

  float xi[4];
  float mxv = -1e30f;
#pragma unroll
  for (int i = 0; i < 4; i++) {
    xi[i] = -d[i] / tau[i];
    mxv = fmaxf(mxv, xi[i]);
  }
  float es = 0.f, e[4];
#pragma unroll
  for (int i = 0; i < 4; i++) {
    e[i] = expf(xi[i] - mxv);
    es += e[i];
  }
  float w[4];
#pragma unroll
  for (int i = 0; i < 4; i++) w[i] = e[i] / es;

#pragma unroll
  for (int i = 0; i < 4; i++)
    out[(size_t)b * 512 + i * 128 + j] = feats[(size_t)b * 512 + i * 128 + j] / cnt * w[i];

  if (j < 4) {
    out[65536 + b * 4 + j] = w[j];
    out[66048 + b * 4 + j] = d[j];
  }
  if (b == 0 && j < 4) out[66560 + j] = tau[j];
}

// ---------------- host launcher ----------------
extern "C" void kernel_launch(void* const* d_in, const int* in_sizes, int n_in,
                              void* d_out, int out_size, void* d_ws, size_t ws_size,
                              hipStream_t stream) {
  const float* x = (const float*)d_in[0];
  const int* ei = (const int*)d_in[1];
  const int* batch = (const int*)d_in[2];
  const float* ew1 = (const float*)d_in[3];
  const float* eb1 = (const float*)d_in[4];
  const float* ew2 = (const float*)d_in[5];
  const float* eb2 = (const float*)d_in[6];
  const float* gw1 = (const float*)d_in[7];
  const float* gb1 = (const float*)d_in[8];
  const float* gw2 = (const float*)d_in[9];
  const float* gb2 = (const float*)d_in[10];
  const float* gu = (const float*)d_in[11];
  const float* traw = (const float*)d_in[12];
  float* out = (float*)d_out;

  const int N = NN, E = EE, ET = ETOT, B = BB;

  float* ws = (float*)d_ws;
  size_t o = 0;
  f16* tbh = (f16*)ws;      o += (size_t)N * 64;  // N*128 halfs
  float* agg = ws + o;      o += (size_t)N * 128;
  f16* xhi = (f16*)(ws + o);    o += (size_t)N * 64;
  f16* xlo = (f16*)(ws + o);    o += (size_t)N * 64;
  f16* aggh = (f16*)(ws + o);   o += (size_t)N * 64;
  f16* aggl = (f16*)(ws + o);   o += (size_t)N * 64;
  float* m1 = ws + o;       o += (size_t)N * 32;
  float* g1 = ws + o;       o += (size_t)N * 32;
  float* deg = ws + o;      o += N;  // becomes dinv
  float* scl1 = ws + o;     o += (size_t)4 * N;
  float* xnk1 = ws + o;     o += (size_t)4 * N;
  float* scl2 = ws + o;     o += N;
  float* xnk2 = ws + o;     o += N;
  float* counts = ws + o;   o += 256;
  float* feats = ws + o;    o += (size_t)B * 512;
  float* hg = ws + o;       o += (size_t)B * 128;
  float* biasb = ws + o;    o += 8 * 132;
  f16* whi = (f16*)(ws + o);    o += 8 * 16384 / 2;
  f16* wlo = (f16*)(ws + o);    o += 8 * 16384 / 2;
  int* ideg = (int*)(ws + o);   o += N;
  int* csroff = (int*)(ws + o); o += N + 8;
  int* cursor = (int*)(ws + o); o += N;
  int* boff = (int*)(ws + o);   o += 136;
  int* bsum = (int*)(ws + o);   o += 256;
  int* bnode = (int*)(ws + o);  o += NCHUNK + 8;
  int2* esw = (int2*)(ws + o);  o += (size_t)2 * ET;

  // zero: counts + feats + hg (contiguous)
  hipMemsetAsync(counts, 0, (256 + (size_t)B * 512 + (size_t)B * 128) * sizeof(float), stream);

  const double curvs[4] = {-1.0, 0.0, 1.0, -0.5};
  CurvPack cp;
  for (int i = 0; i < 4; i++) {
    double kd = curvs[i];
    double skd = sqrt(fabs(kd));
    cp.k[i] = (float)kd;
    cp.sk[i] = (float)skd;
    cp.mx[i] = (kd < 0) ? (float)((1.0 - 1e-5) / skd) : 3.0e38f;
  }

  k_init<<<(N + 255) / 256, 256, 0, stream>>>(deg, N);
  k_counts<<<1, 256, 0, stream>>>(batch, boff, counts, N);
  k_deg<<<(E + 255) / 256, 256, 0, stream>>>(ei, deg, E);
  k_dinv<<<(N + 255) / 256, 256, 0, stream>>>(deg, ideg, N);
  k_scanA<<<SCB, 256, 0, stream>>>(ideg, bsum, N);
  k_scanB<<<1, 256, 0, stream>>>(bsum, SCB);
  k_scanC<<<SCB, 256, 0, stream>>>(ideg, bsum, csroff, cursor, N);
  k_bnodes<<<(NCHUNK + 255) / 256, 256, 0, stream>>>(csroff, bnode, NCHUNK, N);
  k_place<<<(ET + 255) / 256, 256, 0, stream>>>(ei, deg, cursor, esw, E, N);
  k_nodeprep<<<(N + 3) / 4, 256, 0, stream>>>(x, scl1, xnk1, N, cp);
  k_xsplit<<<(N * 64 + 255) / 256, 256, 0, stream>>>(x, xhi, xlo, N * 64);
  k_biaspt_all<<<8, 128, 0, stream>>>(eb1, eb2, biasb, cp);
  k_w2h<<<512, 256, 0, stream>>>(ew1, ew2, whi, wlo);

  const int aggBlocks = (NCHUNK + 3) / 4;
  const int mfmaBlocks = (N + 15) / 16;

  for (int ex = 0; ex < 4; ex++) {
    float kv = cp.k[ex], sk = cp.sk[ex], mxn = cp.mx[ex];
    int s1 = ex * 2, s2 = ex * 2 + 1;
    // layer 1
    k_matmfma<<<mfmaBlocks, 256, 0, stream>>>(xhi, xlo, scl1 + (size_t)ex * N,
                                              xnk1 + (size_t)ex * N, whi + (size_t)s1 * 16384,
                                              wlo + (size_t)s1 * 16384, biasb + s1 * 132, tbh, N,
                                              kv, sk, mxn);
    k_zerob<<<aggBlocks, 256, 0, stream>>>(bnode, agg, NCHUNK);
    k_aggF<0><<<aggBlocks, 256, 0, stream>>>(esw, csroff, bnode, batch, (const f16x2*)tbh, agg,
                                             aggh, aggl, scl2, xnk2, nullptr, 0, nullptr,
                                             nullptr, ET, N, kv, sk, mxn);
    k_fix1<<<aggBlocks, 256, 0, stream>>>(bnode, csroff, agg, aggh, aggl, scl2, xnk2, NCHUNK,
                                          kv, sk, mxn);
    // layer 2
    k_matmfma<<<mfmaBlocks, 256, 0, stream>>>(aggh, aggl, scl2, xnk2, whi + (size_t)s2 * 16384,
                                              wlo + (size_t)s2 * 16384, biasb + s2 * 132, tbh, N,
                                              kv, sk, mxn);
    k_zerob<<<aggBlocks, 256, 0, stream>>>(bnode, agg, NCHUNK);
    k_aggF<1><<<aggBlocks, 256, 0, stream>>>(esw, csroff, bnode, batch, (const f16x2*)tbh, agg,
                                             nullptr, nullptr, nullptr, nullptr, feats, ex,
                                             nullptr, nullptr, ET, N, kv, sk, mxn);
    k_fix2<<<aggBlocks, 256, 0, stream>>>(bnode, csroff, agg, batch, feats, ex, NCHUNK, kv, sk,
                                          mxn);
  }

  // gate GCN
  k_gate1<<<(N + 63) / 64, 256, 0, stream>>>(x, gw1, m1, N);
  k_agg_relu32<<<(N + 3) / 4, 256, 0, stream>>>(m1, csroff, esw, gb1, g1, N);
  k_gate2<<<(N + 63) / 64, 256, 0, stream>>>(g1, gw2, tbh, N);
  k_zerob<<<aggBlocks, 256, 0, stream>>>(bnode, agg, NCHUNK);
  k_aggF<2><<<aggBlocks, 256, 0, stream>>>(esw, csroff, bnode, batch, (const f16x2*)tbh, agg,
                                           nullptr, nullptr, nullptr, nullptr, nullptr, 0, gb2,
                                           hg, ET, N, 0.f, 0.f, 0.f);
  k_fixG<<<aggBlocks, 256, 0, stream>>>(bnode, csroff, agg, batch, gb2, hg, NCHUNK);

  k_final<<<B, 128, 0, stream>>>(feats, hg, counts, gu, traw, out, cp);

  (void)in_sizes; (void)n_in; (void)out_size; (void)ws_size;
}

// Round 11
// 1023.758 us; speedup vs baseline: 1.4501x; 1.1842x over previous
//
#include <hip/hip_runtime.h>
#include <math.h>

// ---------------- constants ----------------
#define NN 50000
#define EE 800000
#define ETOT (EE + NN)
#define BB 128
#define DIM 128
#define GHID 32
#define CHUNK 128
#define NCHUNK ((ETOT + CHUNK - 1) / CHUNK)
#define SCB 196  // scan blocks: 196*256 >= 50000

typedef _Float16 f16;
typedef _Float16 f16x2 __attribute__((ext_vector_type(2)));
typedef _Float16 f16x8 __attribute__((ext_vector_type(8)));
typedef float f32x4 __attribute__((ext_vector_type(4)));

struct CurvPack {
  float k[4], sk[4], mx[4];
};

// ---------------- device math helpers ----------------
__device__ __forceinline__ float wsum64(float v) {
#pragma unroll
  for (int m = 32; m; m >>= 1) v += __shfl_xor(v, m, 64);
  return v;
}

__device__ __forceinline__ float tan_k_d(float x, float kv, float sk) {
  if (kv > 0.f) return tanf(x * sk) / sk;
  if (kv < 0.f) return tanhf(x * sk) / sk;
  return x;
}

__device__ __forceinline__ float artan_k_d(float x, float kv, float sk) {
  if (kv > 0.f) return atanf(x * sk) / sk;
  if (kv < 0.f) {
    float t = x * sk;
    t = fminf(fmaxf(t, -1.f + 1e-7f), 1.f - 1e-7f);
    return atanhf(t) / sk;
  }
  return x;
}

__device__ __forceinline__ float proj_scale_d(float n, float kv, float maxn) {
  if (kv < 0.f && n > maxn) return maxn / n;
  return 1.f;
}

// ---------------- graph preprocessing ----------------
__global__ void k_init(float* __restrict__ deg, int n) {
  int i = blockIdx.x * 256 + threadIdx.x;
  if (i < n) deg[i] = 1.0f;  // self loop
}

__global__ void k_counts(const int* __restrict__ batch, int* __restrict__ boff,
                         float* __restrict__ counts, int n) {
  int b = threadIdx.x;
  if (b <= 128) {
    int lo = 0, hi = n;
    while (lo < hi) {
      int mid = (lo + hi) >> 1;
      if (batch[mid] < b) lo = mid + 1; else hi = mid;
    }
    boff[b] = lo;
  }
  __syncthreads();
  if (b < 128) counts[b] = (float)(boff[b + 1] - boff[b]);
}

__global__ void k_deg(const int* __restrict__ ei, float* __restrict__ deg, int e) {
  int i = blockIdx.x * 256 + threadIdx.x;
  if (i < e) atomicAdd(&deg[ei[e + i]], 1.0f);
}

__global__ void k_dinv(float* __restrict__ deg, int* __restrict__ ideg, int n) {
  int i = blockIdx.x * 256 + threadIdx.x;
  if (i < n) {
    float d = deg[i];
    ideg[i] = (int)(d + 0.5f);
    deg[i] = 1.0f / sqrtf(d);
  }
}

// ---------------- parallel scan ----------------
__global__ void k_scanA(const int* __restrict__ ideg, int* __restrict__ bsum, int n) {
  __shared__ int ls[4];
  int i = blockIdx.x * 256 + threadIdx.x;
  int v = (i < n) ? ideg[i] : 0;
#pragma unroll
  for (int m = 1; m < 64; m <<= 1) v += __shfl_xor(v, m, 64);
  if ((threadIdx.x & 63) == 0) ls[threadIdx.x >> 6] = v;
  __syncthreads();
  if (threadIdx.x == 0) bsum[blockIdx.x] = ls[0] + ls[1] + ls[2] + ls[3];
}

__global__ void k_scanB(int* __restrict__ bsum, int nb) {
  __shared__ int wsh[4];
  int tid = threadIdx.x;
  int lane = tid & 63, w = tid >> 6;
  int v = (tid < nb) ? bsum[tid] : 0;
  int x = v;
#pragma unroll
  for (int o = 1; o < 64; o <<= 1) {
    int t = __shfl_up(x, o, 64);
    if (lane >= o) x += t;
  }
  if (lane == 63) wsh[w] = x;
  __syncthreads();
  int add = 0;
  for (int k2 = 0; k2 < w; k2++) add += wsh[k2];
  if (tid < nb) bsum[tid] = add + x - v;
}

__global__ void k_scanC(const int* __restrict__ ideg, const int* __restrict__ bsum,
                        int* __restrict__ off, int* __restrict__ cursor, int n) {
  __shared__ int wsh[4];
  int i = blockIdx.x * 256 + threadIdx.x;
  int lane = threadIdx.x & 63, w = threadIdx.x >> 6;
  int v = (i < n) ? ideg[i] : 0;
  int x = v;
#pragma unroll
  for (int o = 1; o < 64; o <<= 1) {
    int t = __shfl_up(x, o, 64);
    if (lane >= o) x += t;
  }
  if (lane == 63) wsh[w] = x;
  __syncthreads();
  int add = bsum[blockIdx.x];
  for (int k2 = 0; k2 < w; k2++) add += wsh[k2];
  int excl = add + x - v;
  if (i < n) {
    off[i] = excl;
    cursor[i] = excl;
  }
  if (i == n - 1) off[n] = excl + v;
}

// ---------------- chunk head nodes + first-occurrence slots ----------------
__global__ void k_bnodes(const int* __restrict__ off, int* __restrict__ bnode, int nchunk,
                         int n) {
  int g = blockIdx.x * 256 + threadIdx.x;
  if (g >= nchunk) return;
  int e0 = g * CHUNK;
  int lo = 0, hi = n;
  while (hi - lo > 1) {
    int mid = (lo + hi) >> 1;
    if (off[mid] <= e0) lo = mid; else hi = mid;
  }
  bnode[g] = lo;
}

__global__ void k_bslot(const int* __restrict__ bnode, int* __restrict__ bslot, int nchunk) {
  int g = blockIdx.x * 256 + threadIdx.x;
  if (g >= nchunk) return;
  int v = bnode[g];
  int lo = 0, hi = g;
  while (lo < hi) {
    int mid = (lo + hi) >> 1;
    if (bnode[mid] < v) lo = mid + 1; else hi = mid;
  }
  bslot[g] = lo;
}

__device__ __forceinline__ bool span_head(const int* bnode, const int* bslot, const int* off,
                                          int g, int& nd) {
  if (bslot[g] != g) return false;
  nd = bnode[g];
  int s = off[nd], e = off[nd + 1];
  return (s / CHUNK) != ((e - 1) / CHUNK);
}

// zero spanning boundary slots of aggc
__global__ void k_zeroc(const int* __restrict__ bnode, const int* __restrict__ bslot,
                        const int* __restrict__ off, float* __restrict__ aggc, int nchunk) {
  int g = blockIdx.x * 4 + (threadIdx.x >> 6);
  int lane = threadIdx.x & 63;
  if (g >= nchunk) return;
  int nd;
  if (!span_head(bnode, bslot, off, g, nd)) return;
  float2 z = make_float2(0.f, 0.f);
#pragma unroll
  for (int i = 0; i < 4; i++) ((float2*)aggc)[(size_t)g * 256 + i * 64 + lane] = z;
}

// ---------------- edge placement ----------------
__global__ void k_place(const int* __restrict__ ei, const float* __restrict__ dinv,
                        int* __restrict__ cursor, int2* __restrict__ esw, int e, int n) {
  int i = blockIdx.x * 256 + threadIdx.x;
  int et = e + n;
  if (i >= et) return;
  int r_, c_;
  if (i < e) {
    r_ = ei[i];
    c_ = ei[e + i];
  } else {
    r_ = i - e;
    c_ = i - e;
  }
  int p = atomicAdd(&cursor[c_], 1);
  esw[p] = make_int2(r_, __float_as_int(dinv[r_] * dinv[c_]));
}

// ---------------- per-node prep (scl1/xnk1 layout [ex*N + node]) ----------------
__global__ void k_nodeprep(const float* __restrict__ x, float* __restrict__ scl,
                           float* __restrict__ xnk, int n, CurvPack cp) {
  int wid = blockIdx.x * 4 + (threadIdx.x >> 6);
  int lane = threadIdx.x & 63;
  if (wid >= n) return;
  float2 v = ((const float2*)x)[(size_t)wid * 64 + lane];
  float n2 = wsum64(v.x * v.x + v.y * v.y);
  float nraw = sqrtf(n2);
  if (lane < 4) {
    float kv = cp.k[lane], sk = cp.sk[lane], maxn = cp.mx[lane];
    float nnv = fmaxf(nraw, 1e-15f);
    float tk = tan_k_d(nnv, kv, sk);
    float s = tk / nnv;
    float pn = fmaxf(fabsf(tk) * (nraw / nnv), 1e-15f);
    float ps = proj_scale_d(pn, kv, maxn);
    scl[(size_t)lane * n + wid] = s * ps;
    xnk[(size_t)lane * n + wid] = pn * ps;
  }
}

// ---------------- bias points ----------------
__global__ void k_biaspt_all(const float* __restrict__ eb1, const float* __restrict__ eb2,
                             float* __restrict__ biasb, CurvPack cp) {
  __shared__ float l2[2];
  int blk = blockIdx.x;  // ex*2 + layer
  int ex = blk >> 1, layer = blk & 1;
  float kv = cp.k[ex], sk = cp.sk[ex], maxn = cp.mx[ex];
  const float* b = (layer ? eb2 : eb1) + ex * 128;
  float* outb = biasb + blk * 132;
  int j = threadIdx.x;
  float v = b[j];
  float n2 = wsum64(v * v);
  if ((j & 63) == 0) l2[j >> 6] = n2;
  __syncthreads();
  n2 = l2[0] + l2[1];
  float nraw = sqrtf(n2);
  float nnv = fmaxf(nraw, 1e-15f);
  float tk = tan_k_d(nnv, kv, sk);
  float s = tk / nnv;
  float pn = fmaxf(fabsf(tk) * (nraw / nnv), 1e-15f);
  float ps = proj_scale_d(pn, kv, maxn);
  float bp = ps * s * v;
  outb[j] = bp;
  float y2v = wsum64(bp * bp);
  __syncthreads();
  if ((j & 63) == 0) l2[j >> 6] = y2v;
  __syncthreads();
  if (j == 0) outb[128] = l2[0] + l2[1];
}

// ---------------- W -> fp16 hi/lo split ----------------
__global__ void k_w2h(const float* __restrict__ ew1, const float* __restrict__ ew2,
                      f16* __restrict__ whi, f16* __restrict__ wlo) {
  int i = blockIdx.x * 256 + threadIdx.x;
  if (i >= 8 * 16384) return;
  int slot = i >> 14;
  int r = i & 16383;
  int ex = slot >> 1, layer = slot & 1;
  float w = (layer ? ew2 : ew1)[ex * 16384 + r];
  f16 h = (f16)w;
  whi[i] = h;
  wlo[i] = (f16)(w - (float)h);
}

// ---------------- MFMA expert GEMM (fp32 A in-kernel split, deduped epilogue) ----------
// grid.y = expert. Output interleaved t[node][ex*128].
__global__ __launch_bounds__(256) void k_matmfma(
    const float* __restrict__ A, int astr, int aoffPerEx, const float* __restrict__ sclB,
    const float* __restrict__ xnkB, const f16* __restrict__ whiB,
    const f16* __restrict__ wloB, const float* __restrict__ biasB, int layer,
    f16* __restrict__ tout, int n, CurvPack cp) {
  __shared__ float red[3][16][4];
  __shared__ float redT[16][4];
  __shared__ float nAs[16], nCs[16], nL[16];
  int ex = blockIdx.y;
  float kv = cp.k[ex], sk = cp.sk[ex], maxn = cp.mx[ex];
  const f16* whi = whiB + (size_t)(ex * 2 + layer) * 16384;
  const f16* wlo = wloB + (size_t)(ex * 2 + layer) * 16384;
  const float* biasb = biasB + (ex * 2 + layer) * 132;
  const float* scale = sclB + (size_t)ex * n;
  const float* xnorm = xnkB + (size_t)ex * n;

  int tid = threadIdx.x;
  int w = tid >> 6;
  int lane = tid & 63;
  int col = lane & 15;
  int quad = lane >> 4;
  int n0w = blockIdx.x * 16;
  if (n0w >= n) return;

  int anodec = min(n0w + col, n - 1);
  const float* arow = A + (size_t)anodec * astr + ex * aoffPerEx;
  int jt0 = w * 2;

  f32x4 acc[2];
  acc[0] = (f32x4){0.f, 0.f, 0.f, 0.f};
  acc[1] = (f32x4){0.f, 0.f, 0.f, 0.f};

#pragma unroll
  for (int kc = 0; kc < 4; kc++) {
    int kb = kc * 32 + quad * 8;
    float4 a0 = *(const float4*)(arow + kb);
    float4 a1 = *(const float4*)(arow + kb + 4);
    float av[8] = {a0.x, a0.y, a0.z, a0.w, a1.x, a1.y, a1.z, a1.w};
    f16x8 Ah, Al;
#pragma unroll
    for (int i = 0; i < 8; i++) {
      f16 h = (f16)av[i];
      Ah[i] = h;
      Al[i] = (f16)(av[i] - (float)h);
    }
#pragma unroll
    for (int j2 = 0; j2 < 2; j2++) {
      const f16* bh = whi + (size_t)((jt0 + j2) * 16 + col) * 128 + kb;
      const f16* bl = wlo + (size_t)((jt0 + j2) * 16 + col) * 128 + kb;
      f16x8 Bh = *(const f16x8*)bh;
      f16x8 Bl = *(const f16x8*)bl;
      acc[j2] = __builtin_amdgcn_mfma_f32_16x16x32_f16(Ah, Bh, acc[j2], 0, 0, 0);
      acc[j2] = __builtin_amdgcn_mfma_f32_16x16x32_f16(Ah, Bl, acc[j2], 0, 0, 0);
      acc[j2] = __builtin_amdgcn_mfma_f32_16x16x32_f16(Al, Bh, acc[j2], 0, 0, 0);
    }
  }

  float bpj[2];
  bpj[0] = biasb[jt0 * 16 + col];
  bpj[1] = biasb[(jt0 + 1) * 16 + col];
  float y2 = biasb[128];

#pragma unroll
  for (int r = 0; r < 4; r++) {
    float s0 = 0.f, s1 = 0.f, s2 = 0.f;
#pragma unroll
    for (int j2 = 0; j2 < 2; j2++) {
      float v = acc[j2][r];
      s0 = fmaf(v, v, s0);
      s1 += fabsf(v);
      s2 = fmaf(v, bpj[j2], s2);
    }
#pragma unroll
    for (int m = 1; m < 16; m <<= 1) {
      s0 += __shfl_xor(s0, m, 64);
      s1 += __shfl_xor(s1, m, 64);
      s2 += __shfl_xor(s2, m, 64);
    }
    if (col == 0) {
      red[0][quad * 4 + r][w] = s0;
      red[1][quad * 4 + r][w] = s1;
      red[2][quad * 4 + r][w] = s2;
    }
  }
  __syncthreads();

  if (tid < 16) {
    int gnode = min(n0w + tid, n - 1);
    float sc = scale[gnode];
    float s0f = (red[0][tid][0] + red[0][tid][1] + red[0][tid][2] + red[0][tid][3]) * sc * sc;
    float s1f = (red[1][tid][0] + red[1][tid][1] + red[1][tid][2] + red[1][tid][3]) * fabsf(sc);
    float s2f = (red[2][tid][0] + red[2][tid][1] + red[2][tid][2] + red[2][tid][3]) * sc;
    float xnr = xnorm[gnode];
    float xn = fmaxf(xnr, 1e-15f);
    float mxraw = sqrtf(s0f);
    float mxv = fmaxf(mxraw, 1e-15f);
    float ar = artan_k_d(xn, kv, sk);
    float c1 = tan_k_d(mxv / xn * ar, kv, sk);
    float s = (s1f == 0.f) ? 0.f : c1 / mxv;
    float pn = fmaxf(fabsf(c1) * (mxraw / mxv), 1e-15f);
    float ps = (s1f == 0.f) ? 1.f : proj_scale_d(pn, kv, maxn);
    s *= ps;
    float x2 = (s * s) * s0f;
    float xy = s * s2f;
    float Aa = 1.f - 2.f * kv * xy - kv * y2;
    float Cc = 1.f + kv * x2;
    float den = fmaxf(1.f - 2.f * kv * xy + (kv * kv) * x2 * y2, 1e-15f);
    nAs[tid] = Aa * s / den * sc;
    nCs[tid] = Cc / den;
  }
  __syncthreads();

#pragma unroll
  for (int r = 0; r < 4; r++) {
    int idx = quad * 4 + r;
    float Asc = nAs[idx], Cs = nCs[idx];
    float t0 = 0.f;
#pragma unroll
    for (int j2 = 0; j2 < 2; j2++) {
      float v = fmaf(Asc, acc[j2][r], Cs * bpj[j2]);
      t0 = fmaf(v, v, t0);
    }
#pragma unroll
    for (int m = 1; m < 16; m <<= 1) t0 += __shfl_xor(t0, m, 64);
    if (col == 0) redT[idx][w] = t0;
  }
  __syncthreads();

  if (tid < 16) {
    float t0f = redT[tid][0] + redT[tid][1] + redT[tid][2] + redT[tid][3];
    float nraw = sqrtf(t0f);
    float ps2 = proj_scale_d(fmaxf(nraw, 1e-15f), kv, maxn);
    float nh = fmaxf(ps2 * nraw, 1e-15f);
    nL[tid] = artan_k_d(nh, kv, sk) / nh * ps2;
  }
  __syncthreads();

#pragma unroll
  for (int r = 0; r < 4; r++) {
    int idx = quad * 4 + r;
    int gnode = n0w + idx;
    if (gnode >= n) continue;
    float Asc = nAs[idx], Cs = nCs[idx], L = nL[idx];
    f16* trow = tout + (size_t)gnode * 512 + ex * 128;
#pragma unroll
    for (int j2 = 0; j2 < 2; j2++) {
      float v = fmaf(Asc, acc[j2][r], Cs * bpj[j2]);
      trow[(jt0 + j2) * 16 + col] = (f16)(L * v);
    }
  }
}

// ---------------- fused multi-expert edge sweep ----------------
// MODE 0 (NE=4): layer-1 -> interior runs write agg1[node][512] fp32 + scl2/xnk2.
// MODE 1 (NE=4): layer-2 -> per-expert logmap0(expmap0) pooling into feats.
// MODE 2 (NE=1): gate    -> relu(+bias) pooling into hgate. t rows stride 512 halfs.
template <int MODE, int NE>
__global__ __launch_bounds__(256) void k_aggF(
    const int2* __restrict__ esw, const int* __restrict__ off,
    const int* __restrict__ bnode, const int* __restrict__ bslot,
    const int* __restrict__ batch, const f16x2* __restrict__ t, float* __restrict__ agg1,
    float* __restrict__ aggc, float* __restrict__ scl2, float* __restrict__ xnk2,
    float* __restrict__ feats, const float* __restrict__ bias, float* __restrict__ hgate,
    int etot, int n, CurvPack cp) {
  int gw = blockIdx.x * 4 + (threadIdx.x >> 6);
  int lane = threadIdx.x & 63;
  int e0 = gw * CHUNK;
  if (e0 >= etot) return;
  int e1 = min(e0 + CHUNK, etot);
  int bnHead = bnode[gw];
  int slotA = bslot[gw];
  int slotB = ((gw + 1) * CHUNK < etot) ? bslot[gw + 1] : slotA;
  int cur = bnHead;
  int runStart = off[cur];
  int eend = off[cur + 1];
  float ax[NE], ay[NE], pax[NE], pay[NE];
#pragma unroll
  for (int e = 0; e < NE; e++) {
    ax[e] = ay[e] = pax[e] = pay[e] = 0.f;
  }
  int bcur = (MODE >= 1) ? batch[cur] : 0;
  float bbx = 0.f, bby = 0.f;
  if (MODE == 2) {
    float2 bb = ((const float2*)bias)[lane];
    bbx = bb.x;
    bby = bb.y;
  }

  auto flushInterior = [&]() {
#pragma unroll
    for (int e = 0; e < NE; e++) {
      if (MODE == 0) {
        ((float2*)agg1)[(size_t)cur * 256 + e * 64 + lane] = make_float2(ax[e], ay[e]);
        float n2 = wsum64(fmaf(ax[e], ax[e], ay[e] * ay[e]));
        float nraw = sqrtf(n2);
        float nnv = fmaxf(nraw, 1e-15f);
        float tk = tan_k_d(nnv, cp.k[e], cp.sk[e]);
        float s = tk / nnv;
        float pn = fmaxf(fabsf(tk) * (nraw / nnv), 1e-15f);
        float ps = proj_scale_d(pn, cp.k[e], cp.mx[e]);
        if (lane == 0) {
          scl2[(size_t)e * n + cur] = s * ps;
          xnk2[(size_t)e * n + cur] = pn * ps;
        }
      } else if (MODE == 1) {
        float n2 = wsum64(fmaf(ax[e], ax[e], ay[e] * ay[e]));
        float nraw = sqrtf(n2);
        float nnv = fmaxf(nraw, 1e-15f);
        float tk = tan_k_d(nnv, cp.k[e], cp.sk[e]);
        float s = tk / nnv;
        float pn = fmaxf(fabsf(tk) * (nraw / nnv), 1e-15f);
        float ps = proj_scale_d(pn, cp.k[e], cp.mx[e]);
        s *= ps;
        float nh = fmaxf(pn * ps, 1e-15f);
        float sc = artan_k_d(nh, cp.k[e], cp.sk[e]) / nh * s;
        pax[e] = fmaf(sc, ax[e], pax[e]);
        pay[e] = fmaf(sc, ay[e], pay[e]);
      } else {
        pax[e] += fmaxf(ax[e] + bbx, 0.f);
        pay[e] += fmaxf(ay[e] + bby, 0.f);
      }
    }
  };
  auto flushBoundary = [&]() {
    int slot = (cur == bnHead) ? slotA : slotB;
#pragma unroll
    for (int e = 0; e < NE; e++) {
      float* dp = aggc + (size_t)slot * 512 + e * 128 + lane * 2;
      atomicAdd(dp, ax[e]);
      atomicAdd(dp + 1, ay[e]);
    }
  };
  auto flushPool = [&]() {
#pragma unroll
    for (int e = 0; e < NE; e++) {
      if (MODE == 1) {
        float* fp = &feats[(size_t)bcur * 512 + e * 128 + lane * 2];
        atomicAdd(fp, pax[e]);
        atomicAdd(fp + 1, pay[e]);
      } else if (MODE == 2) {
        float* hp = &hgate[(size_t)bcur * 128 + lane * 2];
        atomicAdd(hp, pax[e]);
        atomicAdd(hp + 1, pay[e]);
      }
    }
  };

  int j = e0;
  while (j < e1) {
    if (j + 8 <= e1 && eend >= j + 8) {
      int2 m[8];
#pragma unroll
      for (int q = 0; q < 8; q++) m[q] = esw[j + q];
      f16x2 r[8][NE];
#pragma unroll
      for (int q = 0; q < 8; q++) {
        int s = __builtin_amdgcn_readfirstlane(m[q].x);
        const f16x2* base = t + (size_t)s * 256;
#pragma unroll
        for (int e = 0; e < NE; e++) r[q][e] = base[e * 64 + lane];
      }
#pragma unroll
      for (int q = 0; q < 8; q++) {
        float w = __int_as_float(m[q].y);
#pragma unroll
        for (int e = 0; e < NE; e++) {
          ax[e] = fmaf(w, (float)r[q][e][0], ax[e]);
          ay[e] = fmaf(w, (float)r[q][e][1], ay[e]);
        }
      }
      j += 8;
    } else if (j + 4 <= e1 && eend >= j + 4) {
      int2 m[4];
#pragma unroll
      for (int q = 0; q < 4; q++) m[q] = esw[j + q];
      f16x2 r[4][NE];
#pragma unroll
      for (int q = 0; q < 4; q++) {
        int s = __builtin_amdgcn_readfirstlane(m[q].x);
        const f16x2* base = t + (size_t)s * 256;
#pragma unroll
        for (int e = 0; e < NE; e++) r[q][e] = base[e * 64 + lane];
      }
#pragma unroll
      for (int q = 0; q < 4; q++) {
        float w = __int_as_float(m[q].y);
#pragma unroll
        for (int e = 0; e < NE; e++) {
          ax[e] = fmaf(w, (float)r[q][e][0], ax[e]);
          ay[e] = fmaf(w, (float)r[q][e][1], ay[e]);
        }
      }
      j += 4;
    } else {
      if (j == eend) {
        if (runStart >= e0) flushInterior(); else flushBoundary();
#pragma unroll
        for (int e = 0; e < NE; e++) ax[e] = ay[e] = 0.f;
        runStart = j;
        cur++;
        eend = off[cur + 1];
        if (MODE >= 1) {
          int nb = batch[cur];
          if (nb != bcur) {
            flushPool();
#pragma unroll
            for (int e = 0; e < NE; e++) pax[e] = pay[e] = 0.f;
            bcur = nb;
          }
        }
      }
      int2 m = esw[j];
      int s = __builtin_amdgcn_readfirstlane(m.x);
      const f16x2* base = t + (size_t)s * 256;
      float w = __int_as_float(m.y);
#pragma unroll
      for (int e = 0; e < NE; e++) {
        f16x2 rv = base[e * 64 + lane];
        ax[e] = fmaf(w, (float)rv[0], ax[e]);
        ay[e] = fmaf(w, (float)rv[1], ay[e]);
      }
      j++;
    }
  }
  if (runStart >= e0 && eend <= e1) flushInterior(); else flushBoundary();
  if (MODE >= 1) flushPool();
}

// ---------------- fixups for chunk-spanning runs ----------------
__global__ void k_fix1(const int* __restrict__ bnode, const int* __restrict__ bslot,
                       const int* __restrict__ off, const float* __restrict__ aggc,
                       float* __restrict__ agg1, float* __restrict__ scl2,
                       float* __restrict__ xnk2, int nchunk, int n, CurvPack cp) {
  int g = blockIdx.x * 4 + (threadIdx.x >> 6);
  int lane = threadIdx.x & 63;
  if (g >= nchunk) return;
  int nd;
  if (!span_head(bnode, bslot, off, g, nd)) return;
#pragma unroll
  for (int e = 0; e < 4; e++) {
    float2 v = ((const float2*)aggc)[(size_t)g * 256 + e * 64 + lane];
    ((float2*)agg1)[(size_t)nd * 256 + e * 64 + lane] = v;
    float n2 = wsum64(fmaf(v.x, v.x, v.y * v.y));
    float nraw = sqrtf(n2);
    float nnv = fmaxf(nraw, 1e-15f);
    float tk = tan_k_d(nnv, cp.k[e], cp.sk[e]);
    float s = tk / nnv;
    float pn = fmaxf(fabsf(tk) * (nraw / nnv), 1e-15f);
    float ps = proj_scale_d(pn, cp.k[e], cp.mx[e]);
    if (lane == 0) {
      scl2[(size_t)e * n + nd] = s * ps;
      xnk2[(size_t)e * n + nd] = pn * ps;
    }
  }
}

__global__ void k_fix2(const int* __restrict__ bnode, const int* __restrict__ bslot,
                       const int* __restrict__ off, const float* __restrict__ aggc,
                       const int* __restrict__ batch, float* __restrict__ feats, int nchunk,
                       CurvPack cp) {
  int g = blockIdx.x * 4 + (threadIdx.x >> 6);
  int lane = threadIdx.x & 63;
  if (g >= nchunk) return;
  int nd;
  if (!span_head(bnode, bslot, off, g, nd)) return;
  int b = batch[nd];
#pragma unroll
  for (int e = 0; e < 4; e++) {
    float2 v = ((const float2*)aggc)[(size_t)g * 256 + e * 64 + lane];
    float n2 = wsum64(fmaf(v.x, v.x, v.y * v.y));
    float nraw = sqrtf(n2);
    float nnv = fmaxf(nraw, 1e-15f);
    float tk = tan_k_d(nnv, cp.k[e], cp.sk[e]);
    float s = tk / nnv;
    float pn = fmaxf(fabsf(tk) * (nraw / nnv), 1e-15f);
    float ps = proj_scale_d(pn, cp.k[e], cp.mx[e]);
    s *= ps;
    float nh = fmaxf(pn * ps, 1e-15f);
    float sc = artan_k_d(nh, cp.k[e], cp.sk[e]) / nh * s;
    float* fp = &feats[(size_t)b * 512 + e * 128 + lane * 2];
    atomicAdd(fp, sc * v.x);
    atomicAdd(fp + 1, sc * v.y);
  }
}

__global__ void k_fixG(const int* __restrict__ bnode, const int* __restrict__ bslot,
                       const int* __restrict__ off, const float* __restrict__ aggc,
                       const int* __restrict__ batch, const float* __restrict__ bias,
                       float* __restrict__ hgate, int nchunk) {
  int g = blockIdx.x * 4 + (threadIdx.x >> 6);
  int lane = threadIdx.x & 63;
  if (g >= nchunk) return;
  int nd;
  if (!span_head(bnode, bslot, off, g, nd)) return;
  float2 v = ((const float2*)aggc)[(size_t)g * 256 + lane];
  float2 bb = ((const float2*)bias)[lane];
  int b = batch[nd];
  float* hp = &hgate[(size_t)b * 128 + lane * 2];
  atomicAdd(hp, fmaxf(v.x + bb.x, 0.f));
  atomicAdd(hp + 1, fmaxf(v.y + bb.y, 0.f));
}

// ---------------- gate GEMM 1 ----------------
__global__ __launch_bounds__(256) void k_gate1(const float* __restrict__ x,
                                               const float* __restrict__ gw1,
                                               float* __restrict__ m1, int n) {
  __shared__ float xT[64][68];
  __shared__ float Wt[64][36];
  int tid = threadIdx.x;
  int n0 = blockIdx.x * 64;
  int c = tid & 7, r = tid >> 3;
  float acc[2][4];
#pragma unroll
  for (int i = 0; i < 2; i++)
#pragma unroll
    for (int jj = 0; jj < 4; jj++) acc[i][jj] = 0.f;

  for (int kc = 0; kc < 2; kc++) {
    if (kc) __syncthreads();
#pragma unroll
    for (int it = 0; it < 8; it++) {
      int u = tid + it * 256;
      int j = u >> 6, kd = u & 63;
      Wt[kd][j] = gw1[j * 128 + kc * 64 + kd];
    }
#pragma unroll
    for (int it = 0; it < 4; it++) {
      int u = tid + it * 256;
      int node = u >> 4, c4 = u & 15;
      float4 v = make_float4(0.f, 0.f, 0.f, 0.f);
      if (n0 + node < n) v = ((const float4*)x)[(size_t)(n0 + node) * 32 + kc * 16 + c4];
      xT[4 * c4 + 0][node] = v.x;
      xT[4 * c4 + 1][node] = v.y;
      xT[4 * c4 + 2][node] = v.z;
      xT[4 * c4 + 3][node] = v.w;
    }
    __syncthreads();
#pragma unroll 8
    for (int kd = 0; kd < 64; kd++) {
      float2 av = *(const float2*)&xT[kd][r * 2];
      float4 bv = *(const float4*)&Wt[kd][c * 4];
      float a[2] = {av.x, av.y};
      float bbv[4] = {bv.x, bv.y, bv.z, bv.w};
#pragma unroll
      for (int i = 0; i < 2; i++)
#pragma unroll
        for (int jj = 0; jj < 4; jj++) acc[i][jj] = fmaf(a[i], bbv[jj], acc[i][jj]);
    }
  }
#pragma unroll
  for (int i = 0; i < 2; i++) {
    int node = n0 + r * 2 + i;
    if (node >= n) continue;
    ((float4*)m1)[(size_t)node * 8 + c] = make_float4(acc[i][0], acc[i][1], acc[i][2], acc[i][3]);
  }
}

// ---------------- gate GEMM 2 (fp16 out, row stride 512 halfs) ----------------
__global__ __launch_bounds__(256) void k_gate2(const float* __restrict__ g1,
                                               const float* __restrict__ gw2,
                                               f16* __restrict__ m2, int n) {
  __shared__ float xT[32][68];
  __shared__ float Wt[32][132];
  int tid = threadIdx.x;
  int n0 = blockIdx.x * 64;
  int c = tid & 15, r = tid >> 4;
  float acc[4][8];
#pragma unroll
  for (int i = 0; i < 4; i++)
#pragma unroll
    for (int jj = 0; jj < 8; jj++) acc[i][jj] = 0.f;

#pragma unroll
  for (int it = 0; it < 16; it++) {
    int u = tid + it * 256;
    int j = u >> 5, kd = u & 31;
    Wt[kd][j] = gw2[j * 32 + kd];
  }
#pragma unroll
  for (int it = 0; it < 2; it++) {
    int u = tid + it * 256;
    int node = u >> 3, c4 = u & 7;
    float4 v = make_float4(0.f, 0.f, 0.f, 0.f);
    if (n0 + node < n) v = ((const float4*)g1)[(size_t)(n0 + node) * 8 + c4];
    xT[4 * c4 + 0][node] = v.x;
    xT[4 * c4 + 1][node] = v.y;
    xT[4 * c4 + 2][node] = v.z;
    xT[4 * c4 + 3][node] = v.w;
  }
  __syncthreads();
#pragma unroll 8
  for (int kd = 0; kd < 32; kd++) {
    float4 av = *(const float4*)&xT[kd][r * 4];
    float4 b0 = *(const float4*)&Wt[kd][c * 8];
    float4 b1 = *(const float4*)&Wt[kd][c * 8 + 4];
    float a[4] = {av.x, av.y, av.z, av.w};
    float bbv[8] = {b0.x, b0.y, b0.z, b0.w, b1.x, b1.y, b1.z, b1.w};
#pragma unroll
    for (int i = 0; i < 4; i++)
#pragma unroll
      for (int jj = 0; jj < 8; jj++) acc[i][jj] = fmaf(a[i], bbv[jj], acc[i][jj]);
  }
#pragma unroll
  for (int i = 0; i < 4; i++) {
    int node = n0 + r * 4 + i;
    if (node >= n) continue;
    f16x8 hv;
#pragma unroll
    for (int jj = 0; jj < 8; jj++) hv[jj] = (f16)acc[i][jj];
    *((f16x8*)(m2 + (size_t)node * 512) + c) = hv;
  }
}

// ---------------- gate aggregation dim32 ----------------
__global__ void k_agg_relu32(const float* __restrict__ m1, const int* __restrict__ off,
                             const int2* __restrict__ esw, const float* __restrict__ bias,
                             float* __restrict__ g1, int n) {
  int node = blockIdx.x * 4 + (threadIdx.x >> 6);
  int lane = threadIdx.x & 63;
  if (node >= n) return;
  int grp = lane >> 3, l8 = lane & 7;
  int e0 = off[node], e1 = off[node + 1];
  float4 acc = make_float4(0.f, 0.f, 0.f, 0.f);
  for (int base = e0 + grp; base < e1; base += 8) {
    int2 me = esw[base];
    int ss = me.x;
    float ww = __int_as_float(me.y);
    float4 tv = ((const float4*)m1)[(size_t)ss * 8 + l8];
    acc.x = fmaf(ww, tv.x, acc.x);
    acc.y = fmaf(ww, tv.y, acc.y);
    acc.z = fmaf(ww, tv.z, acc.z);
    acc.w = fmaf(ww, tv.w, acc.w);
  }
#pragma unroll
  for (int m = 8; m <= 32; m <<= 1) {
    acc.x += __shfl_xor(acc.x, m, 64);
    acc.y += __shfl_xor(acc.y, m, 64);
    acc.z += __shfl_xor(acc.z, m, 64);
    acc.w += __shfl_xor(acc.w, m, 64);
  }
  if (grp == 0) {
    float4 bb = ((const float4*)bias)[l8];
    float4 o = make_float4(fmaxf(acc.x + bb.x, 0.f), fmaxf(acc.y + bb.y, 0.f),
                           fmaxf(acc.z + bb.z, 0.f), fmaxf(acc.w + bb.w, 0.f));
    ((float4*)g1)[(size_t)node * 8 + l8] = o;
  }
}

// ---------------- final ----------------
__global__ __launch_bounds__(128) void k_final(const float* __restrict__ feats,
                                               const float* __restrict__ hgate,
                                               const float* __restrict__ counts,
                                               const float* __restrict__ gate_u,
                                               const float* __restrict__ tau_raw,
                                               float* __restrict__ out, CurvPack cp) {
  __shared__ float l2[2];
  int b = blockIdx.x;
  int j = threadIdx.x;
  float cnt = fmaxf(counts[b], 1.f);
  float hg = hgate[(size_t)b * 128 + j] / cnt;

  auto bsum = [&](float v) -> float {
    v = wsum64(v);
    __syncthreads();
    if ((j & 63) == 0) l2[j >> 6] = v;
    __syncthreads();
    return l2[0] + l2[1];
  };

  float nhg2 = bsum(hg * hg);
  float nhgraw = sqrtf(nhg2);
  float nhg = fmaxf(nhgraw, 1e-15f);

  float d[4], tau[4];
#pragma unroll
  for (int i = 0; i < 4; i++) {
    float kv = cp.k[i], sk = cp.sk[i], mxn = cp.mx[i];
    float tk = tan_k_d(nhg, kv, sk);
    float s = tk / nhg;
    float pn = fmaxf(fabsf(tk) * (nhgraw / nhg), 1e-15f);
    s *= proj_scale_d(pn, kv, mxn);
    float zk = s * hg;

    float u = gate_u[i * 128 + j];
    float nu2 = bsum(u * u);
    float nuraw = sqrtf(nu2);
    float nu = fmaxf(nuraw, 1e-15f);
    float tku = tan_k_d(nu, kv, sk);
    float su = tku / nu;
    float pnu = fmaxf(fabsf(tku) * (nuraw / nu), 1e-15f);
    su *= proj_scale_d(pnu, kv, mxn);
    float yk = su * u;

    float xv = -zk;
    float x2 = bsum(xv * xv);
    float y2 = bsum(yk * yk);
    float xy = bsum(xv * yk);
    float A = 1.f - 2.f * kv * xy - kv * y2;
    float C = 1.f + kv * x2;
    float den = fmaxf(1.f - 2.f * kv * xy + (kv * kv) * x2 * y2, 1e-15f);
    float ma = (A * xv + C * yk) / den;
    float m2 = bsum(ma * ma);
    float mraw = sqrtf(m2);
    float ps2 = proj_scale_d(fmaxf(mraw, 1e-15f), kv, mxn);
    float nm = fmaxf(ps2 * mraw, 1e-15f);
    d[i] = 2.f * artan_k_d(nm, kv, sk);

    float tr = tau_raw[i];
    tau[i] = fminf(fmaxf(log1pf(expf(tr)) + 0.05f, 0.05f), 10.f);
  }

  float xi[4];
  float mxv = -1e30f;
#pragma unroll
  for (int i = 0; i < 4; i++) {
    xi[i] = -d[i] / tau[i];
    mxv = fmaxf(mxv, xi[i]);
  }
  float es = 0.f, e[4];
#pragma unroll
  for (int i = 0; i < 4; i++) {
    e[i] = expf(xi[i] - mxv);
    es += e[i];
  }
  float w[4];
#pragma unroll
  for (int i = 0; i < 4; i++) w[i] = e[i] / es;

#pragma unroll
  for (int i = 0; i < 4; i++)
    out[(size_t)b * 512 + i * 128 + j] = feats[(size_t)b * 512 + i * 128 + j] / cnt * w[i];

  if (j < 4) {
    out[65536 + b * 4 + j] = w[j];
    out[66048 + b * 4 + j] = d[j];
  }
  if (b == 0 && j < 4) out[66560 + j] = tau[j];
}

// ---------------- host launcher ----------------
extern "C" void kernel_launch(void* const* d_in, const int* in_sizes, int n_in,
                              void* d_out, int out_size, void* d_ws, size_t ws_size,
                              hipStream_t stream) {
  const float* x = (const float*)d_in[0];
  const int* ei = (const int*)d_in[1];
  const int* batch = (const int*)d_in[2];
  const float* ew1 = (const float*)d_in[3];
  const float* eb1 = (const float*)d_in[4];
  const float* ew2 = (const float*)d_in[5];
  const float* eb2 = (const float*)d_in[6];
  const float* gw1 = (const float*)d_in[7];
  const float* gb1 = (const float*)d_in[8];
  const float* gw2 = (const float*)d_in[9];
  const float* gb2 = (const float*)d_in[10];
  const float* gu = (const float*)d_in[11];
  const float* traw = (const float*)d_in[12];
  float* out = (float*)d_out;

  const int N = NN, E = EE, ET = ETOT, B = BB;

  float* ws = (float*)d_ws;
  size_t o = 0;
  f16* t4 = (f16*)ws;       o += (size_t)N * 256;   // N*512 halfs, interleaved [node][ex*128]
  float* agg1 = ws + o;     o += (size_t)N * 512;   // layer-1 output fp32 interleaved
  float* aggc = ws + o;     o += (size_t)NCHUNK * 512;  // compact boundary accum
  float* deg = ws + o;      o += N;                 // becomes dinv
  float* scl1 = ws + o;     o += (size_t)4 * N;
  float* xnk1 = ws + o;     o += (size_t)4 * N;
  float* scl2 = ws + o;     o += (size_t)4 * N;
  float* xnk2 = ws + o;     o += (size_t)4 * N;
  float* counts = ws + o;   o += 256;
  float* feats = ws + o;    o += (size_t)B * 512;
  float* hg = ws + o;       o += (size_t)B * 128;
  float* biasb = ws + o;    o += 8 * 132;
  f16* whi = (f16*)(ws + o);    o += 8 * 16384 / 2;
  f16* wlo = (f16*)(ws + o);    o += 8 * 16384 / 2;
  int* ideg = (int*)(ws + o);   o += N;
  int* csroff = (int*)(ws + o); o += N + 8;
  int* cursor = (int*)(ws + o); o += N;
  int* boff = (int*)(ws + o);   o += 136;
  int* bsum = (int*)(ws + o);   o += 256;
  int* bnode = (int*)(ws + o);  o += NCHUNK + 8;
  int* bslot = (int*)(ws + o);  o += NCHUNK + 8;
  int2* esw = (int2*)(ws + o);  o += (size_t)2 * ET;

  // gate scratch aliases agg1 (free after layer-2 matmfma consumed it)
  float* m1 = agg1;
  float* g1 = agg1 + (size_t)N * 32;

  hipMemsetAsync(counts, 0, (256 + (size_t)B * 512 + (size_t)B * 128) * sizeof(float), stream);

  const double curvs[4] = {-1.0, 0.0, 1.0, -0.5};
  CurvPack cp;
  for (int i = 0; i < 4; i++) {
    double kd = curvs[i];
    double skd = sqrt(fabs(kd));
    cp.k[i] = (float)kd;
    cp.sk[i] = (float)skd;
    cp.mx[i] = (kd < 0) ? (float)((1.0 - 1e-5) / skd) : 3.0e38f;
  }

  k_init<<<(N + 255) / 256, 256, 0, stream>>>(deg, N);
  k_counts<<<1, 256, 0, stream>>>(batch, boff, counts, N);
  k_deg<<<(E + 255) / 256, 256, 0, stream>>>(ei, deg, E);
  k_dinv<<<(N + 255) / 256, 256, 0, stream>>>(deg, ideg, N);
  k_scanA<<<SCB, 256, 0, stream>>>(ideg, bsum, N);
  k_scanB<<<1, 256, 0, stream>>>(bsum, SCB);
  k_scanC<<<SCB, 256, 0, stream>>>(ideg, bsum, csroff, cursor, N);
  k_bnodes<<<(NCHUNK + 255) / 256, 256, 0, stream>>>(csroff, bnode, NCHUNK, N);
  k_bslot<<<(NCHUNK + 255) / 256, 256, 0, stream>>>(bnode, bslot, NCHUNK);
  k_place<<<(ET + 255) / 256, 256, 0, stream>>>(ei, deg, cursor, esw, E, N);
  k_nodeprep<<<(N + 3) / 4, 256, 0, stream>>>(x, scl1, xnk1, N, cp);
  k_biaspt_all<<<8, 128, 0, stream>>>(eb1, eb2, biasb, cp);
  k_w2h<<<512, 256, 0, stream>>>(ew1, ew2, whi, wlo);

  const int aggBlocks = (NCHUNK + 3) / 4;
  dim3 mfmaGrid((N + 15) / 16, 4);

  // ---- layer 1 (all 4 experts fused) ----
  k_matmfma<<<mfmaGrid, 256, 0, stream>>>(x, 128, 0, scl1, xnk1, whi, wlo, biasb, 0, t4, N, cp);
  k_zeroc<<<aggBlocks, 256, 0, stream>>>(bnode, bslot, csroff, aggc, NCHUNK);
  k_aggF<0, 4><<<aggBlocks, 256, 0, stream>>>(esw, csroff, bnode, bslot, batch,
                                              (const f16x2*)t4, agg1, aggc, scl2, xnk2, nullptr,
                                              nullptr, nullptr, ET, N, cp);
  k_fix1<<<aggBlocks, 256, 0, stream>>>(bnode, bslot, csroff, aggc, agg1, scl2, xnk2, NCHUNK, N,
                                        cp);
  // ---- layer 2 ----
  k_matmfma<<<mfmaGrid, 256, 0, stream>>>(agg1, 512, 128, scl2, xnk2, whi, wlo, biasb, 1, t4, N,
                                          cp);
  k_zeroc<<<aggBlocks, 256, 0, stream>>>(bnode, bslot, csroff, aggc, NCHUNK);
  k_aggF<1, 4><<<aggBlocks, 256, 0, stream>>>(esw, csroff, bnode, bslot, batch,
                                              (const f16x2*)t4, nullptr, aggc, nullptr, nullptr,
                                              feats, nullptr, nullptr, ET, N, cp);
  k_fix2<<<aggBlocks, 256, 0, stream>>>(bnode, bslot, csroff, aggc, batch, feats, NCHUNK, cp);

  // ---- gate GCN ----
  k_gate1<<<(N + 63) / 64, 256, 0, stream>>>(x, gw1, m1, N);
  k_agg_relu32<<<(N + 3) / 4, 256, 0, stream>>>(m1, csroff, esw, gb1, g1, N);
  k_gate2<<<(N + 63) / 64, 256, 0, stream>>>(g1, gw2, t4, N);
  k_zeroc<<<aggBlocks, 256, 0, stream>>>(bnode, bslot, csroff, aggc, NCHUNK);
  k_aggF<2, 1><<<aggBlocks, 256, 0, stream>>>(esw, csroff, bnode, bslot, batch,
                                              (const f16x2*)t4, nullptr, aggc, nullptr, nullptr,
                                              nullptr, gb2, hg, ET, N, cp);
  k_fixG<<<aggBlocks, 256, 0, stream>>>(bnode, bslot, csroff, aggc, batch, gb2, hg, NCHUNK);

  k_final<<<B, 128, 0, stream>>>(feats, hg, counts, gu, traw, out, cp);

  (void)in_sizes; (void)n_in; (void)out_size; (void)ws_size;
}